// Round 2
// baseline (1275.794 us; speedup 1.0000x reference)
//
#include <hip/hip_runtime.h>
#include <math.h>

#define B_    2
#define L_    2048
#define DM    1024
#define DIN   2048
#define NH    32
#define HD    64
#define NST   128
#define NA    32
#define NC    32
#define CHK   64
#define DPROJ 4480

#define OFF_Z    0
#define OFF_X    2048
#define OFF_BG   4096
#define OFF_CG   4224
#define OFF_DDT  4352
#define OFF_DDA  4384
#define OFF_TRAP 4416
#define OFF_ANG  4448

typedef union { float4 v; float a[4]; } F4;

__device__ __forceinline__ float softplusf_(float x) {
  return (x > 20.0f) ? x : log1pf(expf(x));
}
__device__ __forceinline__ float sigmoidf_(float x) {
  return 1.0f / (1.0f + expf(-x));
}

// ---------------- P1/P7: f32 GEMM, 128x128 tile, BK=16, 8x8 per thread ----------------
__global__ __launch_bounds__(256) void gemm_f32_128(
    const float* __restrict__ A, const float* __restrict__ Bm,
    float* __restrict__ C, int M, int N, int K) {
  __shared__ float As[16][132];
  __shared__ float Bs[16][132];
  const int t  = threadIdx.x;
  const int bm = blockIdx.y * 128;
  const int bn = blockIdx.x * 128;
  const int tr = t >> 4, tc = t & 15;
  float acc[8][8];
#pragma unroll
  for (int i = 0; i < 8; ++i)
#pragma unroll
    for (int j = 0; j < 8; ++j) acc[i][j] = 0.0f;

  const int am  = t >> 2, ak  = (t & 3) << 2;
  const int bk  = t >> 5, bn4 = (t & 31) << 2;

  for (int k0 = 0; k0 < K; k0 += 16) {
    float4 a0 = *(const float4*)(A + (size_t)(bm + am) * K + k0 + ak);
    float4 a1 = *(const float4*)(A + (size_t)(bm + am + 64) * K + k0 + ak);
    float4 b0 = *(const float4*)(Bm + (size_t)(k0 + bk) * N + bn + bn4);
    float4 b1 = *(const float4*)(Bm + (size_t)(k0 + bk + 8) * N + bn + bn4);
    As[ak + 0][am] = a0.x; As[ak + 1][am] = a0.y; As[ak + 2][am] = a0.z; As[ak + 3][am] = a0.w;
    As[ak + 0][am + 64] = a1.x; As[ak + 1][am + 64] = a1.y; As[ak + 2][am + 64] = a1.z; As[ak + 3][am + 64] = a1.w;
    *(float4*)&Bs[bk][bn4] = b0;
    *(float4*)&Bs[bk + 8][bn4] = b1;
    __syncthreads();
#pragma unroll
    for (int kk = 0; kk < 16; ++kk) {
      float a[8], b[8];
      *(float4*)&a[0] = *(const float4*)&As[kk][tr * 8];
      *(float4*)&a[4] = *(const float4*)&As[kk][tr * 8 + 4];
      *(float4*)&b[0] = *(const float4*)&Bs[kk][tc * 8];
      *(float4*)&b[4] = *(const float4*)&Bs[kk][tc * 8 + 4];
#pragma unroll
      for (int i = 0; i < 8; ++i)
#pragma unroll
        for (int j = 0; j < 8; ++j)
          acc[i][j] = fmaf(a[i], b[j], acc[i][j]);
    }
    __syncthreads();
  }
#pragma unroll
  for (int i = 0; i < 8; ++i) {
    float* cp = C + (size_t)(bm + tr * 8 + i) * N + bn + tc * 8;
    *(float4*)cp       = *(float4*)&acc[i][0];
    *(float4*)(cp + 4) = *(float4*)&acc[i][4];
  }
}

// ---------------- P2: per-(b,l) pointwise: dt/adt/g1/g2 + rmsnorm(Bg,Cg) ----------------
__global__ __launch_bounds__(128) void pointwise_kernel(
    const float* __restrict__ proj, const float* __restrict__ dt_bias,
    const float* __restrict__ Bnw, const float* __restrict__ Cnw,
    float* __restrict__ Bn, float* __restrict__ Cn,
    float* __restrict__ dtg, float* __restrict__ adtg,
    float* __restrict__ g1g, float* __restrict__ g2g) {
  const int bl = blockIdx.x;
  const int l  = bl & (L_ - 1);
  const int b  = bl >> 11;
  const int t  = threadIdx.x;
  const float* row = proj + (size_t)bl * DPROJ;

  float vb = row[OFF_BG + t];
  float vc = row[OFF_CG + t];
  float sb = vb * vb, sc = vc * vc;
#pragma unroll
  for (int off = 32; off >= 1; off >>= 1) {
    sb += __shfl_xor(sb, off, 64);
    sc += __shfl_xor(sc, off, 64);
  }
  __shared__ float red[4];
  if ((t & 63) == 0) { red[t >> 6] = sb; red[2 + (t >> 6)] = sc; }
  __syncthreads();
  sb = red[0] + red[1];
  sc = red[2] + red[3];
  float rb = rsqrtf(sb * (1.0f / 128.0f) + 1e-5f);
  float rc = rsqrtf(sc * (1.0f / 128.0f) + 1e-5f);
  Bn[(size_t)bl * NST + t] = vb * rb * Bnw[t];
  Cn[(size_t)bl * NST + t] = vc * rc * Cnw[t];

  if (t < NH) {
    const int h = t;
    float dt = softplusf_(row[OFF_DDT + h] + dt_bias[h]);
    float a  = -softplusf_(row[OFF_DDA + h]);
    a = fminf(a, -1e-4f);
    float adt  = a * dt;
    float beta = sigmoidf_(row[OFF_TRAP + h]);
    float dtp  = 0.0f;
    if (l > 0) dtp = softplusf_(proj[(size_t)(bl - 1) * DPROJ + OFF_DDT + h] + dt_bias[h]);
    float g2 = (1.0f - beta) * expf(adt) * dtp;
    size_t idx = ((size_t)b * NH + h) * L_ + l;
    dtg[idx]  = dt;
    adtg[idx] = adt;
    g1g[idx]  = beta * dt;
    g2g[idx]  = g2;
  }
}

// ---------------- P3: theta[b,l,h,na] = cumsum_l( angles[b,l,na] * dt[b,l,h] ) ----------------
__global__ __launch_bounds__(64) void theta_kernel(
    const float* __restrict__ proj, const float* __restrict__ dtg,
    float* __restrict__ theta) {
  const int b  = blockIdx.x >> 5;
  const int h  = blockIdx.x & 31;
  const int na = threadIdx.x;
  if (na >= NA) return;
  const float* ap = proj + (size_t)b * L_ * DPROJ + OFF_ANG + na;
  const float* dp = dtg + ((size_t)b * NH + h) * L_;
  float* tp = theta + ((size_t)b * L_ * NH + h) * NA + na;
  float th = 0.0f;
#pragma unroll 16
  for (int l = 0; l < L_; ++l) {
    th = fmaf(ap[(size_t)l * DPROJ], dp[l], th);
    tp[(size_t)l * NH * NA] = th;
  }
}

// ---------------- P4: per-(b,chunk,head): rope-in-LDS, S1/S2, y_intra, Wsum, chunk_decay ----------------
__global__ __launch_bounds__(256) void chunk_kernel(
    const float* __restrict__ proj,
    const float* __restrict__ Bn, const float* __restrict__ Cn,
    const float* __restrict__ theta,
    const float* __restrict__ B_bias, const float* __restrict__ C_bias,
    const float* __restrict__ adtg, const float* __restrict__ g1g,
    const float* __restrict__ g2g,
    float* __restrict__ Wsum, float* __restrict__ cdg,
    float* __restrict__ ybuf) {
  const int h  = blockIdx.x & 31;
  const int c  = (blockIdx.x >> 5) & 31;
  const int b  = blockIdx.x >> 10;
  const int t  = threadIdx.x;
  const int l0 = c * CHK;

  __shared__ float Qs[64][132];
  __shared__ float Kxs[65][132];   // row i = K at global l0+i-1 (row 0: prev-chunk tail or 0)
  __shared__ float xxs[65][68];    // same indexing for x
  __shared__ float Ss[64][68];
  __shared__ float ell[64], g1s[64], g2s[64], w1s[64], w2s[64];

  // stage Q raw = Cn(row l0+i) + C_bias[h]
#pragma unroll
  for (int k = 0; k < 8; ++k) {
    int f = t + k * 256;
    int i = f >> 5, n = (f & 31) << 2;
    F4 v, bb;
    v.v  = *(const float4*)(Cn + (size_t)(b * L_ + l0 + i) * NST + n);
    bb.v = *(const float4*)(C_bias + h * NST + n);
#pragma unroll
    for (int q = 0; q < 4; ++q) v.a[q] += bb.a[q];
    *(float4*)&Qs[i][n] = v.v;
  }
  // stage K raw rows: Kxs[i] = Bn(row l0+i-1) + B_bias[h]
#pragma unroll
  for (int k = 0; k < 9; ++k) {
    int f = t + k * 256;
    if (f < 65 * 32) {
      int i = f >> 5, n = (f & 31) << 2;
      F4 v;
      if (i == 0 && c == 0) v.v = make_float4(0.f, 0.f, 0.f, 0.f);
      else {
        F4 bb;
        v.v  = *(const float4*)(Bn + (size_t)(b * L_ + l0 + i - 1) * NST + n);
        bb.v = *(const float4*)(B_bias + h * NST + n);
#pragma unroll
        for (int q = 0; q < 4; ++q) v.a[q] += bb.a[q];
      }
      *(float4*)&Kxs[i][n] = v.v;
    }
  }
  // stage x rows (same shifted indexing)
#pragma unroll
  for (int k = 0; k < 5; ++k) {
    int f = t + k * 256;
    if (f < 65 * 16) {
      int i = f >> 4, p = (f & 15) << 2;
      float4 v;
      if (i == 0 && c == 0) v = make_float4(0.f, 0.f, 0.f, 0.f);
      else v = *(const float4*)(proj + (size_t)(b * L_ + l0 + i - 1) * DPROJ + OFF_X + h * HD + p);
      *(float4*)&xxs[i][p] = v;
    }
  }
  if (t < 64) {
    size_t idx = ((size_t)b * NH + h) * L_ + l0 + t;
    float adt = adtg[idx];
    float g1  = g1g[idx];
    float g2  = g2g[idx];
    float v = adt;
#pragma unroll
    for (int off = 1; off < 64; off <<= 1) {
      float u = __shfl_up(v, off, 64);
      if (t >= off) v += u;
    }
    ell[t] = v;
    float last = __shfl(v, 63, 64);
    float de = expf(last - v);
    g1s[t] = g1; g2s[t] = g2;
    w1s[t] = g1 * de; w2s[t] = g2 * de;
    if (t == 63) cdg[((size_t)b * NC + c) * NH + h] = expf(v);
  }
  __syncthreads();

  // rope in place: pair (i, na); K row i uses theta[l0+i-1], Q row i-1 uses the same
#pragma unroll
  for (int k = 0; k < 9; ++k) {
    int f = t + k * 256;
    if (f < 65 * 32) {
      int i = f >> 5, na = f & 31;
      if (!(i == 0 && c == 0)) {
        float th = theta[((size_t)(b * L_ + l0 + i - 1) * NH + h) * NA + na];
        float sn, cs;
        sincosf(th, &sn, &cs);
        float a1 = Kxs[i][na], a2 = Kxs[i][na + 32];
        Kxs[i][na]      = a1 * cs - a2 * sn;
        Kxs[i][na + 32] = a1 * sn + a2 * cs;
        if (i >= 1) {
          float b1 = Qs[i - 1][na], b2 = Qs[i - 1][na + 32];
          Qs[i - 1][na]      = b1 * cs - b2 * sn;
          Qs[i - 1][na + 32] = b1 * sn + b2 * cs;
        }
      }
    }
  }
  __syncthreads();

  const int i0 = (t >> 4) << 2;
  const int j0 = (t & 15) << 2;   // doubles as p0 in the y pass
  float yacc[4][4];
#pragma unroll
  for (int r = 0; r < 4; ++r)
#pragma unroll
    for (int p = 0; p < 4; ++p) yacc[r][p] = 0.0f;

  float elli[4], ellj[4];
#pragma unroll
  for (int r = 0; r < 4; ++r) elli[r] = ell[i0 + r];
#pragma unroll
  for (int s = 0; s < 4; ++s) ellj[s] = ell[j0 + s];

#pragma unroll 1
  for (int pass = 0; pass < 2; ++pass) {
    const int KOFF = (pass == 0) ? 1 : 0;   // 1 -> K/x, 0 -> Kp/xp
    float acc[4][4];
#pragma unroll
    for (int r = 0; r < 4; ++r)
#pragma unroll
      for (int s = 0; s < 4; ++s) acc[r][s] = 0.0f;

    for (int n4 = 0; n4 < 32; ++n4) {
      F4 qa[4], kb[4];
#pragma unroll
      for (int r = 0; r < 4; ++r) qa[r].v = *(const float4*)&Qs[i0 + r][n4 << 2];
#pragma unroll
      for (int s = 0; s < 4; ++s) kb[s].v = *(const float4*)&Kxs[KOFF + j0 + s][n4 << 2];
#pragma unroll
      for (int r = 0; r < 4; ++r)
#pragma unroll
        for (int s = 0; s < 4; ++s) {
          acc[r][s] = fmaf(qa[r].a[0], kb[s].a[0], acc[r][s]);
          acc[r][s] = fmaf(qa[r].a[1], kb[s].a[1], acc[r][s]);
          acc[r][s] = fmaf(qa[r].a[2], kb[s].a[2], acc[r][s]);
          acc[r][s] = fmaf(qa[r].a[3], kb[s].a[3], acc[r][s]);
        }
    }
    const float* gs = (pass == 0) ? g1s : g2s;
#pragma unroll
    for (int r = 0; r < 4; ++r)
#pragma unroll
      for (int s = 0; s < 4; ++s) {
        int i = i0 + r, j = j0 + s;
        float val = 0.0f;
        if (j <= i) val = acc[r][s] * gs[j] * expf(elli[r] - ellj[s]);
        Ss[i][j] = val;
      }
    __syncthreads();

    for (int j4 = 0; j4 < 16; ++j4) {
      F4 sa[4], xv[4];
#pragma unroll
      for (int r = 0; r < 4; ++r)  sa[r].v  = *(const float4*)&Ss[i0 + r][j4 << 2];
#pragma unroll
      for (int jj = 0; jj < 4; ++jj) xv[jj].v = *(const float4*)&xxs[KOFF + (j4 << 2) + jj][j0];
#pragma unroll
      for (int r = 0; r < 4; ++r)
#pragma unroll
        for (int p = 0; p < 4; ++p) {
          yacc[r][p] = fmaf(sa[r].a[0], xv[0].a[p], yacc[r][p]);
          yacc[r][p] = fmaf(sa[r].a[1], xv[1].a[p], yacc[r][p]);
          yacc[r][p] = fmaf(sa[r].a[2], xv[2].a[p], yacc[r][p]);
          yacc[r][p] = fmaf(sa[r].a[3], xv[3].a[p], yacc[r][p]);
        }
    }
    __syncthreads();
  }

#pragma unroll
  for (int r = 0; r < 4; ++r) {
    float* yp = ybuf + (size_t)(b * L_ + l0 + i0 + r) * DIN + h * HD + j0;
    *(float4*)yp = make_float4(yacc[r][0], yacc[r][1], yacc[r][2], yacc[r][3]);
  }

  // Wsum[b][c][h][n][p] = sum_j w1[j] x[j][p] K[j][n] + w2[j] xp[j][p] Kp[j][n]
  {
    const int p0 = (t & 15) << 2;
    const int n0 = (t >> 4) << 3;
    float acc2[8][4];
#pragma unroll
    for (int s = 0; s < 8; ++s)
#pragma unroll
      for (int r = 0; r < 4; ++r) acc2[s][r] = 0.0f;

    for (int j = 0; j < 64; ++j) {
      float w1 = w1s[j], w2 = w2s[j];
      F4 xv, xpv, kv0, kv1, kp0, kp1;
      xv.v  = *(const float4*)&xxs[j + 1][p0];
      xpv.v = *(const float4*)&xxs[j][p0];
      kv0.v = *(const float4*)&Kxs[j + 1][n0];
      kv1.v = *(const float4*)&Kxs[j + 1][n0 + 4];
      kp0.v = *(const float4*)&Kxs[j][n0];
      kp1.v = *(const float4*)&Kxs[j][n0 + 4];
      float t1[4], t2[4];
#pragma unroll
      for (int r = 0; r < 4; ++r) { t1[r] = w1 * xv.a[r]; t2[r] = w2 * xpv.a[r]; }
      float kva[8], kpa[8];
#pragma unroll
      for (int s = 0; s < 4; ++s) { kva[s] = kv0.a[s]; kva[s + 4] = kv1.a[s]; kpa[s] = kp0.a[s]; kpa[s + 4] = kp1.a[s]; }
#pragma unroll
      for (int s = 0; s < 8; ++s)
#pragma unroll
        for (int r = 0; r < 4; ++r) {
          acc2[s][r] = fmaf(t1[r], kva[s], acc2[s][r]);
          acc2[s][r] = fmaf(t2[r], kpa[s], acc2[s][r]);
        }
    }
    size_t wbase = ((size_t)(b * NC + c) * NH + h) * (size_t)(NST * HD);
#pragma unroll
    for (int s = 0; s < 8; ++s)
      *(float4*)(Wsum + wbase + (size_t)(n0 + s) * HD + p0) =
          make_float4(acc2[s][0], acc2[s][1], acc2[s][2], acc2[s][3]);
  }
}

// ---------------- P5: sequential scan over chunks, Hprev stored in place of Wsum ----------------
__global__ __launch_bounds__(256) void state_scan_kernel(
    float* __restrict__ Wsum, const float* __restrict__ cdg) {
  const int b = blockIdx.x >> 5;
  const int h = blockIdx.x & 31;
  float Hst[32];
#pragma unroll
  for (int k = 0; k < 32; ++k) Hst[k] = 0.0f;
  for (int c = 0; c < NC; ++c) {
    float cd = cdg[((size_t)b * NC + c) * NH + h];
    float* wp = Wsum + ((size_t)(b * NC + c) * NH + h) * (size_t)(NST * HD);
#pragma unroll
    for (int k = 0; k < 32; ++k) {
      int e = threadIdx.x + k * 256;
      float w  = wp[e];
      float hv = Hst[k];
      wp[e]    = hv;             // store Hprev (state before this chunk)
      Hst[k]   = fmaf(cd, hv, w);
    }
  }
}

// ---------------- P6: y = (y_intra + exp(ell)*Q.Hprev^T + D*x) * silu(z) ----------------
__global__ __launch_bounds__(256) void finalize_kernel(
    const float* __restrict__ proj, const float* __restrict__ Cn,
    const float* __restrict__ theta, const float* __restrict__ C_bias,
    const float* __restrict__ Hprev, const float* __restrict__ adtg,
    const float* __restrict__ dvec, float* __restrict__ ybuf) {
  const int h  = blockIdx.x & 31;
  const int c  = (blockIdx.x >> 5) & 31;
  const int b  = blockIdx.x >> 10;
  const int t  = threadIdx.x;
  const int l0 = c * CHK;

  __shared__ float Qs[64][132];
  __shared__ float Hs[128][68];
  __shared__ float ell[64];

  // stage Q raw = Cn(row l0+i) + C_bias[h]
#pragma unroll
  for (int k = 0; k < 8; ++k) {
    int f = t + k * 256;
    int i = f >> 5, n = (f & 31) << 2;
    F4 v, bb;
    v.v  = *(const float4*)(Cn + (size_t)(b * L_ + l0 + i) * NST + n);
    bb.v = *(const float4*)(C_bias + h * NST + n);
#pragma unroll
    for (int q = 0; q < 4; ++q) v.a[q] += bb.a[q];
    *(float4*)&Qs[i][n] = v.v;
  }
  {
    const float* hp = Hprev + ((size_t)(b * NC + c) * NH + h) * (size_t)(NST * HD);
#pragma unroll
    for (int k = 0; k < 8; ++k) {
      int f = t + k * 256;
      int n = f >> 4, p = (f & 15) << 2;
      *(float4*)&Hs[n][p] = *(const float4*)(hp + (size_t)n * HD + p);
    }
  }
  if (t < 64) {
    float v = adtg[((size_t)b * NH + h) * L_ + l0 + t];
#pragma unroll
    for (int off = 1; off < 64; off <<= 1) {
      float u = __shfl_up(v, off, 64);
      if (t >= off) v += u;
    }
    ell[t] = v;
  }
  __syncthreads();

  // rope Q in place: pair (i, na), theta row l0+i
#pragma unroll
  for (int k = 0; k < 8; ++k) {
    int f = t + k * 256;
    int i = f >> 5, na = f & 31;
    float th = theta[((size_t)(b * L_ + l0 + i) * NH + h) * NA + na];
    float sn, cs;
    sincosf(th, &sn, &cs);
    float q1 = Qs[i][na], q2 = Qs[i][na + 32];
    Qs[i][na]      = q1 * cs - q2 * sn;
    Qs[i][na + 32] = q1 * sn + q2 * cs;
  }
  __syncthreads();

  const int i0 = (t >> 4) << 2, p0 = (t & 15) << 2;
  float acc[4][4];
#pragma unroll
  for (int r = 0; r < 4; ++r)
#pragma unroll
    for (int p = 0; p < 4; ++p) acc[r][p] = 0.0f;

  for (int n4 = 0; n4 < 32; ++n4) {
    F4 qa[4], hb[4];
#pragma unroll
    for (int r = 0; r < 4; ++r)  qa[r].v = *(const float4*)&Qs[i0 + r][n4 << 2];
#pragma unroll
    for (int nn = 0; nn < 4; ++nn) hb[nn].v = *(const float4*)&Hs[(n4 << 2) + nn][p0];
#pragma unroll
    for (int r = 0; r < 4; ++r)
#pragma unroll
      for (int p = 0; p < 4; ++p) {
        acc[r][p] = fmaf(qa[r].a[0], hb[0].a[p], acc[r][p]);
        acc[r][p] = fmaf(qa[r].a[1], hb[1].a[p], acc[r][p]);
        acc[r][p] = fmaf(qa[r].a[2], hb[2].a[p], acc[r][p]);
        acc[r][p] = fmaf(qa[r].a[3], hb[3].a[p], acc[r][p]);
      }
  }

  const float Dv = dvec[h];
#pragma unroll
  for (int r = 0; r < 4; ++r) {
    const int l = l0 + i0 + r;
    const float e = expf(ell[i0 + r]);
    const size_t rowoff = (size_t)(b * L_ + l);
    F4 yi, xv, zv, o;
    yi.v = *(float4*)(ybuf + rowoff * DIN + h * HD + p0);
    xv.v = *(const float4*)(proj + rowoff * DPROJ + OFF_X + h * HD + p0);
    zv.v = *(const float4*)(proj + rowoff * DPROJ + OFF_Z + h * HD + p0);
#pragma unroll
    for (int p = 0; p < 4; ++p) {
      float z = zv.a[p];
      o.a[p] = (yi.a[p] + e * acc[r][p] + Dv * xv.a[p]) * (z * sigmoidf_(z));
    }
    *(float4*)(ybuf + rowoff * DIN + h * HD + p0) = o.v;
  }
}

// ---------------- fallback: clean wrong-answer instead of OOB fault ----------------
__global__ void zero_out_kernel(float* __restrict__ out, int n) {
  int i = blockIdx.x * 256 + threadIdx.x;
  if (i < n) out[i] = 0.0f;
}

extern "C" void kernel_launch(void* const* d_in, const int* in_sizes, int n_in,
                              void* d_out, int out_size, void* d_ws, size_t ws_size,
                              hipStream_t stream) {
  const float* u        = (const float*)d_in[0];
  const float* W_in     = (const float*)d_in[1];
  const float* W_out    = (const float*)d_in[2];
  const float* dt_bias  = (const float*)d_in[3];
  const float* B_bias   = (const float*)d_in[4];
  const float* C_bias   = (const float*)d_in[5];
  const float* B_norm_w = (const float*)d_in[6];
  const float* C_norm_w = (const float*)d_in[7];
  const float* Dv       = (const float*)d_in[8];
  float* out = (float*)d_out;
  float* ws  = (float*)d_ws;

  size_t o = 0;
  float* proj  = ws + o; o += (size_t)B_ * L_ * DPROJ;          // 18,350,080
  float* Bn    = ws + o; o += (size_t)B_ * L_ * NST;            //    524,288
  float* Cn    = ws + o; o += (size_t)B_ * L_ * NST;
  float* dtg   = ws + o; o += (size_t)B_ * NH * L_;             //    131,072 x4
  float* adtg  = ws + o; o += (size_t)B_ * NH * L_;
  float* g1g   = ws + o; o += (size_t)B_ * NH * L_;
  float* g2g   = ws + o; o += (size_t)B_ * NH * L_;
  float* theta = ws + o; o += (size_t)B_ * L_ * NH * NA;        //  4,194,304
  float* Wsum  = ws + o; o += (size_t)B_ * NC * NH * NST * HD;  // 16,777,216 (Hprev after scan)
  float* cdg   = ws + o; o += (size_t)B_ * NC * NH;
  float* ybuf  = ws + o; o += (size_t)B_ * L_ * DIN;            //  8,388,608
  // total: 49,285,120 floats = ~188 MB

  if (ws_size < o * sizeof(float)) {
    // workspace too small: produce deterministic zeros (clean failure, not a GPU fault)
    zero_out_kernel<<<(out_size + 255) / 256, 256, 0, stream>>>(out, out_size);
    return;
  }

  gemm_f32_128<<<dim3(DPROJ / 128, (B_ * L_) / 128), 256, 0, stream>>>(
      u, W_in, proj, B_ * L_, DPROJ, DM);
  pointwise_kernel<<<B_ * L_, 128, 0, stream>>>(
      proj, dt_bias, B_norm_w, C_norm_w, Bn, Cn, dtg, adtg, g1g, g2g);
  theta_kernel<<<B_ * NH, 64, 0, stream>>>(proj, dtg, theta);
  chunk_kernel<<<B_ * NC * NH, 256, 0, stream>>>(
      proj, Bn, Cn, theta, B_bias, C_bias, adtg, g1g, g2g, Wsum, cdg, ybuf);
  state_scan_kernel<<<B_ * NH, 256, 0, stream>>>(Wsum, cdg);
  finalize_kernel<<<B_ * NC * NH, 256, 0, stream>>>(
      proj, Cn, theta, C_bias, Wsum, adtg, Dv, ybuf);
  gemm_f32_128<<<dim3(DM / 128, (B_ * L_) / 128), 256, 0, stream>>>(
      ybuf, W_out, out, B_ * L_, DM, DIN);
}

// Round 3
// 864.245 us; speedup vs baseline: 1.4762x; 1.4762x over previous
//
#include <hip/hip_runtime.h>
#include <math.h>

#define B_    2
#define L_    2048
#define DM    1024
#define DIN   2048
#define NH    32
#define HD    64
#define NST   128
#define NA    32
#define NC    32
#define CHK   64
#define DPROJ 4480

#define OFF_Z    0
#define OFF_X    2048
#define OFF_BG   4096
#define OFF_CG   4224
#define OFF_DDT  4352
#define OFF_DDA  4384
#define OFF_TRAP 4416
#define OFF_ANG  4448

typedef union { float4 v; float a[4]; } F4;
typedef unsigned short ushort_t;
typedef __attribute__((ext_vector_type(8))) short bf16x8;
typedef __attribute__((ext_vector_type(4))) float f32x4;
typedef union { bf16x8 v; ushort_t u[8]; uint4 q; } BF8;

__device__ __forceinline__ float softplusf_(float x) {
  return (x > 20.0f) ? x : log1pf(expf(x));
}
__device__ __forceinline__ float sigmoidf_(float x) {
  return 1.0f / (1.0f + expf(-x));
}
__device__ __forceinline__ ushort_t f2bf(float x) {
  union { float f; unsigned u; } v; v.f = x;
  unsigned r = v.u + 0x7fffu + ((v.u >> 16) & 1u);
  return (ushort_t)(r >> 16);
}
__device__ __forceinline__ float bf2f(ushort_t h) {
  union { unsigned u; float f; } v; v.u = ((unsigned)h) << 16;
  return v.f;
}
// XOR-swizzled LDS byte offset for a [128][32] bf16 tile (64B row stride)
__device__ __forceinline__ int lds_off(int r, int cbyte) {
  return ((r << 6) + cbyte) ^ ((r & 7) << 4);
}

// ---------------- transpose+split: src[Kd][Nd] f32 -> hi/lo [Nd][Kd] bf16 ----------------
__global__ __launch_bounds__(256) void tsplit_kernel(
    const float* __restrict__ src, ushort_t* __restrict__ hi,
    ushort_t* __restrict__ lo, int Kd, int Nd) {
  __shared__ float tile[64][65];
  const int k0 = blockIdx.y * 64, n0 = blockIdx.x * 64;
  const int t = threadIdx.x;
  {
    const int r = t >> 4, c4 = (t & 15) << 2;
#pragma unroll
    for (int rr = 0; rr < 4; ++rr) {
      F4 v; v.v = *(const float4*)(src + (size_t)(k0 + r + rr * 16) * Nd + n0 + c4);
      tile[r + rr * 16][c4] = v.a[0]; tile[r + rr * 16][c4 + 1] = v.a[1];
      tile[r + rr * 16][c4 + 2] = v.a[2]; tile[r + rr * 16][c4 + 3] = v.a[3];
    }
  }
  __syncthreads();
  const int n = t >> 2, kc = (t & 3) << 4;
  BF8 h0, h1, l0, l1;
#pragma unroll
  for (int e = 0; e < 8; ++e) {
    float x = tile[kc + e][n];
    ushort_t h = f2bf(x); h0.u[e] = h; l0.u[e] = f2bf(x - bf2f(h));
    float y = tile[kc + 8 + e][n];
    ushort_t g = f2bf(y); h1.u[e] = g; l1.u[e] = f2bf(y - bf2f(g));
  }
  size_t ob = (size_t)(n0 + n) * Kd + k0 + kc;
  *(uint4*)(hi + ob) = h0.q; *(uint4*)(hi + ob + 8) = h1.q;
  *(uint4*)(lo + ob) = l0.q; *(uint4*)(lo + ob + 8) = l1.q;
}

// ---------------- split-bf16 x3 MFMA GEMM: C[M][N] = A[M][K](f32) * Bt[N][K](bf16 hi/lo) ----------------
__global__ __launch_bounds__(256) void gemm_s3(
    const float* __restrict__ A, const ushort_t* __restrict__ Bth,
    const ushort_t* __restrict__ Btl, float* __restrict__ C,
    int M, int N, int K) {
  __shared__ char ldsA_h[8192], ldsA_l[8192], ldsB_h[8192], ldsB_l[8192];
  const int t  = threadIdx.x;
  const int bm = blockIdx.y * 128, bn = blockIdx.x * 128;
  const int row = t >> 1, khe = (t & 1) << 4;     // element offset 0/16
  const int khb = khe << 1;                       // byte offset 0/32
  const int w = t >> 6, lane = t & 63;
  const int wm = (w >> 1) << 6, wn = (w & 1) << 6;
  const int lr = lane & 15, lkb = ((lane >> 4) << 3) << 1;  // k-byte offset 0/16/32/48

  f32x4 acc[4][4];
#pragma unroll
  for (int i = 0; i < 4; ++i)
#pragma unroll
    for (int j = 0; j < 4; ++j) acc[i][j] = (f32x4){0.f, 0.f, 0.f, 0.f};

  const float* ap = A + (size_t)(bm + row) * K + khe;
  const ushort_t* bhp = Bth + (size_t)(bn + row) * K + khe;
  const ushort_t* blp = Btl + (size_t)(bn + row) * K + khe;

  for (int k0 = 0; k0 < K; k0 += 32) {
    float av[16];
    *(float4*)&av[0]  = *(const float4*)(ap + k0);
    *(float4*)&av[4]  = *(const float4*)(ap + k0 + 4);
    *(float4*)&av[8]  = *(const float4*)(ap + k0 + 8);
    *(float4*)&av[12] = *(const float4*)(ap + k0 + 12);
    uint4 bh0 = *(const uint4*)(bhp + k0);
    uint4 bh1 = *(const uint4*)(bhp + k0 + 8);
    uint4 bl0 = *(const uint4*)(blp + k0);
    uint4 bl1 = *(const uint4*)(blp + k0 + 8);
    BF8 ah0, ah1, al0, al1;
#pragma unroll
    for (int e = 0; e < 8; ++e) {
      float x = av[e];
      ushort_t h = f2bf(x); ah0.u[e] = h; al0.u[e] = f2bf(x - bf2f(h));
      float y = av[e + 8];
      ushort_t g = f2bf(y); ah1.u[e] = g; al1.u[e] = f2bf(y - bf2f(g));
    }
    __syncthreads();   // previous iteration's LDS reads complete
    *(uint4*)(ldsA_h + lds_off(row, khb))      = ah0.q;
    *(uint4*)(ldsA_h + lds_off(row, khb + 16)) = ah1.q;
    *(uint4*)(ldsA_l + lds_off(row, khb))      = al0.q;
    *(uint4*)(ldsA_l + lds_off(row, khb + 16)) = al1.q;
    *(uint4*)(ldsB_h + lds_off(row, khb))      = bh0;
    *(uint4*)(ldsB_h + lds_off(row, khb + 16)) = bh1;
    *(uint4*)(ldsB_l + lds_off(row, khb))      = bl0;
    *(uint4*)(ldsB_l + lds_off(row, khb + 16)) = bl1;
    __syncthreads();

    bf16x8 a_h[4], a_l[4], b_h[4], b_l[4];
#pragma unroll
    for (int mf = 0; mf < 4; ++mf) {
      a_h[mf] = *(const bf16x8*)(ldsA_h + lds_off(wm + mf * 16 + lr, lkb));
      a_l[mf] = *(const bf16x8*)(ldsA_l + lds_off(wm + mf * 16 + lr, lkb));
    }
#pragma unroll
    for (int nf = 0; nf < 4; ++nf) {
      b_h[nf] = *(const bf16x8*)(ldsB_h + lds_off(wn + nf * 16 + lr, lkb));
      b_l[nf] = *(const bf16x8*)(ldsB_l + lds_off(wn + nf * 16 + lr, lkb));
    }
#pragma unroll
    for (int mf = 0; mf < 4; ++mf)
#pragma unroll
      for (int nf = 0; nf < 4; ++nf) {
        acc[mf][nf] = __builtin_amdgcn_mfma_f32_16x16x32_bf16(a_h[mf], b_h[nf], acc[mf][nf], 0, 0, 0);
        acc[mf][nf] = __builtin_amdgcn_mfma_f32_16x16x32_bf16(a_h[mf], b_l[nf], acc[mf][nf], 0, 0, 0);
        acc[mf][nf] = __builtin_amdgcn_mfma_f32_16x16x32_bf16(a_l[mf], b_h[nf], acc[mf][nf], 0, 0, 0);
      }
  }

  const int rsub = (lane >> 4) << 2;
#pragma unroll
  for (int mf = 0; mf < 4; ++mf)
#pragma unroll
    for (int nf = 0; nf < 4; ++nf) {
      float* cp = C + (size_t)(bm + wm + mf * 16 + rsub) * N + bn + wn + nf * 16 + lr;
#pragma unroll
      for (int j = 0; j < 4; ++j) cp[(size_t)j * N] = acc[mf][nf][j];
    }
}

// ---------------- fallback f32 GEMM (R2 version) ----------------
__global__ __launch_bounds__(256) void gemm_f32_128(
    const float* __restrict__ A, const float* __restrict__ Bm,
    float* __restrict__ C, int M, int N, int K) {
  __shared__ float As[16][132];
  __shared__ float Bs[16][132];
  const int t  = threadIdx.x;
  const int bm = blockIdx.y * 128;
  const int bn = blockIdx.x * 128;
  const int tr = t >> 4, tc = t & 15;
  float acc[8][8];
#pragma unroll
  for (int i = 0; i < 8; ++i)
#pragma unroll
    for (int j = 0; j < 8; ++j) acc[i][j] = 0.0f;
  const int am  = t >> 2, ak  = (t & 3) << 2;
  const int bk  = t >> 5, bn4 = (t & 31) << 2;
  for (int k0 = 0; k0 < K; k0 += 16) {
    float4 a0 = *(const float4*)(A + (size_t)(bm + am) * K + k0 + ak);
    float4 a1 = *(const float4*)(A + (size_t)(bm + am + 64) * K + k0 + ak);
    float4 b0 = *(const float4*)(Bm + (size_t)(k0 + bk) * N + bn + bn4);
    float4 b1 = *(const float4*)(Bm + (size_t)(k0 + bk + 8) * N + bn + bn4);
    As[ak + 0][am] = a0.x; As[ak + 1][am] = a0.y; As[ak + 2][am] = a0.z; As[ak + 3][am] = a0.w;
    As[ak + 0][am + 64] = a1.x; As[ak + 1][am + 64] = a1.y; As[ak + 2][am + 64] = a1.z; As[ak + 3][am + 64] = a1.w;
    *(float4*)&Bs[bk][bn4] = b0;
    *(float4*)&Bs[bk + 8][bn4] = b1;
    __syncthreads();
#pragma unroll
    for (int kk = 0; kk < 16; ++kk) {
      float a[8], b[8];
      *(float4*)&a[0] = *(const float4*)&As[kk][tr * 8];
      *(float4*)&a[4] = *(const float4*)&As[kk][tr * 8 + 4];
      *(float4*)&b[0] = *(const float4*)&Bs[kk][tc * 8];
      *(float4*)&b[4] = *(const float4*)&Bs[kk][tc * 8 + 4];
#pragma unroll
      for (int i = 0; i < 8; ++i)
#pragma unroll
        for (int j = 0; j < 8; ++j)
          acc[i][j] = fmaf(a[i], b[j], acc[i][j]);
    }
    __syncthreads();
  }
#pragma unroll
  for (int i = 0; i < 8; ++i) {
    float* cp = C + (size_t)(bm + tr * 8 + i) * N + bn + tc * 8;
    *(float4*)cp       = *(float4*)&acc[i][0];
    *(float4*)(cp + 4) = *(float4*)&acc[i][4];
  }
}

// ---------------- P2: per-(b,l) pointwise ----------------
__global__ __launch_bounds__(128) void pointwise_kernel(
    const float* __restrict__ proj, const float* __restrict__ dt_bias,
    const float* __restrict__ Bnw, const float* __restrict__ Cnw,
    float* __restrict__ Bn, float* __restrict__ Cn,
    float* __restrict__ dtg, float* __restrict__ adtg,
    float* __restrict__ g1g, float* __restrict__ g2g) {
  const int bl = blockIdx.x;
  const int l  = bl & (L_ - 1);
  const int b  = bl >> 11;
  const int t  = threadIdx.x;
  const float* row = proj + (size_t)bl * DPROJ;

  float vb = row[OFF_BG + t];
  float vc = row[OFF_CG + t];
  float sb = vb * vb, sc = vc * vc;
#pragma unroll
  for (int off = 32; off >= 1; off >>= 1) {
    sb += __shfl_xor(sb, off, 64);
    sc += __shfl_xor(sc, off, 64);
  }
  __shared__ float red[4];
  if ((t & 63) == 0) { red[t >> 6] = sb; red[2 + (t >> 6)] = sc; }
  __syncthreads();
  sb = red[0] + red[1];
  sc = red[2] + red[3];
  float rb = rsqrtf(sb * (1.0f / 128.0f) + 1e-5f);
  float rc = rsqrtf(sc * (1.0f / 128.0f) + 1e-5f);
  Bn[(size_t)bl * NST + t] = vb * rb * Bnw[t];
  Cn[(size_t)bl * NST + t] = vc * rc * Cnw[t];

  if (t < NH) {
    const int h = t;
    float dt = softplusf_(row[OFF_DDT + h] + dt_bias[h]);
    float a  = -softplusf_(row[OFF_DDA + h]);
    a = fminf(a, -1e-4f);
    float adt  = a * dt;
    float beta = sigmoidf_(row[OFF_TRAP + h]);
    float dtp  = 0.0f;
    if (l > 0) dtp = softplusf_(proj[(size_t)(bl - 1) * DPROJ + OFF_DDT + h] + dt_bias[h]);
    float g2 = (1.0f - beta) * expf(adt) * dtp;
    size_t idx = ((size_t)b * NH + h) * L_ + l;
    dtg[idx]  = dt;
    adtg[idx] = adt;
    g1g[idx]  = beta * dt;
    g2g[idx]  = g2;
  }
}

// ---------------- P3: theta cumsum ----------------
__global__ __launch_bounds__(64) void theta_kernel(
    const float* __restrict__ proj, const float* __restrict__ dtg,
    float* __restrict__ theta) {
  const int b  = blockIdx.x >> 5;
  const int h  = blockIdx.x & 31;
  const int na = threadIdx.x;
  if (na >= NA) return;
  const float* ap = proj + (size_t)b * L_ * DPROJ + OFF_ANG + na;
  const float* dp = dtg + ((size_t)b * NH + h) * L_;
  float* tp = theta + ((size_t)b * L_ * NH + h) * NA + na;
  float th = 0.0f;
#pragma unroll 16
  for (int l = 0; l < L_; ++l) {
    th = fmaf(ap[(size_t)l * DPROJ], dp[l], th);
    tp[(size_t)l * NH * NA] = th;
  }
}

// ---------------- P4: chunk kernel ----------------
__global__ __launch_bounds__(256) void chunk_kernel(
    const float* __restrict__ proj,
    const float* __restrict__ Bn, const float* __restrict__ Cn,
    const float* __restrict__ theta,
    const float* __restrict__ B_bias, const float* __restrict__ C_bias,
    const float* __restrict__ adtg, const float* __restrict__ g1g,
    const float* __restrict__ g2g,
    float* __restrict__ Wsum, float* __restrict__ cdg,
    float* __restrict__ ybuf) {
  const int h  = blockIdx.x & 31;
  const int c  = (blockIdx.x >> 5) & 31;
  const int b  = blockIdx.x >> 10;
  const int t  = threadIdx.x;
  const int l0 = c * CHK;

  __shared__ float Qs[64][132];
  __shared__ float Kxs[65][132];
  __shared__ float xxs[65][68];
  __shared__ float Ss[64][68];
  __shared__ float ell[64], g1s[64], g2s[64], w1s[64], w2s[64];

#pragma unroll
  for (int k = 0; k < 8; ++k) {
    int f = t + k * 256;
    int i = f >> 5, n = (f & 31) << 2;
    F4 v, bb;
    v.v  = *(const float4*)(Cn + (size_t)(b * L_ + l0 + i) * NST + n);
    bb.v = *(const float4*)(C_bias + h * NST + n);
#pragma unroll
    for (int q = 0; q < 4; ++q) v.a[q] += bb.a[q];
    *(float4*)&Qs[i][n] = v.v;
  }
#pragma unroll
  for (int k = 0; k < 9; ++k) {
    int f = t + k * 256;
    if (f < 65 * 32) {
      int i = f >> 5, n = (f & 31) << 2;
      F4 v;
      if (i == 0 && c == 0) v.v = make_float4(0.f, 0.f, 0.f, 0.f);
      else {
        F4 bb;
        v.v  = *(const float4*)(Bn + (size_t)(b * L_ + l0 + i - 1) * NST + n);
        bb.v = *(const float4*)(B_bias + h * NST + n);
#pragma unroll
        for (int q = 0; q < 4; ++q) v.a[q] += bb.a[q];
      }
      *(float4*)&Kxs[i][n] = v.v;
    }
  }
#pragma unroll
  for (int k = 0; k < 5; ++k) {
    int f = t + k * 256;
    if (f < 65 * 16) {
      int i = f >> 4, p = (f & 15) << 2;
      float4 v;
      if (i == 0 && c == 0) v = make_float4(0.f, 0.f, 0.f, 0.f);
      else v = *(const float4*)(proj + (size_t)(b * L_ + l0 + i - 1) * DPROJ + OFF_X + h * HD + p);
      *(float4*)&xxs[i][p] = v;
    }
  }
  if (t < 64) {
    size_t idx = ((size_t)b * NH + h) * L_ + l0 + t;
    float adt = adtg[idx];
    float g1  = g1g[idx];
    float g2  = g2g[idx];
    float v = adt;
#pragma unroll
    for (int off = 1; off < 64; off <<= 1) {
      float u = __shfl_up(v, off, 64);
      if (t >= off) v += u;
    }
    ell[t] = v;
    float last = __shfl(v, 63, 64);
    float de = expf(last - v);
    g1s[t] = g1; g2s[t] = g2;
    w1s[t] = g1 * de; w2s[t] = g2 * de;
    if (t == 63) cdg[((size_t)b * NC + c) * NH + h] = expf(v);
  }
  __syncthreads();

#pragma unroll
  for (int k = 0; k < 9; ++k) {
    int f = t + k * 256;
    if (f < 65 * 32) {
      int i = f >> 5, na = f & 31;
      if (!(i == 0 && c == 0)) {
        float th = theta[((size_t)(b * L_ + l0 + i - 1) * NH + h) * NA + na];
        float sn, cs;
        sincosf(th, &sn, &cs);
        float a1 = Kxs[i][na], a2 = Kxs[i][na + 32];
        Kxs[i][na]      = a1 * cs - a2 * sn;
        Kxs[i][na + 32] = a1 * sn + a2 * cs;
        if (i >= 1) {
          float b1 = Qs[i - 1][na], b2 = Qs[i - 1][na + 32];
          Qs[i - 1][na]      = b1 * cs - b2 * sn;
          Qs[i - 1][na + 32] = b1 * sn + b2 * cs;
        }
      }
    }
  }
  __syncthreads();

  const int i0 = (t >> 4) << 2;
  const int j0 = (t & 15) << 2;
  float yacc[4][4];
#pragma unroll
  for (int r = 0; r < 4; ++r)
#pragma unroll
    for (int p = 0; p < 4; ++p) yacc[r][p] = 0.0f;

  float elli[4], ellj[4];
#pragma unroll
  for (int r = 0; r < 4; ++r) elli[r] = ell[i0 + r];
#pragma unroll
  for (int s = 0; s < 4; ++s) ellj[s] = ell[j0 + s];

#pragma unroll 1
  for (int pass = 0; pass < 2; ++pass) {
    const int KOFF = (pass == 0) ? 1 : 0;
    float acc[4][4];
#pragma unroll
    for (int r = 0; r < 4; ++r)
#pragma unroll
      for (int s = 0; s < 4; ++s) acc[r][s] = 0.0f;

    for (int n4 = 0; n4 < 32; ++n4) {
      F4 qa[4], kb[4];
#pragma unroll
      for (int r = 0; r < 4; ++r) qa[r].v = *(const float4*)&Qs[i0 + r][n4 << 2];
#pragma unroll
      for (int s = 0; s < 4; ++s) kb[s].v = *(const float4*)&Kxs[KOFF + j0 + s][n4 << 2];
#pragma unroll
      for (int r = 0; r < 4; ++r)
#pragma unroll
        for (int s = 0; s < 4; ++s) {
          acc[r][s] = fmaf(qa[r].a[0], kb[s].a[0], acc[r][s]);
          acc[r][s] = fmaf(qa[r].a[1], kb[s].a[1], acc[r][s]);
          acc[r][s] = fmaf(qa[r].a[2], kb[s].a[2], acc[r][s]);
          acc[r][s] = fmaf(qa[r].a[3], kb[s].a[3], acc[r][s]);
        }
    }
    const float* gs = (pass == 0) ? g1s : g2s;
#pragma unroll
    for (int r = 0; r < 4; ++r)
#pragma unroll
      for (int s = 0; s < 4; ++s) {
        int i = i0 + r, j = j0 + s;
        float val = 0.0f;
        if (j <= i) val = acc[r][s] * gs[j] * expf(elli[r] - ellj[s]);
        Ss[i][j] = val;
      }
    __syncthreads();

    for (int j4 = 0; j4 < 16; ++j4) {
      F4 sa[4], xv[4];
#pragma unroll
      for (int r = 0; r < 4; ++r)  sa[r].v  = *(const float4*)&Ss[i0 + r][j4 << 2];
#pragma unroll
      for (int jj = 0; jj < 4; ++jj) xv[jj].v = *(const float4*)&xxs[KOFF + (j4 << 2) + jj][j0];
#pragma unroll
      for (int r = 0; r < 4; ++r)
#pragma unroll
        for (int p = 0; p < 4; ++p) {
          yacc[r][p] = fmaf(sa[r].a[0], xv[0].a[p], yacc[r][p]);
          yacc[r][p] = fmaf(sa[r].a[1], xv[1].a[p], yacc[r][p]);
          yacc[r][p] = fmaf(sa[r].a[2], xv[2].a[p], yacc[r][p]);
          yacc[r][p] = fmaf(sa[r].a[3], xv[3].a[p], yacc[r][p]);
        }
    }
    __syncthreads();
  }

#pragma unroll
  for (int r = 0; r < 4; ++r) {
    float* yp = ybuf + (size_t)(b * L_ + l0 + i0 + r) * DIN + h * HD + j0;
    *(float4*)yp = make_float4(yacc[r][0], yacc[r][1], yacc[r][2], yacc[r][3]);
  }

  {
    const int p0 = (t & 15) << 2;
    const int n0 = (t >> 4) << 3;
    float acc2[8][4];
#pragma unroll
    for (int s = 0; s < 8; ++s)
#pragma unroll
      for (int r = 0; r < 4; ++r) acc2[s][r] = 0.0f;

    for (int j = 0; j < 64; ++j) {
      float w1 = w1s[j], w2 = w2s[j];
      F4 xv, xpv, kv0, kv1, kp0, kp1;
      xv.v  = *(const float4*)&xxs[j + 1][p0];
      xpv.v = *(const float4*)&xxs[j][p0];
      kv0.v = *(const float4*)&Kxs[j + 1][n0];
      kv1.v = *(const float4*)&Kxs[j + 1][n0 + 4];
      kp0.v = *(const float4*)&Kxs[j][n0];
      kp1.v = *(const float4*)&Kxs[j][n0 + 4];
      float t1[4], t2[4];
#pragma unroll
      for (int r = 0; r < 4; ++r) { t1[r] = w1 * xv.a[r]; t2[r] = w2 * xpv.a[r]; }
      float kva[8], kpa[8];
#pragma unroll
      for (int s = 0; s < 4; ++s) { kva[s] = kv0.a[s]; kva[s + 4] = kv1.a[s]; kpa[s] = kp0.a[s]; kpa[s + 4] = kp1.a[s]; }
#pragma unroll
      for (int s = 0; s < 8; ++s)
#pragma unroll
        for (int r = 0; r < 4; ++r) {
          acc2[s][r] = fmaf(t1[r], kva[s], acc2[s][r]);
          acc2[s][r] = fmaf(t2[r], kpa[s], acc2[s][r]);
        }
    }
    size_t wbase = ((size_t)(b * NC + c) * NH + h) * (size_t)(NST * HD);
#pragma unroll
    for (int s = 0; s < 8; ++s)
      *(float4*)(Wsum + wbase + (size_t)(n0 + s) * HD + p0) =
          make_float4(acc2[s][0], acc2[s][1], acc2[s][2], acc2[s][3]);
  }
}

// ---------------- P5: state scan ----------------
__global__ __launch_bounds__(256) void state_scan_kernel(
    float* __restrict__ Wsum, const float* __restrict__ cdg) {
  const int b = blockIdx.x >> 5;
  const int h = blockIdx.x & 31;
  float Hst[32];
#pragma unroll
  for (int k = 0; k < 32; ++k) Hst[k] = 0.0f;
  for (int c = 0; c < NC; ++c) {
    float cd = cdg[((size_t)b * NC + c) * NH + h];
    float* wp = Wsum + ((size_t)(b * NC + c) * NH + h) * (size_t)(NST * HD);
#pragma unroll
    for (int k = 0; k < 32; ++k) {
      int e = threadIdx.x + k * 256;
      float w  = wp[e];
      float hv = Hst[k];
      wp[e]    = hv;
      Hst[k]   = fmaf(cd, hv, w);
    }
  }
}

// ---------------- P6: finalize ----------------
__global__ __launch_bounds__(256) void finalize_kernel(
    const float* __restrict__ proj, const float* __restrict__ Cn,
    const float* __restrict__ theta, const float* __restrict__ C_bias,
    const float* __restrict__ Hprev, const float* __restrict__ adtg,
    const float* __restrict__ dvec, float* __restrict__ ybuf) {
  const int h  = blockIdx.x & 31;
  const int c  = (blockIdx.x >> 5) & 31;
  const int b  = blockIdx.x >> 10;
  const int t  = threadIdx.x;
  const int l0 = c * CHK;

  __shared__ float Qs[64][132];
  __shared__ float Hs[128][68];
  __shared__ float ell[64];

#pragma unroll
  for (int k = 0; k < 8; ++k) {
    int f = t + k * 256;
    int i = f >> 5, n = (f & 31) << 2;
    F4 v, bb;
    v.v  = *(const float4*)(Cn + (size_t)(b * L_ + l0 + i) * NST + n);
    bb.v = *(const float4*)(C_bias + h * NST + n);
#pragma unroll
    for (int q = 0; q < 4; ++q) v.a[q] += bb.a[q];
    *(float4*)&Qs[i][n] = v.v;
  }
  {
    const float* hp = Hprev + ((size_t)(b * NC + c) * NH + h) * (size_t)(NST * HD);
#pragma unroll
    for (int k = 0; k < 8; ++k) {
      int f = t + k * 256;
      int n = f >> 4, p = (f & 15) << 2;
      *(float4*)&Hs[n][p] = *(const float4*)(hp + (size_t)n * HD + p);
    }
  }
  if (t < 64) {
    float v = adtg[((size_t)b * NH + h) * L_ + l0 + t];
#pragma unroll
    for (int off = 1; off < 64; off <<= 1) {
      float u = __shfl_up(v, off, 64);
      if (t >= off) v += u;
    }
    ell[t] = v;
  }
  __syncthreads();

#pragma unroll
  for (int k = 0; k < 8; ++k) {
    int f = t + k * 256;
    int i = f >> 5, na = f & 31;
    float th = theta[((size_t)(b * L_ + l0 + i) * NH + h) * NA + na];
    float sn, cs;
    sincosf(th, &sn, &cs);
    float q1 = Qs[i][na], q2 = Qs[i][na + 32];
    Qs[i][na]      = q1 * cs - q2 * sn;
    Qs[i][na + 32] = q1 * sn + q2 * cs;
  }
  __syncthreads();

  const int i0 = (t >> 4) << 2, p0 = (t & 15) << 2;
  float acc[4][4];
#pragma unroll
  for (int r = 0; r < 4; ++r)
#pragma unroll
    for (int p = 0; p < 4; ++p) acc[r][p] = 0.0f;

  for (int n4 = 0; n4 < 32; ++n4) {
    F4 qa[4], hb[4];
#pragma unroll
    for (int r = 0; r < 4; ++r)  qa[r].v = *(const float4*)&Qs[i0 + r][n4 << 2];
#pragma unroll
    for (int nn = 0; nn < 4; ++nn) hb[nn].v = *(const float4*)&Hs[(n4 << 2) + nn][p0];
#pragma unroll
    for (int r = 0; r < 4; ++r)
#pragma unroll
      for (int p = 0; p < 4; ++p) {
        acc[r][p] = fmaf(qa[r].a[0], hb[0].a[p], acc[r][p]);
        acc[r][p] = fmaf(qa[r].a[1], hb[1].a[p], acc[r][p]);
        acc[r][p] = fmaf(qa[r].a[2], hb[2].a[p], acc[r][p]);
        acc[r][p] = fmaf(qa[r].a[3], hb[3].a[p], acc[r][p]);
      }
  }

  const float Dv = dvec[h];
#pragma unroll
  for (int r = 0; r < 4; ++r) {
    const int l = l0 + i0 + r;
    const float e = expf(ell[i0 + r]);
    const size_t rowoff = (size_t)(b * L_ + l);
    F4 yi, xv, zv, o;
    yi.v = *(float4*)(ybuf + rowoff * DIN + h * HD + p0);
    xv.v = *(const float4*)(proj + rowoff * DPROJ + OFF_X + h * HD + p0);
    zv.v = *(const float4*)(proj + rowoff * DPROJ + OFF_Z + h * HD + p0);
#pragma unroll
    for (int p = 0; p < 4; ++p) {
      float z = zv.a[p];
      o.a[p] = (yi.a[p] + e * acc[r][p] + Dv * xv.a[p]) * (z * sigmoidf_(z));
    }
    *(float4*)(ybuf + rowoff * DIN + h * HD + p0) = o.v;
  }
}

__global__ void zero_out_kernel(float* __restrict__ out, int n) {
  int i = blockIdx.x * 256 + threadIdx.x;
  if (i < n) out[i] = 0.0f;
}

extern "C" void kernel_launch(void* const* d_in, const int* in_sizes, int n_in,
                              void* d_out, int out_size, void* d_ws, size_t ws_size,
                              hipStream_t stream) {
  const float* u        = (const float*)d_in[0];
  const float* W_in     = (const float*)d_in[1];
  const float* W_out    = (const float*)d_in[2];
  const float* dt_bias  = (const float*)d_in[3];
  const float* B_bias   = (const float*)d_in[4];
  const float* C_bias   = (const float*)d_in[5];
  const float* B_norm_w = (const float*)d_in[6];
  const float* C_norm_w = (const float*)d_in[7];
  const float* Dv       = (const float*)d_in[8];
  float* out = (float*)d_out;
  float* ws  = (float*)d_ws;

  size_t o = 0;
  float* proj  = ws + o; o += (size_t)B_ * L_ * DPROJ;
  float* Bn    = ws + o; o += (size_t)B_ * L_ * NST;
  float* Cn    = ws + o; o += (size_t)B_ * L_ * NST;
  float* dtg   = ws + o; o += (size_t)B_ * NH * L_;
  float* adtg  = ws + o; o += (size_t)B_ * NH * L_;
  float* g1g   = ws + o; o += (size_t)B_ * NH * L_;
  float* g2g   = ws + o; o += (size_t)B_ * NH * L_;
  float* theta = ws + o; o += (size_t)B_ * L_ * NH * NA;
  float* Wsum  = ws + o; o += (size_t)B_ * NC * NH * NST * HD;
  float* cdg   = ws + o; o += (size_t)B_ * NC * NH;
  float* ybuf  = ws + o; o += (size_t)B_ * L_ * DIN;
  const size_t base_floats = o;                         // 49,285,120 (~188 MB, proven)
  // bf16 split+transposed weights
  ushort_t* Wth = (ushort_t*)(ws + o); o += (size_t)DPROJ * DM / 2;   // 4480x1024
  ushort_t* Wtl = (ushort_t*)(ws + o); o += (size_t)DPROJ * DM / 2;
  ushort_t* Woh = (ushort_t*)(ws + o); o += (size_t)DM * DIN / 2;     // 1024x2048
  ushort_t* Wol = (ushort_t*)(ws + o); o += (size_t)DM * DIN / 2;
  const bool mfma_ok = (ws_size >= o * sizeof(float));

  if (ws_size < base_floats * sizeof(float)) {
    zero_out_kernel<<<(out_size + 255) / 256, 256, 0, stream>>>(out, out_size);
    return;
  }

  if (mfma_ok) {
    tsplit_kernel<<<dim3(DPROJ / 64, DM / 64), 256, 0, stream>>>(W_in, Wth, Wtl, DM, DPROJ);
    tsplit_kernel<<<dim3(DM / 64, DIN / 64), 256, 0, stream>>>(W_out, Woh, Wol, DIN, DM);
    gemm_s3<<<dim3(DPROJ / 128, (B_ * L_) / 128), 256, 0, stream>>>(
        u, Wth, Wtl, proj, B_ * L_, DPROJ, DM);
  } else {
    gemm_f32_128<<<dim3(DPROJ / 128, (B_ * L_) / 128), 256, 0, stream>>>(
        u, W_in, proj, B_ * L_, DPROJ, DM);
  }
  pointwise_kernel<<<B_ * L_, 128, 0, stream>>>(
      proj, dt_bias, B_norm_w, C_norm_w, Bn, Cn, dtg, adtg, g1g, g2g);
  theta_kernel<<<B_ * NH, 64, 0, stream>>>(proj, dtg, theta);
  chunk_kernel<<<B_ * NC * NH, 256, 0, stream>>>(
      proj, Bn, Cn, theta, B_bias, C_bias, adtg, g1g, g2g, Wsum, cdg, ybuf);
  state_scan_kernel<<<B_ * NH, 256, 0, stream>>>(Wsum, cdg);
  finalize_kernel<<<B_ * NC * NH, 256, 0, stream>>>(
      proj, Cn, theta, C_bias, Wsum, adtg, Dv, ybuf);
  if (mfma_ok) {
    gemm_s3<<<dim3(DM / 128, (B_ * L_) / 128), 256, 0, stream>>>(
        ybuf, Woh, Wol, out, B_ * L_, DM, DIN);
  } else {
    gemm_f32_128<<<dim3(DM / 128, (B_ * L_) / 128), 256, 0, stream>>>(
        ybuf, W_out, out, B_ * L_, DM, DIN);
  }
}

// Round 4
// 712.540 us; speedup vs baseline: 1.7905x; 1.2129x over previous
//
#include <hip/hip_runtime.h>
#include <math.h>

#define B_    2
#define L_    2048
#define DM    1024
#define DIN   2048
#define NH    32
#define HD    64
#define NST   128
#define NA    32
#define NC    32
#define CHK   64
#define DPROJ 4480

#define OFF_Z    0
#define OFF_X    2048
#define OFF_BG   4096
#define OFF_CG   4224
#define OFF_DDT  4352
#define OFF_DDA  4384
#define OFF_TRAP 4416
#define OFF_ANG  4448

typedef union { float4 v; float a[4]; } F4;
typedef unsigned short ushort_t;
typedef __attribute__((ext_vector_type(8))) short bf16x8;
typedef __attribute__((ext_vector_type(4))) float f32x4;
typedef union { bf16x8 v; ushort_t u[8]; uint4 q; } BF8;

__device__ __forceinline__ float softplusf_(float x) {
  return (x > 20.0f) ? x : log1pf(expf(x));
}
__device__ __forceinline__ float sigmoidf_(float x) {
  return 1.0f / (1.0f + expf(-x));
}
__device__ __forceinline__ ushort_t f2bf(float x) {
  union { float f; unsigned u; } v; v.f = x;
  unsigned r = v.u + 0x7fffu + ((v.u >> 16) & 1u);
  return (ushort_t)(r >> 16);
}
__device__ __forceinline__ float bf2f(ushort_t h) {
  union { unsigned u; float f; } v; v.u = ((unsigned)h) << 16;
  return v.f;
}
// XOR-swizzled LDS access; stride must be a multiple of 128B so the XOR stays row-local
__device__ __forceinline__ bf16x8 ldf(const char* base, int row, int stride, int cb) {
  return *(const bf16x8*)(base + row * stride + (cb ^ ((row & 7) << 4)));
}
__device__ __forceinline__ void st_bf16(char* base, int row, int stride, int colb, ushort_t v) {
  *(ushort_t*)(base + row * stride + (colb ^ ((row & 7) << 4))) = v;
}

// ---------------- transpose+split: src[Kd][Nd] f32 -> hi/lo [Nd][Kd] bf16 ----------------
__global__ __launch_bounds__(256) void tsplit_kernel(
    const float* __restrict__ src, ushort_t* __restrict__ hi,
    ushort_t* __restrict__ lo, int Kd, int Nd) {
  __shared__ float tile[64][65];
  const int k0 = blockIdx.y * 64, n0 = blockIdx.x * 64;
  const int t = threadIdx.x;
  {
    const int r = t >> 4, c4 = (t & 15) << 2;
#pragma unroll
    for (int rr = 0; rr < 4; ++rr) {
      F4 v; v.v = *(const float4*)(src + (size_t)(k0 + r + rr * 16) * Nd + n0 + c4);
      tile[r + rr * 16][c4] = v.a[0]; tile[r + rr * 16][c4 + 1] = v.a[1];
      tile[r + rr * 16][c4 + 2] = v.a[2]; tile[r + rr * 16][c4 + 3] = v.a[3];
    }
  }
  __syncthreads();
  const int n = t >> 2, kc = (t & 3) << 4;
  BF8 h0, h1, l0, l1;
#pragma unroll
  for (int e = 0; e < 8; ++e) {
    float x = tile[kc + e][n];
    ushort_t h = f2bf(x); h0.u[e] = h; l0.u[e] = f2bf(x - bf2f(h));
    float y = tile[kc + 8 + e][n];
    ushort_t g = f2bf(y); h1.u[e] = g; l1.u[e] = f2bf(y - bf2f(g));
  }
  size_t ob = (size_t)(n0 + n) * Kd + k0 + kc;
  *(uint4*)(hi + ob) = h0.q; *(uint4*)(hi + ob + 8) = h1.q;
  *(uint4*)(lo + ob) = l0.q; *(uint4*)(lo + ob + 8) = l1.q;
}

// ---------------- split-bf16 x3 MFMA GEMM ----------------
__global__ __launch_bounds__(256) void gemm_s3(
    const float* __restrict__ A, const ushort_t* __restrict__ Bth,
    const ushort_t* __restrict__ Btl, float* __restrict__ C,
    int M, int N, int K) {
  __shared__ char ldsA_h[8192], ldsA_l[8192], ldsB_h[8192], ldsB_l[8192];
  const int t  = threadIdx.x;
  const int bm = blockIdx.y * 128, bn = blockIdx.x * 128;
  const int row = t >> 1, khe = (t & 1) << 4;
  const int khb = khe << 1;
  const int w = t >> 6, lane = t & 63;
  const int wm = (w >> 1) << 6, wn = (w & 1) << 6;
  const int lr = lane & 15, lkb = ((lane >> 4) << 3) << 1;

  f32x4 acc[4][4];
#pragma unroll
  for (int i = 0; i < 4; ++i)
#pragma unroll
    for (int j = 0; j < 4; ++j) acc[i][j] = (f32x4){0.f, 0.f, 0.f, 0.f};

  const float* ap = A + (size_t)(bm + row) * K + khe;
  const ushort_t* bhp = Bth + (size_t)(bn + row) * K + khe;
  const ushort_t* blp = Btl + (size_t)(bn + row) * K + khe;

  for (int k0 = 0; k0 < K; k0 += 32) {
    float av[16];
    *(float4*)&av[0]  = *(const float4*)(ap + k0);
    *(float4*)&av[4]  = *(const float4*)(ap + k0 + 4);
    *(float4*)&av[8]  = *(const float4*)(ap + k0 + 8);
    *(float4*)&av[12] = *(const float4*)(ap + k0 + 12);
    uint4 bh0 = *(const uint4*)(bhp + k0);
    uint4 bh1 = *(const uint4*)(bhp + k0 + 8);
    uint4 bl0 = *(const uint4*)(blp + k0);
    uint4 bl1 = *(const uint4*)(blp + k0 + 8);
    BF8 ah0, ah1, al0, al1;
#pragma unroll
    for (int e = 0; e < 8; ++e) {
      float x = av[e];
      ushort_t h = f2bf(x); ah0.u[e] = h; al0.u[e] = f2bf(x - bf2f(h));
      float y = av[e + 8];
      ushort_t g = f2bf(y); ah1.u[e] = g; al1.u[e] = f2bf(y - bf2f(g));
    }
    __syncthreads();
    *(uint4*)(ldsA_h + ((row << 6) + khb       ^ ((row & 7) << 4))) = ah0.q;
    *(uint4*)(ldsA_h + ((row << 6) + khb + 16  ^ ((row & 7) << 4))) = ah1.q;
    *(uint4*)(ldsA_l + ((row << 6) + khb       ^ ((row & 7) << 4))) = al0.q;
    *(uint4*)(ldsA_l + ((row << 6) + khb + 16  ^ ((row & 7) << 4))) = al1.q;
    *(uint4*)(ldsB_h + ((row << 6) + khb       ^ ((row & 7) << 4))) = bh0;
    *(uint4*)(ldsB_h + ((row << 6) + khb + 16  ^ ((row & 7) << 4))) = bh1;
    *(uint4*)(ldsB_l + ((row << 6) + khb       ^ ((row & 7) << 4))) = bl0;
    *(uint4*)(ldsB_l + ((row << 6) + khb + 16  ^ ((row & 7) << 4))) = bl1;
    __syncthreads();

    bf16x8 a_h[4], a_l[4], b_h[4], b_l[4];
#pragma unroll
    for (int mf = 0; mf < 4; ++mf) {
      a_h[mf] = ldf(ldsA_h, wm / 16 * 16 + mf * 16 + lr - wm + wm, 64, lkb); // placeholder avoided below
    }
    // (use explicit swizzled reads)
#pragma unroll
    for (int mf = 0; mf < 4; ++mf) {
      int r2 = wm + mf * 16 + lr;
      a_h[mf] = *(const bf16x8*)(ldsA_h + ((r2 << 6) + lkb ^ ((r2 & 7) << 4)));
      a_l[mf] = *(const bf16x8*)(ldsA_l + ((r2 << 6) + lkb ^ ((r2 & 7) << 4)));
    }
#pragma unroll
    for (int nf = 0; nf < 4; ++nf) {
      int r2 = wn + nf * 16 + lr;
      b_h[nf] = *(const bf16x8*)(ldsB_h + ((r2 << 6) + lkb ^ ((r2 & 7) << 4)));
      b_l[nf] = *(const bf16x8*)(ldsB_l + ((r2 << 6) + lkb ^ ((r2 & 7) << 4)));
    }
#pragma unroll
    for (int mf = 0; mf < 4; ++mf)
#pragma unroll
      for (int nf = 0; nf < 4; ++nf) {
        acc[mf][nf] = __builtin_amdgcn_mfma_f32_16x16x32_bf16(a_h[mf], b_h[nf], acc[mf][nf], 0, 0, 0);
        acc[mf][nf] = __builtin_amdgcn_mfma_f32_16x16x32_bf16(a_h[mf], b_l[nf], acc[mf][nf], 0, 0, 0);
        acc[mf][nf] = __builtin_amdgcn_mfma_f32_16x16x32_bf16(a_l[mf], b_h[nf], acc[mf][nf], 0, 0, 0);
      }
  }

  const int rsub = (lane >> 4) << 2;
#pragma unroll
  for (int mf = 0; mf < 4; ++mf)
#pragma unroll
    for (int nf = 0; nf < 4; ++nf) {
      float* cp = C + (size_t)(bm + wm + mf * 16 + rsub) * N + bn + wn + nf * 16 + lr;
#pragma unroll
      for (int j = 0; j < 4; ++j) cp[(size_t)j * N] = acc[mf][nf][j];
    }
}

// ---------------- P2: per-(b,l) pointwise ----------------
__global__ __launch_bounds__(128) void pointwise_kernel(
    const float* __restrict__ proj, const float* __restrict__ dt_bias,
    const float* __restrict__ Bnw, const float* __restrict__ Cnw,
    float* __restrict__ Bn, float* __restrict__ Cn,
    float* __restrict__ dtg, float* __restrict__ adtg,
    float* __restrict__ g1g, float* __restrict__ g2g) {
  const int bl = blockIdx.x;
  const int l  = bl & (L_ - 1);
  const int b  = bl >> 11;
  const int t  = threadIdx.x;
  const float* row = proj + (size_t)bl * DPROJ;

  float vb = row[OFF_BG + t];
  float vc = row[OFF_CG + t];
  float sb = vb * vb, sc = vc * vc;
#pragma unroll
  for (int off = 32; off >= 1; off >>= 1) {
    sb += __shfl_xor(sb, off, 64);
    sc += __shfl_xor(sc, off, 64);
  }
  __shared__ float red[4];
  if ((t & 63) == 0) { red[t >> 6] = sb; red[2 + (t >> 6)] = sc; }
  __syncthreads();
  sb = red[0] + red[1];
  sc = red[2] + red[3];
  float rb = rsqrtf(sb * (1.0f / 128.0f) + 1e-5f);
  float rc = rsqrtf(sc * (1.0f / 128.0f) + 1e-5f);
  Bn[(size_t)bl * NST + t] = vb * rb * Bnw[t];
  Cn[(size_t)bl * NST + t] = vc * rc * Cnw[t];

  if (t < NH) {
    const int h = t;
    float dt = softplusf_(row[OFF_DDT + h] + dt_bias[h]);
    float a  = -softplusf_(row[OFF_DDA + h]);
    a = fminf(a, -1e-4f);
    float adt  = a * dt;
    float beta = sigmoidf_(row[OFF_TRAP + h]);
    float dtp  = 0.0f;
    if (l > 0) dtp = softplusf_(proj[(size_t)(bl - 1) * DPROJ + OFF_DDT + h] + dt_bias[h]);
    float g2 = (1.0f - beta) * expf(adt) * dtp;
    size_t idx = ((size_t)b * NH + h) * L_ + l;
    dtg[idx]  = dt;
    adtg[idx] = adt;
    g1g[idx]  = beta * dt;
    g2g[idx]  = g2;
  }
}

// ---------------- P3: theta cumsum ----------------
__global__ __launch_bounds__(64) void theta_kernel(
    const float* __restrict__ proj, const float* __restrict__ dtg,
    float* __restrict__ theta) {
  const int b  = blockIdx.x >> 5;
  const int h  = blockIdx.x & 31;
  const int na = threadIdx.x;
  if (na >= NA) return;
  const float* ap = proj + (size_t)b * L_ * DPROJ + OFF_ANG + na;
  const float* dp = dtg + ((size_t)b * NH + h) * L_;
  float* tp = theta + ((size_t)b * L_ * NH + h) * NA + na;
  float th = 0.0f;
#pragma unroll 16
  for (int l = 0; l < L_; ++l) {
    th = fmaf(ap[(size_t)l * DPROJ], dp[l], th);
    tp[(size_t)l * NH * NA] = th;
  }
}

// ---------------- P4: MFMA chunk kernel (512 threads) ----------------
__global__ __launch_bounds__(512, 1) void chunk_kernel(
    const float* __restrict__ proj,
    const float* __restrict__ Bn, const float* __restrict__ Cn,
    const float* __restrict__ theta,
    const float* __restrict__ B_bias, const float* __restrict__ C_bias,
    const float* __restrict__ adtg, const float* __restrict__ g1g,
    const float* __restrict__ g2g,
    float* __restrict__ WsT, float* __restrict__ cdg,
    float* __restrict__ ybuf) {
  const int h  = blockIdx.x & 31;
  const int c  = (blockIdx.x >> 5) & 31;
  const int b  = blockIdx.x >> 10;
  const int t  = threadIdx.x;
  const int l0 = c * CHK;

  __shared__ __align__(16) char QbH[16384], QbL[16384];     // [64][128] bf16 swz
  __shared__ __align__(16) char KbH[16640], KbL[16640];     // [65][128] bf16 swz (row i = l0+i-1)
  __shared__ __align__(16) char KTwH[16384], KTwL[16384];   // [128][64] bf16 swz (cw-weighted K^T)
  __shared__ __align__(16) char xT0H[8192], xT0L[8192];     // [64][64] bf16 swz : xp (col j')
  __shared__ __align__(16) char xT1H[8192], xT1L[8192];     // [64][64] bf16 swz : x  (col j)
  __shared__ __align__(16) char Ubuf[17680];                // union: xxs f32 [65][68] / Sb hi+lo
  __shared__ float ell[64], g1s[64], g2s[64], w1s[64], cw[64], xtail[64], ktail[128];
  float (*xxs)[68] = (float(*)[68])Ubuf;
  char* SbH = Ubuf;
  char* SbL = Ubuf + 8192;

  // ---------- phase 1 ----------
  if (t < 64) {
    size_t idx = ((size_t)b * NH + h) * L_ + l0 + t;
    float adt = adtg[idx], g1 = g1g[idx], g2 = g2g[idx];
    float v = adt;
#pragma unroll
    for (int off = 1; off < 64; off <<= 1) {
      float u = __shfl_up(v, off, 64);
      if (t >= off) v += u;
    }
    ell[t] = v;
    float last = __shfl(v, 63, 64);
    float de = expf(last - v);
    float w1 = g1 * de, w2 = g2 * de;
    g1s[t] = g1; g2s[t] = g2; w1s[t] = w1;
    float w1p = __shfl_up(w1, 1, 64);
    cw[t] = (t >= 1 ? w1p : 0.0f) + w2;
    if (t == 63) cdg[((size_t)b * NC + c) * NH + h] = expf(v);
  }
  // Q rope (elems 0..63) -> Qb
#pragma unroll
  for (int k = 0; k < 4; ++k) {
    int f = t + k * 512;
    int i = f >> 5, na = f & 31;
    size_t lrow = (size_t)(b * L_ + l0 + i);
    float c1 = Cn[lrow * NST + na]      + C_bias[h * NST + na];
    float c2 = Cn[lrow * NST + na + 32] + C_bias[h * NST + na + 32];
    float th = theta[(lrow * NH + h) * NA + na];
    float sn, cs; sincosf(th, &sn, &cs);
    float q1 = c1 * cs - c2 * sn;
    float q2 = c1 * sn + c2 * cs;
    ushort_t h1 = f2bf(q1), h2 = f2bf(q2);
    st_bf16(QbH, i, 256, na * 2, h1);
    st_bf16(QbH, i, 256, (na + 32) * 2, h2);
    st_bf16(QbL, i, 256, na * 2, f2bf(q1 - bf2f(h1)));
    st_bf16(QbL, i, 256, (na + 32) * 2, f2bf(q2 - bf2f(h2)));
  }
  // Q rest (elems 64..127) -> Qb
#pragma unroll
  for (int k = 0; k < 4; ++k) {
    int f = t + k * 512;
    int i = f >> 5, e2 = f & 31;
    int n1 = 64 + 2 * e2;
    size_t lrow = (size_t)(b * L_ + l0 + i);
    float v1 = Cn[lrow * NST + n1]     + C_bias[h * NST + n1];
    float v2 = Cn[lrow * NST + n1 + 1] + C_bias[h * NST + n1 + 1];
    ushort_t h1 = f2bf(v1), h2 = f2bf(v2);
    st_bf16(QbH, i, 256, n1 * 2, h1);
    st_bf16(QbH, i, 256, (n1 + 1) * 2, h2);
    st_bf16(QbL, i, 256, n1 * 2, f2bf(v1 - bf2f(h1)));
    st_bf16(QbL, i, 256, (n1 + 1) * 2, f2bf(v2 - bf2f(h2)));
  }
  // x rows f32 -> xxs
#pragma unroll
  for (int k = 0; k < 3; ++k) {
    int f = t + k * 512;
    if (f < 65 * 16) {
      int i = f >> 4, p4 = (f & 15) << 2;
      float4 v;
      if (i == 0 && c == 0) v = make_float4(0.f, 0.f, 0.f, 0.f);
      else v = *(const float4*)(proj + (size_t)(b * L_ + l0 + i - 1) * DPROJ + OFF_X + h * HD + p4);
      *(float4*)&xxs[i][p4] = v;
    }
  }
  __syncthreads();

  // ---------- phase 2 ----------
  // K rope (elems 0..63) -> Kb, KTw, ktail
#pragma unroll
  for (int k = 0; k < 5; ++k) {
    int f = t + k * 512;
    if (f < 65 * 32) {
      int i = f >> 5, na = f & 31;
      float k1 = 0.f, k2 = 0.f;
      if (!(i == 0 && c == 0)) {
        size_t lrow = (size_t)(b * L_ + l0 + i - 1);
        float b1 = Bn[lrow * NST + na]      + B_bias[h * NST + na];
        float b2 = Bn[lrow * NST + na + 32] + B_bias[h * NST + na + 32];
        float th = theta[(lrow * NH + h) * NA + na];
        float sn, cs; sincosf(th, &sn, &cs);
        k1 = b1 * cs - b2 * sn;
        k2 = b1 * sn + b2 * cs;
      }
      ushort_t h1 = f2bf(k1), h2 = f2bf(k2);
      st_bf16(KbH, i, 256, na * 2, h1);
      st_bf16(KbH, i, 256, (na + 32) * 2, h2);
      st_bf16(KbL, i, 256, na * 2, f2bf(k1 - bf2f(h1)));
      st_bf16(KbL, i, 256, (na + 32) * 2, f2bf(k2 - bf2f(h2)));
      if (i < 64) {
        float wc = cw[i];
        float kw1 = k1 * wc, kw2 = k2 * wc;
        ushort_t g1_ = f2bf(kw1), g2_ = f2bf(kw2);
        st_bf16(KTwH, na, 128, i * 2, g1_);
        st_bf16(KTwH, na + 32, 128, i * 2, g2_);
        st_bf16(KTwL, na, 128, i * 2, f2bf(kw1 - bf2f(g1_)));
        st_bf16(KTwL, na + 32, 128, i * 2, f2bf(kw2 - bf2f(g2_)));
      } else {
        float tw = w1s[63];
        ktail[na]      = k1 * tw;
        ktail[na + 32] = k2 * tw;
      }
    }
  }
  // K rest (elems 64..127)
#pragma unroll
  for (int k = 0; k < 5; ++k) {
    int f = t + k * 512;
    if (f < 65 * 32) {
      int i = f >> 5, e2 = f & 31;
      int n1 = 64 + 2 * e2;
      float v1 = 0.f, v2 = 0.f;
      if (!(i == 0 && c == 0)) {
        size_t lrow = (size_t)(b * L_ + l0 + i - 1);
        v1 = Bn[lrow * NST + n1]     + B_bias[h * NST + n1];
        v2 = Bn[lrow * NST + n1 + 1] + B_bias[h * NST + n1 + 1];
      }
      ushort_t h1 = f2bf(v1), h2 = f2bf(v2);
      st_bf16(KbH, i, 256, n1 * 2, h1);
      st_bf16(KbH, i, 256, (n1 + 1) * 2, h2);
      st_bf16(KbL, i, 256, n1 * 2, f2bf(v1 - bf2f(h1)));
      st_bf16(KbL, i, 256, (n1 + 1) * 2, f2bf(v2 - bf2f(h2)));
      if (i < 64) {
        float wc = cw[i];
        float kw1 = v1 * wc, kw2 = v2 * wc;
        ushort_t g1_ = f2bf(kw1), g2_ = f2bf(kw2);
        st_bf16(KTwH, n1, 128, i * 2, g1_);
        st_bf16(KTwH, n1 + 1, 128, i * 2, g2_);
        st_bf16(KTwL, n1, 128, i * 2, f2bf(kw1 - bf2f(g1_)));
        st_bf16(KTwL, n1 + 1, 128, i * 2, f2bf(kw2 - bf2f(g2_)));
      } else {
        float tw = w1s[63];
        ktail[n1]     = v1 * tw;
        ktail[n1 + 1] = v2 * tw;
      }
    }
  }
  // xT transpose + split (xT0: col j' = xxs[j'], xT1: col j = xxs[j+1])
  {
    int p = t >> 3, jc = (t & 7) << 3;
    float r[9];
#pragma unroll
    for (int e = 0; e < 9; ++e) r[e] = xxs[jc + e][p];
    BF8 t0h, t0l, t1h, t1l;
#pragma unroll
    for (int e = 0; e < 8; ++e) {
      ushort_t hh = f2bf(r[e]);     t0h.u[e] = hh; t0l.u[e] = f2bf(r[e] - bf2f(hh));
      ushort_t gg = f2bf(r[e + 1]); t1h.u[e] = gg; t1l.u[e] = f2bf(r[e + 1] - bf2f(gg));
    }
    int cb = (jc * 2) ^ ((p & 7) << 4);
    *(uint4*)(xT0H + p * 128 + cb) = t0h.q;
    *(uint4*)(xT0L + p * 128 + cb) = t0l.q;
    *(uint4*)(xT1H + p * 128 + cb) = t1h.q;
    *(uint4*)(xT1L + p * 128 + cb) = t1l.q;
    if (jc == 56) xtail[p] = r[8];
  }
  __syncthreads();

  // ---------- phase 3: compute ----------
  const int lane = t & 63, wv = t >> 6;
  const int q4 = lane >> 4, l15 = lane & 15;
  const int Rr = (wv >> 1) << 4;   // row-block base (0,16,32,48)
  const int Cb = (wv & 1) << 5;    // col-half base (0,32)

  bf16x8 qh[4], ql[4];
#pragma unroll
  for (int ks = 0; ks < 4; ++ks) {
    int cb = ks * 64 + q4 * 16;
    qh[ks] = ldf(QbH, Rr + l15, 256, cb);
    ql[ks] = ldf(QbL, Rr + l15, 256, cb);
  }
  f32x4 s1a[2], s2a[2];
#pragma unroll
  for (int ct = 0; ct < 2; ++ct) { s1a[ct] = (f32x4){0.f,0.f,0.f,0.f}; s2a[ct] = (f32x4){0.f,0.f,0.f,0.f}; }

#pragma unroll
  for (int ct = 0; ct < 2; ++ct) {
    int jb = Cb + ct * 16 + l15;
#pragma unroll
    for (int ks = 0; ks < 4; ++ks) {
      int cb = ks * 64 + q4 * 16;
      bf16x8 kh1 = ldf(KbH, jb + 1, 256, cb);
      bf16x8 kl1 = ldf(KbL, jb + 1, 256, cb);
      s1a[ct] = __builtin_amdgcn_mfma_f32_16x16x32_bf16(qh[ks], kh1, s1a[ct], 0, 0, 0);
      s1a[ct] = __builtin_amdgcn_mfma_f32_16x16x32_bf16(qh[ks], kl1, s1a[ct], 0, 0, 0);
      s1a[ct] = __builtin_amdgcn_mfma_f32_16x16x32_bf16(ql[ks], kh1, s1a[ct], 0, 0, 0);
      bf16x8 kh0 = ldf(KbH, jb, 256, cb);
      bf16x8 kl0 = ldf(KbL, jb, 256, cb);
      s2a[ct] = __builtin_amdgcn_mfma_f32_16x16x32_bf16(qh[ks], kh0, s2a[ct], 0, 0, 0);
      s2a[ct] = __builtin_amdgcn_mfma_f32_16x16x32_bf16(qh[ks], kl0, s2a[ct], 0, 0, 0);
      s2a[ct] = __builtin_amdgcn_mfma_f32_16x16x32_bf16(ql[ks], kh0, s2a[ct], 0, 0, 0);
    }
  }

  // S1 -> Sb (decay+mask)
#pragma unroll
  for (int ct = 0; ct < 2; ++ct) {
    int j = Cb + ct * 16 + l15;
    float ej = ell[j], gj = g1s[j];
#pragma unroll
    for (int reg = 0; reg < 4; ++reg) {
      int i = Rr + q4 * 4 + reg;
      float v = (j <= i) ? s1a[ct][reg] * gj * expf(ell[i] - ej) : 0.0f;
      ushort_t hv = f2bf(v);
      st_bf16(SbH, i, 128, j * 2, hv);
      st_bf16(SbL, i, 128, j * 2, f2bf(v - bf2f(hv)));
    }
  }
  __syncthreads();

  f32x4 yacc[2];
  yacc[0] = (f32x4){0.f,0.f,0.f,0.f}; yacc[1] = (f32x4){0.f,0.f,0.f,0.f};
  {
    bf16x8 sh[2], sl[2];
#pragma unroll
    for (int ks = 0; ks < 2; ++ks) {
      int cb = ks * 64 + q4 * 16;
      sh[ks] = ldf(SbH, Rr + l15, 128, cb);
      sl[ks] = ldf(SbL, Rr + l15, 128, cb);
    }
#pragma unroll
    for (int pt = 0; pt < 2; ++pt) {
      int prow = Cb + pt * 16 + l15;
#pragma unroll
      for (int ks = 0; ks < 2; ++ks) {
        int cb = ks * 64 + q4 * 16;
        bf16x8 xh = ldf(xT1H, prow, 128, cb);
        bf16x8 xl = ldf(xT1L, prow, 128, cb);
        yacc[pt] = __builtin_amdgcn_mfma_f32_16x16x32_bf16(sh[ks], xh, yacc[pt], 0, 0, 0);
        yacc[pt] = __builtin_amdgcn_mfma_f32_16x16x32_bf16(sh[ks], xl, yacc[pt], 0, 0, 0);
        yacc[pt] = __builtin_amdgcn_mfma_f32_16x16x32_bf16(sl[ks], xh, yacc[pt], 0, 0, 0);
      }
    }
  }
  __syncthreads();

  // S2 -> Sb
#pragma unroll
  for (int ct = 0; ct < 2; ++ct) {
    int j = Cb + ct * 16 + l15;
    float ej = ell[j], gj = g2s[j];
#pragma unroll
    for (int reg = 0; reg < 4; ++reg) {
      int i = Rr + q4 * 4 + reg;
      float v = (j <= i) ? s2a[ct][reg] * gj * expf(ell[i] - ej) : 0.0f;
      ushort_t hv = f2bf(v);
      st_bf16(SbH, i, 128, j * 2, hv);
      st_bf16(SbL, i, 128, j * 2, f2bf(v - bf2f(hv)));
    }
  }
  __syncthreads();

  {
    bf16x8 sh[2], sl[2];
#pragma unroll
    for (int ks = 0; ks < 2; ++ks) {
      int cb = ks * 64 + q4 * 16;
      sh[ks] = ldf(SbH, Rr + l15, 128, cb);
      sl[ks] = ldf(SbL, Rr + l15, 128, cb);
    }
#pragma unroll
    for (int pt = 0; pt < 2; ++pt) {
      int prow = Cb + pt * 16 + l15;
#pragma unroll
      for (int ks = 0; ks < 2; ++ks) {
        int cb = ks * 64 + q4 * 16;
        bf16x8 xh = ldf(xT0H, prow, 128, cb);
        bf16x8 xl = ldf(xT0L, prow, 128, cb);
        yacc[pt] = __builtin_amdgcn_mfma_f32_16x16x32_bf16(sh[ks], xh, yacc[pt], 0, 0, 0);
        yacc[pt] = __builtin_amdgcn_mfma_f32_16x16x32_bf16(sh[ks], xl, yacc[pt], 0, 0, 0);
        yacc[pt] = __builtin_amdgcn_mfma_f32_16x16x32_bf16(sl[ks], xh, yacc[pt], 0, 0, 0);
      }
    }
  }
  // y_intra store
#pragma unroll
  for (int pt = 0; pt < 2; ++pt) {
    int p = Cb + pt * 16 + l15;
#pragma unroll
    for (int reg = 0; reg < 4; ++reg) {
      int i = Rr + q4 * 4 + reg;
      ybuf[(size_t)(b * L_ + l0 + i) * DIN + h * HD + p] = yacc[pt][reg];
    }
  }

  // WsumT[p][n] = sum_j' xT0[p][j'] * KTw[n][j'] (+ rank-1 tail j'=64)
  {
    const int Pw = (wv >> 1) << 4;
    const int Nb = (wv & 1) << 6;
    f32x4 wacc[4];
#pragma unroll
    for (int nt = 0; nt < 4; ++nt) wacc[nt] = (f32x4){0.f,0.f,0.f,0.f};
    bf16x8 axh[2], axl[2];
#pragma unroll
    for (int ks = 0; ks < 2; ++ks) {
      int cb = ks * 64 + q4 * 16;
      axh[ks] = ldf(xT0H, Pw + l15, 128, cb);
      axl[ks] = ldf(xT0L, Pw + l15, 128, cb);
    }
#pragma unroll
    for (int nt = 0; nt < 4; ++nt) {
      int nrow = Nb + nt * 16 + l15;
#pragma unroll
      for (int ks = 0; ks < 2; ++ks) {
        int cb = ks * 64 + q4 * 16;
        bf16x8 bh = ldf(KTwH, nrow, 128, cb);
        bf16x8 bl = ldf(KTwL, nrow, 128, cb);
        wacc[nt] = __builtin_amdgcn_mfma_f32_16x16x32_bf16(axh[ks], bh, wacc[nt], 0, 0, 0);
        wacc[nt] = __builtin_amdgcn_mfma_f32_16x16x32_bf16(axh[ks], bl, wacc[nt], 0, 0, 0);
        wacc[nt] = __builtin_amdgcn_mfma_f32_16x16x32_bf16(axl[ks], bh, wacc[nt], 0, 0, 0);
      }
    }
    size_t wbase = ((size_t)(b * NC + c) * NH + h) * (size_t)(NST * HD);
#pragma unroll
    for (int nt = 0; nt < 4; ++nt) {
      int n = Nb + nt * 16 + l15;
      float kt = ktail[n];
#pragma unroll
      for (int reg = 0; reg < 4; ++reg) {
        int p = Pw + q4 * 4 + reg;
        WsT[wbase + (size_t)p * NST + n] = wacc[nt][reg] + xtail[p] * kt;
      }
    }
  }
}

// ---------------- P5: state scan (elementwise over [p][n]-major Wsum) ----------------
__global__ __launch_bounds__(256) void state_scan_kernel(
    float* __restrict__ Wsum, const float* __restrict__ cdg) {
  const int b = blockIdx.x >> 5;
  const int h = blockIdx.x & 31;
  float Hst[32];
#pragma unroll
  for (int k = 0; k < 32; ++k) Hst[k] = 0.0f;
  for (int c = 0; c < NC; ++c) {
    float cd = cdg[((size_t)b * NC + c) * NH + h];
    float* wp = Wsum + ((size_t)(b * NC + c) * NH + h) * (size_t)(NST * HD);
#pragma unroll
    for (int k = 0; k < 32; ++k) {
      int e = threadIdx.x + k * 256;
      float w  = wp[e];
      float hv = Hst[k];
      wp[e]    = hv;
      Hst[k]   = fmaf(cd, hv, w);
    }
  }
}

// ---------------- P6: finalize (HprevT layout [p][n]) ----------------
__global__ __launch_bounds__(256) void finalize_kernel(
    const float* __restrict__ proj, const float* __restrict__ Cn,
    const float* __restrict__ theta, const float* __restrict__ C_bias,
    const float* __restrict__ Hprev, const float* __restrict__ adtg,
    const float* __restrict__ dvec, float* __restrict__ ybuf) {
  const int h  = blockIdx.x & 31;
  const int c  = (blockIdx.x >> 5) & 31;
  const int b  = blockIdx.x >> 10;
  const int t  = threadIdx.x;
  const int l0 = c * CHK;

  __shared__ float Qs[64][132];
  __shared__ float HsT[64][132];
  __shared__ float ell[64];

#pragma unroll
  for (int k = 0; k < 8; ++k) {
    int f = t + k * 256;
    int i = f >> 5, n = (f & 31) << 2;
    F4 v, bb;
    v.v  = *(const float4*)(Cn + (size_t)(b * L_ + l0 + i) * NST + n);
    bb.v = *(const float4*)(C_bias + h * NST + n);
#pragma unroll
    for (int q = 0; q < 4; ++q) v.a[q] += bb.a[q];
    *(float4*)&Qs[i][n] = v.v;
  }
  {
    const float* hp = Hprev + ((size_t)(b * NC + c) * NH + h) * (size_t)(NST * HD);
#pragma unroll
    for (int k = 0; k < 8; ++k) {
      int f = t + k * 256;
      int p = f >> 5, n4 = (f & 31) << 2;
      *(float4*)&HsT[p][n4] = *(const float4*)(hp + (size_t)p * NST + n4);
    }
  }
  if (t < 64) {
    float v = adtg[((size_t)b * NH + h) * L_ + l0 + t];
#pragma unroll
    for (int off = 1; off < 64; off <<= 1) {
      float u = __shfl_up(v, off, 64);
      if (t >= off) v += u;
    }
    ell[t] = v;
  }
  __syncthreads();

#pragma unroll
  for (int k = 0; k < 8; ++k) {
    int f = t + k * 256;
    int i = f >> 5, na = f & 31;
    float th = theta[((size_t)(b * L_ + l0 + i) * NH + h) * NA + na];
    float sn, cs;
    sincosf(th, &sn, &cs);
    float q1 = Qs[i][na], q2 = Qs[i][na + 32];
    Qs[i][na]      = q1 * cs - q2 * sn;
    Qs[i][na + 32] = q1 * sn + q2 * cs;
  }
  __syncthreads();

  const int i0 = (t >> 4) << 2, p0 = (t & 15) << 2;
  float acc[4][4];
#pragma unroll
  for (int r = 0; r < 4; ++r)
#pragma unroll
    for (int p = 0; p < 4; ++p) acc[r][p] = 0.0f;

  for (int n4 = 0; n4 < 32; ++n4) {
    F4 qa[4], hb[4];
#pragma unroll
    for (int r = 0; r < 4; ++r)  qa[r].v = *(const float4*)&Qs[i0 + r][n4 << 2];
#pragma unroll
    for (int pp = 0; pp < 4; ++pp) hb[pp].v = *(const float4*)&HsT[p0 + pp][n4 << 2];
#pragma unroll
    for (int r = 0; r < 4; ++r)
#pragma unroll
      for (int pp = 0; pp < 4; ++pp) {
        acc[r][pp] = fmaf(qa[r].a[0], hb[pp].a[0], acc[r][pp]);
        acc[r][pp] = fmaf(qa[r].a[1], hb[pp].a[1], acc[r][pp]);
        acc[r][pp] = fmaf(qa[r].a[2], hb[pp].a[2], acc[r][pp]);
        acc[r][pp] = fmaf(qa[r].a[3], hb[pp].a[3], acc[r][pp]);
      }
  }

  const float Dv = dvec[h];
#pragma unroll
  for (int r = 0; r < 4; ++r) {
    const int l = l0 + i0 + r;
    const float e = expf(ell[i0 + r]);
    const size_t rowoff = (size_t)(b * L_ + l);
    F4 yi, xv, zv, o;
    yi.v = *(float4*)(ybuf + rowoff * DIN + h * HD + p0);
    xv.v = *(const float4*)(proj + rowoff * DPROJ + OFF_X + h * HD + p0);
    zv.v = *(const float4*)(proj + rowoff * DPROJ + OFF_Z + h * HD + p0);
#pragma unroll
    for (int p = 0; p < 4; ++p) {
      float z = zv.a[p];
      o.a[p] = (yi.a[p] + e * acc[r][p] + Dv * xv.a[p]) * (z * sigmoidf_(z));
    }
    *(float4*)(ybuf + rowoff * DIN + h * HD + p0) = o.v;
  }
}

__global__ void zero_out_kernel(float* __restrict__ out, int n) {
  int i = blockIdx.x * 256 + threadIdx.x;
  if (i < n) out[i] = 0.0f;
}

extern "C" void kernel_launch(void* const* d_in, const int* in_sizes, int n_in,
                              void* d_out, int out_size, void* d_ws, size_t ws_size,
                              hipStream_t stream) {
  const float* u        = (const float*)d_in[0];
  const float* W_in     = (const float*)d_in[1];
  const float* W_out    = (const float*)d_in[2];
  const float* dt_bias  = (const float*)d_in[3];
  const float* B_bias   = (const float*)d_in[4];
  const float* C_bias   = (const float*)d_in[5];
  const float* B_norm_w = (const float*)d_in[6];
  const float* C_norm_w = (const float*)d_in[7];
  const float* Dv       = (const float*)d_in[8];
  float* out = (float*)d_out;
  float* ws  = (float*)d_ws;

  size_t o = 0;
  float* proj  = ws + o; o += (size_t)B_ * L_ * DPROJ;
  float* Bn    = ws + o; o += (size_t)B_ * L_ * NST;
  float* Cn    = ws + o; o += (size_t)B_ * L_ * NST;
  float* dtg   = ws + o; o += (size_t)B_ * NH * L_;
  float* adtg  = ws + o; o += (size_t)B_ * NH * L_;
  float* g1g   = ws + o; o += (size_t)B_ * NH * L_;
  float* g2g   = ws + o; o += (size_t)B_ * NH * L_;
  float* theta = ws + o; o += (size_t)B_ * L_ * NH * NA;
  float* Wsum  = ws + o; o += (size_t)B_ * NC * NH * NST * HD;
  float* cdg   = ws + o; o += (size_t)B_ * NC * NH;
  float* ybuf  = ws + o; o += (size_t)B_ * L_ * DIN;
  ushort_t* Wth = (ushort_t*)(ws + o); o += (size_t)DPROJ * DM / 2;
  ushort_t* Wtl = (ushort_t*)(ws + o); o += (size_t)DPROJ * DM / 2;
  ushort_t* Woh = (ushort_t*)(ws + o); o += (size_t)DM * DIN / 2;
  ushort_t* Wol = (ushort_t*)(ws + o); o += (size_t)DM * DIN / 2;

  if (ws_size < o * sizeof(float)) {
    zero_out_kernel<<<(out_size + 255) / 256, 256, 0, stream>>>(out, out_size);
    return;
  }

  tsplit_kernel<<<dim3(DPROJ / 64, DM / 64), 256, 0, stream>>>(W_in, Wth, Wtl, DM, DPROJ);
  tsplit_kernel<<<dim3(DM / 64, DIN / 64), 256, 0, stream>>>(W_out, Woh, Wol, DIN, DM);
  gemm_s3<<<dim3(DPROJ / 128, (B_ * L_) / 128), 256, 0, stream>>>(
      u, Wth, Wtl, proj, B_ * L_, DPROJ, DM);
  pointwise_kernel<<<B_ * L_, 128, 0, stream>>>(
      proj, dt_bias, B_norm_w, C_norm_w, Bn, Cn, dtg, adtg, g1g, g2g);
  theta_kernel<<<B_ * NH, 64, 0, stream>>>(proj, dtg, theta);
  chunk_kernel<<<B_ * NC * NH, 512, 0, stream>>>(
      proj, Bn, Cn, theta, B_bias, C_bias, adtg, g1g, g2g, Wsum, cdg, ybuf);
  state_scan_kernel<<<B_ * NH, 256, 0, stream>>>(Wsum, cdg);
  finalize_kernel<<<B_ * NC * NH, 256, 0, stream>>>(
      proj, Cn, theta, C_bias, Wsum, adtg, Dv, ybuf);
  gemm_s3<<<dim3(DM / 128, (B_ * L_) / 128), 256, 0, stream>>>(
      ybuf, Woh, Wol, out, B_ * L_, DM, DIN);
}

// Round 5
// 602.781 us; speedup vs baseline: 2.1165x; 1.1821x over previous
//
#include <hip/hip_runtime.h>
#include <math.h>

#define B_    2
#define L_    2048
#define DM    1024
#define DIN   2048
#define NH    32
#define HD    64
#define NST   128
#define NA    32
#define NC    32
#define CHK   64
#define DPROJ 4480

#define OFF_Z    0
#define OFF_X    2048
#define OFF_BG   4096
#define OFF_CG   4224
#define OFF_DDT  4352
#define OFF_DDA  4384
#define OFF_TRAP 4416
#define OFF_ANG  4448

typedef union { float4 v; float a[4]; } F4;
typedef unsigned short ushort_t;
typedef union { ushort4 v; ushort_t a[4]; } US4;
typedef __attribute__((ext_vector_type(8))) short bf16x8;
typedef __attribute__((ext_vector_type(4))) float f32x4;
typedef union { bf16x8 v; ushort_t u[8]; uint4 q; } BF8;

__device__ __forceinline__ float softplusf_(float x) {
  return (x > 20.0f) ? x : log1pf(expf(x));
}
__device__ __forceinline__ float sigmoidf_(float x) {
  return 1.0f / (1.0f + expf(-x));
}
__device__ __forceinline__ ushort_t f2bf(float x) {
  union { float f; unsigned u; } v; v.f = x;
  unsigned r = v.u + 0x7fffu + ((v.u >> 16) & 1u);
  return (ushort_t)(r >> 16);
}
__device__ __forceinline__ float bf2f(ushort_t h) {
  union { unsigned u; float f; } v; v.u = ((unsigned)h) << 16;
  return v.f;
}
__device__ __forceinline__ bf16x8 ldf(const char* base, int row, int stride, int cb) {
  return *(const bf16x8*)(base + row * stride + (cb ^ ((row & 7) << 4)));
}
__device__ __forceinline__ void st_bf16(char* base, int row, int stride, int colb, ushort_t v) {
  *(ushort_t*)(base + row * stride + (colb ^ ((row & 7) << 4))) = v;
}
__device__ __forceinline__ void glds16(const void* g, void* l) {
  __builtin_amdgcn_global_load_lds(
      (const __attribute__((address_space(1))) void*)g,
      (__attribute__((address_space(3))) void*)l, 16, 0, 0);
}

// ---------------- transpose+split: src[Kd][Nd] f32 -> hi/lo [Nd][Kd] bf16 ----------------
__global__ __launch_bounds__(256) void tsplit_kernel(
    const float* __restrict__ src, ushort_t* __restrict__ hi,
    ushort_t* __restrict__ lo, int Kd, int Nd) {
  __shared__ float tile[64][65];
  const int k0 = blockIdx.y * 64, n0 = blockIdx.x * 64;
  const int t = threadIdx.x;
  {
    const int r = t >> 4, c4 = (t & 15) << 2;
#pragma unroll
    for (int rr = 0; rr < 4; ++rr) {
      F4 v; v.v = *(const float4*)(src + (size_t)(k0 + r + rr * 16) * Nd + n0 + c4);
      tile[r + rr * 16][c4] = v.a[0]; tile[r + rr * 16][c4 + 1] = v.a[1];
      tile[r + rr * 16][c4 + 2] = v.a[2]; tile[r + rr * 16][c4 + 3] = v.a[3];
    }
  }
  __syncthreads();
  const int n = t >> 2, kc = (t & 3) << 4;
  BF8 h0, h1, l0, l1;
#pragma unroll
  for (int e = 0; e < 8; ++e) {
    float x = tile[kc + e][n];
    ushort_t h = f2bf(x); h0.u[e] = h; l0.u[e] = f2bf(x - bf2f(h));
    float y = tile[kc + 8 + e][n];
    ushort_t g = f2bf(y); h1.u[e] = g; l1.u[e] = f2bf(y - bf2f(g));
  }
  size_t ob = (size_t)(n0 + n) * Kd + k0 + kc;
  *(uint4*)(hi + ob) = h0.q; *(uint4*)(hi + ob + 8) = h1.q;
  *(uint4*)(lo + ob) = l0.q; *(uint4*)(lo + ob + 8) = l1.q;
}

// ---------------- elementwise split: f32 -> hi/lo bf16 (same layout) ----------------
__global__ __launch_bounds__(256) void split_kernel(
    const float* __restrict__ src, ushort_t* __restrict__ hi,
    ushort_t* __restrict__ lo, int n8) {
  int i = blockIdx.x * 256 + threadIdx.x;
  if (i >= n8) return;
  const float* p = src + (size_t)i * 8;
  F4 a, b; a.v = *(const float4*)p; b.v = *(const float4*)(p + 4);
  BF8 h, l;
#pragma unroll
  for (int e = 0; e < 4; ++e) {
    ushort_t hh = f2bf(a.a[e]); h.u[e] = hh; l.u[e] = f2bf(a.a[e] - bf2f(hh));
    ushort_t gg = f2bf(b.a[e]); h.u[e + 4] = gg; l.u[e + 4] = f2bf(b.a[e] - bf2f(gg));
  }
  *(uint4*)(hi + (size_t)i * 8) = h.q;
  *(uint4*)(lo + (size_t)i * 8) = l.q;
}

// ---------------- MFMA GEMM, global_load_lds staging, 3-pass split-bf16 ----------------
// A: hi/lo [M][K] bf16; Bt: hi/lo [N][K] bf16; C: f32 [M][N]
// LDS tile: [128 rows][128 B] = (hi 64B | lo 64B) per row, XOR-swizzled by (row&7)<<4.
__global__ __launch_bounds__(256) void gemm_glds(
    const ushort_t* __restrict__ Ah, const ushort_t* __restrict__ Al,
    const ushort_t* __restrict__ Bth, const ushort_t* __restrict__ Btl,
    float* __restrict__ C, int M, int N, int K, int nbx) {
  __shared__ __align__(16) char ldsA[16384], ldsB[16384];
  const int nwg = gridDim.x;
  const int q8 = nwg >> 3;
  const int swz = (blockIdx.x & 7) * q8 + (blockIdx.x >> 3);
  const int bm = (swz / nbx) << 7, bn = (swz % nbx) << 7;
  const int t = threadIdx.x, w = t >> 6, lane = t & 63;

  // ---- staging geometry (linear LDS dest, inverse-swizzled global source) ----
  // wave w, issue i in 0..3: LDS base = w*4096 + i*1024; lane slot = base + lane*16
  // slot -> row = w*32 + i*8 + (lane>>3), off = (lane&7)*16
  // stored logical col c = off ^ ((row&7)<<4); row&7 == lane>>3 (indep. of i)
  const size_t K2 = (size_t)K << 1;
  const int swl = (lane >> 3) << 4;
  const int cA = ((lane & 7) << 4) ^ swl;    // logical byte col in [0,128)
  const int rl = (w << 5) + (lane >> 3);     // row for issue 0
  const char* gA = (cA < 64 ? (const char*)Ah + cA : (const char*)Al + (cA - 64))
                   + (size_t)(bm + rl) * K2;
  const char* gB = (cA < 64 ? (const char*)Bth + cA : (const char*)Btl + (cA - 64))
                   + (size_t)(bn + rl) * K2;
  const size_t istep = K2 << 3;              // 8 rows
  char* dA = ldsA + (w << 12);
  char* dB = ldsB + (w << 12);

  // ---- compute geometry ----
  const int wm = (w >> 1) << 6, wn = (w & 1) << 6;
  const int lr = lane & 15, cb = (lane >> 4) << 4;

  f32x4 acc[4][4];
#pragma unroll
  for (int i = 0; i < 4; ++i)
#pragma unroll
    for (int j = 0; j < 4; ++j) acc[i][j] = (f32x4){0.f, 0.f, 0.f, 0.f};

#define STAGE(k0) do {                                                  \
    size_t kb = (size_t)(k0) << 1;                                      \
    glds16(gA + kb,             dA);                                    \
    glds16(gA + kb + istep,     dA + 1024);                             \
    glds16(gA + kb + 2 * istep, dA + 2048);                             \
    glds16(gA + kb + 3 * istep, dA + 3072);                             \
    glds16(gB + kb,             dB);                                    \
    glds16(gB + kb + istep,     dB + 1024);                             \
    glds16(gB + kb + 2 * istep, dB + 2048);                             \
    glds16(gB + kb + 3 * istep, dB + 3072);                             \
  } while (0)

  STAGE(0);
  for (int k0 = 0; k0 < K; k0 += 32) {
    __syncthreads();   // staged tile visible (compiler drains vmcnt before barrier)
    bf16x8 ah[4], al[4], bh[4], bl[4];
#pragma unroll
    for (int mf = 0; mf < 4; ++mf) {
      int r2 = wm + (mf << 4) + lr;
      int sw2 = (r2 & 7) << 4;
      ah[mf] = *(const bf16x8*)(ldsA + (r2 << 7) + (cb ^ sw2));
      al[mf] = *(const bf16x8*)(ldsA + (r2 << 7) + ((cb + 64) ^ sw2));
    }
#pragma unroll
    for (int nf = 0; nf < 4; ++nf) {
      int r2 = wn + (nf << 4) + lr;
      int sw2 = (r2 & 7) << 4;
      bh[nf] = *(const bf16x8*)(ldsB + (r2 << 7) + (cb ^ sw2));
      bl[nf] = *(const bf16x8*)(ldsB + (r2 << 7) + ((cb + 64) ^ sw2));
    }
#pragma unroll
    for (int mf = 0; mf < 4; ++mf)
#pragma unroll
      for (int nf = 0; nf < 4; ++nf) {
        acc[mf][nf] = __builtin_amdgcn_mfma_f32_16x16x32_bf16(ah[mf], bh[nf], acc[mf][nf], 0, 0, 0);
        acc[mf][nf] = __builtin_amdgcn_mfma_f32_16x16x32_bf16(ah[mf], bl[nf], acc[mf][nf], 0, 0, 0);
        acc[mf][nf] = __builtin_amdgcn_mfma_f32_16x16x32_bf16(al[mf], bh[nf], acc[mf][nf], 0, 0, 0);
      }
    __syncthreads();   // all waves done reading before overwrite
    if (k0 + 32 < K) STAGE(k0 + 32);
  }
#undef STAGE

  const int rsub = (lane >> 4) << 2;
#pragma unroll
  for (int mf = 0; mf < 4; ++mf)
#pragma unroll
    for (int nf = 0; nf < 4; ++nf) {
      float* cp = C + (size_t)(bm + wm + mf * 16 + rsub) * N + bn + wn + nf * 16 + lr;
#pragma unroll
      for (int j = 0; j < 4; ++j) cp[(size_t)j * N] = acc[mf][nf][j];
    }
}

// ---------------- P2: per-(b,l) pointwise ----------------
__global__ __launch_bounds__(128) void pointwise_kernel(
    const float* __restrict__ proj, const float* __restrict__ dt_bias,
    const float* __restrict__ Bnw, const float* __restrict__ Cnw,
    float* __restrict__ Bn, float* __restrict__ Cn,
    float* __restrict__ dtg, float* __restrict__ adtg,
    float* __restrict__ g1g, float* __restrict__ g2g) {
  const int bl = blockIdx.x;
  const int l  = bl & (L_ - 1);
  const int b  = bl >> 11;
  const int t  = threadIdx.x;
  const float* row = proj + (size_t)bl * DPROJ;

  float vb = row[OFF_BG + t];
  float vc = row[OFF_CG + t];
  float sb = vb * vb, sc = vc * vc;
#pragma unroll
  for (int off = 32; off >= 1; off >>= 1) {
    sb += __shfl_xor(sb, off, 64);
    sc += __shfl_xor(sc, off, 64);
  }
  __shared__ float red[4];
  if ((t & 63) == 0) { red[t >> 6] = sb; red[2 + (t >> 6)] = sc; }
  __syncthreads();
  sb = red[0] + red[1];
  sc = red[2] + red[3];
  float rb = rsqrtf(sb * (1.0f / 128.0f) + 1e-5f);
  float rc = rsqrtf(sc * (1.0f / 128.0f) + 1e-5f);
  Bn[(size_t)bl * NST + t] = vb * rb * Bnw[t];
  Cn[(size_t)bl * NST + t] = vc * rc * Cnw[t];

  if (t < NH) {
    const int h = t;
    float dt = softplusf_(row[OFF_DDT + h] + dt_bias[h]);
    float a  = -softplusf_(row[OFF_DDA + h]);
    a = fminf(a, -1e-4f);
    float adt  = a * dt;
    float beta = sigmoidf_(row[OFF_TRAP + h]);
    float dtp  = 0.0f;
    if (l > 0) dtp = softplusf_(proj[(size_t)(bl - 1) * DPROJ + OFF_DDT + h] + dt_bias[h]);
    float g2 = (1.0f - beta) * expf(adt) * dtp;
    size_t idx = ((size_t)b * NH + h) * L_ + l;
    dtg[idx]  = dt;
    adtg[idx] = adt;
    g1g[idx]  = beta * dt;
    g2g[idx]  = g2;
  }
}

// ---------------- P3: theta cumsum ----------------
__global__ __launch_bounds__(64) void theta_kernel(
    const float* __restrict__ proj, const float* __restrict__ dtg,
    float* __restrict__ theta) {
  const int b  = blockIdx.x >> 5;
  const int h  = blockIdx.x & 31;
  const int na = threadIdx.x;
  if (na >= NA) return;
  const float* ap = proj + (size_t)b * L_ * DPROJ + OFF_ANG + na;
  const float* dp = dtg + ((size_t)b * NH + h) * L_;
  float* tp = theta + ((size_t)b * L_ * NH + h) * NA + na;
  float th = 0.0f;
#pragma unroll 16
  for (int l = 0; l < L_; ++l) {
    th = fmaf(ap[(size_t)l * DPROJ], dp[l], th);
    tp[(size_t)l * NH * NA] = th;
  }
}

// ---------------- P4: MFMA chunk kernel (512 threads) ----------------
__global__ __launch_bounds__(512, 1) void chunk_kernel(
    const float* __restrict__ proj,
    const float* __restrict__ Bn, const float* __restrict__ Cn,
    const float* __restrict__ theta,
    const float* __restrict__ B_bias, const float* __restrict__ C_bias,
    const float* __restrict__ adtg, const float* __restrict__ g1g,
    const float* __restrict__ g2g,
    float* __restrict__ WsT, float* __restrict__ cdg,
    ushort_t* __restrict__ yh, ushort_t* __restrict__ yl) {
  const int h  = blockIdx.x & 31;
  const int c  = (blockIdx.x >> 5) & 31;
  const int b  = blockIdx.x >> 10;
  const int t  = threadIdx.x;
  const int l0 = c * CHK;

  __shared__ __align__(16) char QbH[16384], QbL[16384];
  __shared__ __align__(16) char KbH[16640], KbL[16640];
  __shared__ __align__(16) char KTwH[16384], KTwL[16384];
  __shared__ __align__(16) char xT0H[8192], xT0L[8192];
  __shared__ __align__(16) char xT1H[8192], xT1L[8192];
  __shared__ __align__(16) char Ubuf[17680];
  __shared__ float ell[64], g1s[64], g2s[64], w1s[64], cw[64], xtail[64], ktail[128];
  float (*xxs)[68] = (float(*)[68])Ubuf;
  char* SbH = Ubuf;
  char* SbL = Ubuf + 8192;

  // ---------- phase 1 ----------
  if (t < 64) {
    size_t idx = ((size_t)b * NH + h) * L_ + l0 + t;
    float adt = adtg[idx], g1 = g1g[idx], g2 = g2g[idx];
    float v = adt;
#pragma unroll
    for (int off = 1; off < 64; off <<= 1) {
      float u = __shfl_up(v, off, 64);
      if (t >= off) v += u;
    }
    ell[t] = v;
    float last = __shfl(v, 63, 64);
    float de = expf(last - v);
    float w1 = g1 * de, w2 = g2 * de;
    g1s[t] = g1; g2s[t] = g2; w1s[t] = w1;
    float w1p = __shfl_up(w1, 1, 64);
    cw[t] = (t >= 1 ? w1p : 0.0f) + w2;
    if (t == 63) cdg[((size_t)b * NC + c) * NH + h] = expf(v);
  }
#pragma unroll
  for (int k = 0; k < 4; ++k) {
    int f = t + k * 512;
    int i = f >> 5, na = f & 31;
    size_t lrow = (size_t)(b * L_ + l0 + i);
    float c1 = Cn[lrow * NST + na]      + C_bias[h * NST + na];
    float c2 = Cn[lrow * NST + na + 32] + C_bias[h * NST + na + 32];
    float th = theta[(lrow * NH + h) * NA + na];
    float sn, cs; sincosf(th, &sn, &cs);
    float q1 = c1 * cs - c2 * sn;
    float q2 = c1 * sn + c2 * cs;
    ushort_t h1 = f2bf(q1), h2 = f2bf(q2);
    st_bf16(QbH, i, 256, na * 2, h1);
    st_bf16(QbH, i, 256, (na + 32) * 2, h2);
    st_bf16(QbL, i, 256, na * 2, f2bf(q1 - bf2f(h1)));
    st_bf16(QbL, i, 256, (na + 32) * 2, f2bf(q2 - bf2f(h2)));
  }
#pragma unroll
  for (int k = 0; k < 4; ++k) {
    int f = t + k * 512;
    int i = f >> 5, e2 = f & 31;
    int n1 = 64 + 2 * e2;
    size_t lrow = (size_t)(b * L_ + l0 + i);
    float v1 = Cn[lrow * NST + n1]     + C_bias[h * NST + n1];
    float v2 = Cn[lrow * NST + n1 + 1] + C_bias[h * NST + n1 + 1];
    ushort_t h1 = f2bf(v1), h2 = f2bf(v2);
    st_bf16(QbH, i, 256, n1 * 2, h1);
    st_bf16(QbH, i, 256, (n1 + 1) * 2, h2);
    st_bf16(QbL, i, 256, n1 * 2, f2bf(v1 - bf2f(h1)));
    st_bf16(QbL, i, 256, (n1 + 1) * 2, f2bf(v2 - bf2f(h2)));
  }
#pragma unroll
  for (int k = 0; k < 3; ++k) {
    int f = t + k * 512;
    if (f < 65 * 16) {
      int i = f >> 4, p4 = (f & 15) << 2;
      float4 v;
      if (i == 0 && c == 0) v = make_float4(0.f, 0.f, 0.f, 0.f);
      else v = *(const float4*)(proj + (size_t)(b * L_ + l0 + i - 1) * DPROJ + OFF_X + h * HD + p4);
      *(float4*)&xxs[i][p4] = v;
    }
  }
  __syncthreads();

  // ---------- phase 2 ----------
#pragma unroll
  for (int k = 0; k < 5; ++k) {
    int f = t + k * 512;
    if (f < 65 * 32) {
      int i = f >> 5, na = f & 31;
      float k1 = 0.f, k2 = 0.f;
      if (!(i == 0 && c == 0)) {
        size_t lrow = (size_t)(b * L_ + l0 + i - 1);
        float b1 = Bn[lrow * NST + na]      + B_bias[h * NST + na];
        float b2 = Bn[lrow * NST + na + 32] + B_bias[h * NST + na + 32];
        float th = theta[(lrow * NH + h) * NA + na];
        float sn, cs; sincosf(th, &sn, &cs);
        k1 = b1 * cs - b2 * sn;
        k2 = b1 * sn + b2 * cs;
      }
      ushort_t h1 = f2bf(k1), h2 = f2bf(k2);
      st_bf16(KbH, i, 256, na * 2, h1);
      st_bf16(KbH, i, 256, (na + 32) * 2, h2);
      st_bf16(KbL, i, 256, na * 2, f2bf(k1 - bf2f(h1)));
      st_bf16(KbL, i, 256, (na + 32) * 2, f2bf(k2 - bf2f(h2)));
      if (i < 64) {
        float wc = cw[i];
        float kw1 = k1 * wc, kw2 = k2 * wc;
        ushort_t g1_ = f2bf(kw1), g2_ = f2bf(kw2);
        st_bf16(KTwH, na, 128, i * 2, g1_);
        st_bf16(KTwH, na + 32, 128, i * 2, g2_);
        st_bf16(KTwL, na, 128, i * 2, f2bf(kw1 - bf2f(g1_)));
        st_bf16(KTwL, na + 32, 128, i * 2, f2bf(kw2 - bf2f(g2_)));
      } else {
        float tw = w1s[63];
        ktail[na]      = k1 * tw;
        ktail[na + 32] = k2 * tw;
      }
    }
  }
#pragma unroll
  for (int k = 0; k < 5; ++k) {
    int f = t + k * 512;
    if (f < 65 * 32) {
      int i = f >> 5, e2 = f & 31;
      int n1 = 64 + 2 * e2;
      float v1 = 0.f, v2 = 0.f;
      if (!(i == 0 && c == 0)) {
        size_t lrow = (size_t)(b * L_ + l0 + i - 1);
        v1 = Bn[lrow * NST + n1]     + B_bias[h * NST + n1];
        v2 = Bn[lrow * NST + n1 + 1] + B_bias[h * NST + n1 + 1];
      }
      ushort_t h1 = f2bf(v1), h2 = f2bf(v2);
      st_bf16(KbH, i, 256, n1 * 2, h1);
      st_bf16(KbH, i, 256, (n1 + 1) * 2, h2);
      st_bf16(KbL, i, 256, n1 * 2, f2bf(v1 - bf2f(h1)));
      st_bf16(KbL, i, 256, (n1 + 1) * 2, f2bf(v2 - bf2f(h2)));
      if (i < 64) {
        float wc = cw[i];
        float kw1 = v1 * wc, kw2 = v2 * wc;
        ushort_t g1_ = f2bf(kw1), g2_ = f2bf(kw2);
        st_bf16(KTwH, n1, 128, i * 2, g1_);
        st_bf16(KTwH, n1 + 1, 128, i * 2, g2_);
        st_bf16(KTwL, n1, 128, i * 2, f2bf(kw1 - bf2f(g1_)));
        st_bf16(KTwL, n1 + 1, 128, i * 2, f2bf(kw2 - bf2f(g2_)));
      } else {
        float tw = w1s[63];
        ktail[n1]     = v1 * tw;
        ktail[n1 + 1] = v2 * tw;
      }
    }
  }
  {
    int p = t >> 3, jc = (t & 7) << 3;
    float r[9];
#pragma unroll
    for (int e = 0; e < 9; ++e) r[e] = xxs[jc + e][p];
    BF8 t0h, t0l, t1h, t1l;
#pragma unroll
    for (int e = 0; e < 8; ++e) {
      ushort_t hh = f2bf(r[e]);     t0h.u[e] = hh; t0l.u[e] = f2bf(r[e] - bf2f(hh));
      ushort_t gg = f2bf(r[e + 1]); t1h.u[e] = gg; t1l.u[e] = f2bf(r[e + 1] - bf2f(gg));
    }
    int cb = (jc * 2) ^ ((p & 7) << 4);
    *(uint4*)(xT0H + p * 128 + cb) = t0h.q;
    *(uint4*)(xT0L + p * 128 + cb) = t0l.q;
    *(uint4*)(xT1H + p * 128 + cb) = t1h.q;
    *(uint4*)(xT1L + p * 128 + cb) = t1l.q;
    if (jc == 56) xtail[p] = r[8];
  }
  __syncthreads();

  // ---------- phase 3: compute ----------
  const int lane = t & 63, wv = t >> 6;
  const int q4 = lane >> 4, l15 = lane & 15;
  const int Rr = (wv >> 1) << 4;
  const int Cb = (wv & 1) << 5;

  bf16x8 qh[4], ql[4];
#pragma unroll
  for (int ks = 0; ks < 4; ++ks) {
    int cb = ks * 64 + q4 * 16;
    qh[ks] = ldf(QbH, Rr + l15, 256, cb);
    ql[ks] = ldf(QbL, Rr + l15, 256, cb);
  }
  f32x4 s1a[2], s2a[2];
#pragma unroll
  for (int ct = 0; ct < 2; ++ct) { s1a[ct] = (f32x4){0.f,0.f,0.f,0.f}; s2a[ct] = (f32x4){0.f,0.f,0.f,0.f}; }

#pragma unroll
  for (int ct = 0; ct < 2; ++ct) {
    int jb = Cb + ct * 16 + l15;
#pragma unroll
    for (int ks = 0; ks < 4; ++ks) {
      int cb = ks * 64 + q4 * 16;
      bf16x8 kh1 = ldf(KbH, jb + 1, 256, cb);
      bf16x8 kl1 = ldf(KbL, jb + 1, 256, cb);
      s1a[ct] = __builtin_amdgcn_mfma_f32_16x16x32_bf16(qh[ks], kh1, s1a[ct], 0, 0, 0);
      s1a[ct] = __builtin_amdgcn_mfma_f32_16x16x32_bf16(qh[ks], kl1, s1a[ct], 0, 0, 0);
      s1a[ct] = __builtin_amdgcn_mfma_f32_16x16x32_bf16(ql[ks], kh1, s1a[ct], 0, 0, 0);
      bf16x8 kh0 = ldf(KbH, jb, 256, cb);
      bf16x8 kl0 = ldf(KbL, jb, 256, cb);
      s2a[ct] = __builtin_amdgcn_mfma_f32_16x16x32_bf16(qh[ks], kh0, s2a[ct], 0, 0, 0);
      s2a[ct] = __builtin_amdgcn_mfma_f32_16x16x32_bf16(qh[ks], kl0, s2a[ct], 0, 0, 0);
      s2a[ct] = __builtin_amdgcn_mfma_f32_16x16x32_bf16(ql[ks], kh0, s2a[ct], 0, 0, 0);
    }
  }

#pragma unroll
  for (int ct = 0; ct < 2; ++ct) {
    int j = Cb + ct * 16 + l15;
    float ej = ell[j], gj = g1s[j];
#pragma unroll
    for (int reg = 0; reg < 4; ++reg) {
      int i = Rr + q4 * 4 + reg;
      float v = (j <= i) ? s1a[ct][reg] * gj * expf(ell[i] - ej) : 0.0f;
      ushort_t hv = f2bf(v);
      st_bf16(SbH, i, 128, j * 2, hv);
      st_bf16(SbL, i, 128, j * 2, f2bf(v - bf2f(hv)));
    }
  }
  __syncthreads();

  f32x4 yacc[2];
  yacc[0] = (f32x4){0.f,0.f,0.f,0.f}; yacc[1] = (f32x4){0.f,0.f,0.f,0.f};
  {
    bf16x8 sh[2], sl[2];
#pragma unroll
    for (int ks = 0; ks < 2; ++ks) {
      int cb = ks * 64 + q4 * 16;
      sh[ks] = ldf(SbH, Rr + l15, 128, cb);
      sl[ks] = ldf(SbL, Rr + l15, 128, cb);
    }
#pragma unroll
    for (int pt = 0; pt < 2; ++pt) {
      int prow = Cb + pt * 16 + l15;
#pragma unroll
      for (int ks = 0; ks < 2; ++ks) {
        int cb = ks * 64 + q4 * 16;
        bf16x8 xh = ldf(xT1H, prow, 128, cb);
        bf16x8 xl = ldf(xT1L, prow, 128, cb);
        yacc[pt] = __builtin_amdgcn_mfma_f32_16x16x32_bf16(sh[ks], xh, yacc[pt], 0, 0, 0);
        yacc[pt] = __builtin_amdgcn_mfma_f32_16x16x32_bf16(sh[ks], xl, yacc[pt], 0, 0, 0);
        yacc[pt] = __builtin_amdgcn_mfma_f32_16x16x32_bf16(sl[ks], xh, yacc[pt], 0, 0, 0);
      }
    }
  }
  __syncthreads();

#pragma unroll
  for (int ct = 0; ct < 2; ++ct) {
    int j = Cb + ct * 16 + l15;
    float ej = ell[j], gj = g2s[j];
#pragma unroll
    for (int reg = 0; reg < 4; ++reg) {
      int i = Rr + q4 * 4 + reg;
      float v = (j <= i) ? s2a[ct][reg] * gj * expf(ell[i] - ej) : 0.0f;
      ushort_t hv = f2bf(v);
      st_bf16(SbH, i, 128, j * 2, hv);
      st_bf16(SbL, i, 128, j * 2, f2bf(v - bf2f(hv)));
    }
  }
  __syncthreads();

  {
    bf16x8 sh[2], sl[2];
#pragma unroll
    for (int ks = 0; ks < 2; ++ks) {
      int cb = ks * 64 + q4 * 16;
      sh[ks] = ldf(SbH, Rr + l15, 128, cb);
      sl[ks] = ldf(SbL, Rr + l15, 128, cb);
    }
#pragma unroll
    for (int pt = 0; pt < 2; ++pt) {
      int prow = Cb + pt * 16 + l15;
#pragma unroll
      for (int ks = 0; ks < 2; ++ks) {
        int cb = ks * 64 + q4 * 16;
        bf16x8 xh = ldf(xT0H, prow, 128, cb);
        bf16x8 xl = ldf(xT0L, prow, 128, cb);
        yacc[pt] = __builtin_amdgcn_mfma_f32_16x16x32_bf16(sh[ks], xh, yacc[pt], 0, 0, 0);
        yacc[pt] = __builtin_amdgcn_mfma_f32_16x16x32_bf16(sh[ks], xl, yacc[pt], 0, 0, 0);
        yacc[pt] = __builtin_amdgcn_mfma_f32_16x16x32_bf16(sl[ks], xh, yacc[pt], 0, 0, 0);
      }
    }
  }
  // y_intra store (bf16 hi/lo)
#pragma unroll
  for (int pt = 0; pt < 2; ++pt) {
    int p = Cb + pt * 16 + l15;
#pragma unroll
    for (int reg = 0; reg < 4; ++reg) {
      int i = Rr + q4 * 4 + reg;
      size_t idx = (size_t)(b * L_ + l0 + i) * DIN + h * HD + p;
      float v = yacc[pt][reg];
      ushort_t hv = f2bf(v);
      yh[idx] = hv;
      yl[idx] = f2bf(v - bf2f(hv));
    }
  }

  // WsumT[p][n]
  {
    const int Pw = (wv >> 1) << 4;
    const int Nb = (wv & 1) << 6;
    f32x4 wacc[4];
#pragma unroll
    for (int nt = 0; nt < 4; ++nt) wacc[nt] = (f32x4){0.f,0.f,0.f,0.f};
    bf16x8 axh[2], axl[2];
#pragma unroll
    for (int ks = 0; ks < 2; ++ks) {
      int cb = ks * 64 + q4 * 16;
      axh[ks] = ldf(xT0H, Pw + l15, 128, cb);
      axl[ks] = ldf(xT0L, Pw + l15, 128, cb);
    }
#pragma unroll
    for (int nt = 0; nt < 4; ++nt) {
      int nrow = Nb + nt * 16 + l15;
#pragma unroll
      for (int ks = 0; ks < 2; ++ks) {
        int cb = ks * 64 + q4 * 16;
        bf16x8 bh = ldf(KTwH, nrow, 128, cb);
        bf16x8 bl = ldf(KTwL, nrow, 128, cb);
        wacc[nt] = __builtin_amdgcn_mfma_f32_16x16x32_bf16(axh[ks], bh, wacc[nt], 0, 0, 0);
        wacc[nt] = __builtin_amdgcn_mfma_f32_16x16x32_bf16(axh[ks], bl, wacc[nt], 0, 0, 0);
        wacc[nt] = __builtin_amdgcn_mfma_f32_16x16x32_bf16(axl[ks], bh, wacc[nt], 0, 0, 0);
      }
    }
    size_t wbase = ((size_t)(b * NC + c) * NH + h) * (size_t)(NST * HD);
#pragma unroll
    for (int nt = 0; nt < 4; ++nt) {
      int n = Nb + nt * 16 + l15;
      float kt = ktail[n];
#pragma unroll
      for (int reg = 0; reg < 4; ++reg) {
        int p = Pw + q4 * 4 + reg;
        WsT[wbase + (size_t)p * NST + n] = wacc[nt][reg] + xtail[p] * kt;
      }
    }
  }
}

// ---------------- P5: state scan ----------------
__global__ __launch_bounds__(256) void state_scan_kernel(
    float* __restrict__ Wsum, const float* __restrict__ cdg) {
  const int b = blockIdx.x >> 5;
  const int h = blockIdx.x & 31;
  float Hst[32];
#pragma unroll
  for (int k = 0; k < 32; ++k) Hst[k] = 0.0f;
  for (int c = 0; c < NC; ++c) {
    float cd = cdg[((size_t)b * NC + c) * NH + h];
    float* wp = Wsum + ((size_t)(b * NC + c) * NH + h) * (size_t)(NST * HD);
#pragma unroll
    for (int k = 0; k < 32; ++k) {
      int e = threadIdx.x + k * 256;
      float w  = wp[e];
      float hv = Hst[k];
      wp[e]    = hv;
      Hst[k]   = fmaf(cd, hv, w);
    }
  }
}

// ---------------- P6: finalize ----------------
__global__ __launch_bounds__(256) void finalize_kernel(
    const float* __restrict__ proj, const float* __restrict__ Cn,
    const float* __restrict__ theta, const float* __restrict__ C_bias,
    const float* __restrict__ Hprev, const float* __restrict__ adtg,
    const float* __restrict__ dvec,
    ushort_t* __restrict__ yh, ushort_t* __restrict__ yl) {
  const int h  = blockIdx.x & 31;
  const int c  = (blockIdx.x >> 5) & 31;
  const int b  = blockIdx.x >> 10;
  const int t  = threadIdx.x;
  const int l0 = c * CHK;

  __shared__ float Qs[64][132];
  __shared__ float HsT[64][132];
  __shared__ float ell[64];

#pragma unroll
  for (int k = 0; k < 8; ++k) {
    int f = t + k * 256;
    int i = f >> 5, n = (f & 31) << 2;
    F4 v, bb;
    v.v  = *(const float4*)(Cn + (size_t)(b * L_ + l0 + i) * NST + n);
    bb.v = *(const float4*)(C_bias + h * NST + n);
#pragma unroll
    for (int q = 0; q < 4; ++q) v.a[q] += bb.a[q];
    *(float4*)&Qs[i][n] = v.v;
  }
  {
    const float* hp = Hprev + ((size_t)(b * NC + c) * NH + h) * (size_t)(NST * HD);
#pragma unroll
    for (int k = 0; k < 8; ++k) {
      int f = t + k * 256;
      int p = f >> 5, n4 = (f & 31) << 2;
      *(float4*)&HsT[p][n4] = *(const float4*)(hp + (size_t)p * NST + n4);
    }
  }
  if (t < 64) {
    float v = adtg[((size_t)b * NH + h) * L_ + l0 + t];
#pragma unroll
    for (int off = 1; off < 64; off <<= 1) {
      float u = __shfl_up(v, off, 64);
      if (t >= off) v += u;
    }
    ell[t] = v;
  }
  __syncthreads();

#pragma unroll
  for (int k = 0; k < 8; ++k) {
    int f = t + k * 256;
    int i = f >> 5, na = f & 31;
    float th = theta[((size_t)(b * L_ + l0 + i) * NH + h) * NA + na];
    float sn, cs;
    sincosf(th, &sn, &cs);
    float q1 = Qs[i][na], q2 = Qs[i][na + 32];
    Qs[i][na]      = q1 * cs - q2 * sn;
    Qs[i][na + 32] = q1 * sn + q2 * cs;
  }
  __syncthreads();

  const int i0 = (t >> 4) << 2, p0 = (t & 15) << 2;
  float acc[4][4];
#pragma unroll
  for (int r = 0; r < 4; ++r)
#pragma unroll
    for (int p = 0; p < 4; ++p) acc[r][p] = 0.0f;

  for (int n4 = 0; n4 < 32; ++n4) {
    F4 qa[4], hb[4];
#pragma unroll
    for (int r = 0; r < 4; ++r)  qa[r].v = *(const float4*)&Qs[i0 + r][n4 << 2];
#pragma unroll
    for (int pp = 0; pp < 4; ++pp) hb[pp].v = *(const float4*)&HsT[p0 + pp][n4 << 2];
#pragma unroll
    for (int r = 0; r < 4; ++r)
#pragma unroll
      for (int pp = 0; pp < 4; ++pp) {
        acc[r][pp] = fmaf(qa[r].a[0], hb[pp].a[0], acc[r][pp]);
        acc[r][pp] = fmaf(qa[r].a[1], hb[pp].a[1], acc[r][pp]);
        acc[r][pp] = fmaf(qa[r].a[2], hb[pp].a[2], acc[r][pp]);
        acc[r][pp] = fmaf(qa[r].a[3], hb[pp].a[3], acc[r][pp]);
      }
  }

  const float Dv = dvec[h];
#pragma unroll
  for (int r = 0; r < 4; ++r) {
    const int l = l0 + i0 + r;
    const float e = expf(ell[i0 + r]);
    const size_t rowoff = (size_t)(b * L_ + l);
    const size_t yidx = rowoff * DIN + h * HD + p0;
    US4 yhv, ylv, oh, ol;
    yhv.v = *(const ushort4*)(yh + yidx);
    ylv.v = *(const ushort4*)(yl + yidx);
    F4 xv, zv;
    xv.v = *(const float4*)(proj + rowoff * DPROJ + OFF_X + h * HD + p0);
    zv.v = *(const float4*)(proj + rowoff * DPROJ + OFF_Z + h * HD + p0);
#pragma unroll
    for (int p = 0; p < 4; ++p) {
      float yi = bf2f(yhv.a[p]) + bf2f(ylv.a[p]);
      float z = zv.a[p];
      float o = (yi + e * acc[r][p] + Dv * xv.a[p]) * (z * sigmoidf_(z));
      ushort_t hv = f2bf(o);
      oh.a[p] = hv;
      ol.a[p] = f2bf(o - bf2f(hv));
    }
    *(ushort4*)(yh + yidx) = oh.v;
    *(ushort4*)(yl + yidx) = ol.v;
  }
}

__global__ void zero_out_kernel(float* __restrict__ out, int n) {
  int i = blockIdx.x * 256 + threadIdx.x;
  if (i < n) out[i] = 0.0f;
}

extern "C" void kernel_launch(void* const* d_in, const int* in_sizes, int n_in,
                              void* d_out, int out_size, void* d_ws, size_t ws_size,
                              hipStream_t stream) {
  const float* u        = (const float*)d_in[0];
  const float* W_in     = (const float*)d_in[1];
  const float* W_out    = (const float*)d_in[2];
  const float* dt_bias  = (const float*)d_in[3];
  const float* B_bias   = (const float*)d_in[4];
  const float* C_bias   = (const float*)d_in[5];
  const float* B_norm_w = (const float*)d_in[6];
  const float* C_norm_w = (const float*)d_in[7];
  const float* Dv       = (const float*)d_in[8];
  float* out = (float*)d_out;
  float* ws  = (float*)d_ws;

  size_t o = 0;
  float* proj  = ws + o; o += (size_t)B_ * L_ * DPROJ;
  float* Bn    = ws + o; o += (size_t)B_ * L_ * NST;
  float* Cn    = ws + o; o += (size_t)B_ * L_ * NST;
  float* dtg   = ws + o; o += (size_t)B_ * NH * L_;
  float* adtg  = ws + o; o += (size_t)B_ * NH * L_;
  float* g1g   = ws + o; o += (size_t)B_ * NH * L_;
  float* g2g   = ws + o; o += (size_t)B_ * NH * L_;
  float* theta = ws + o; o += (size_t)B_ * L_ * NH * NA;
  float* Wsum  = ws + o; o += (size_t)B_ * NC * NH * NST * HD;
  float* cdg   = ws + o; o += (size_t)B_ * NC * NH;
  float* yreg  = ws + o; o += (size_t)B_ * L_ * DIN;   // holds yh|yl (bf16 hi/lo)
  ushort_t* Wth = (ushort_t*)(ws + o); o += (size_t)DPROJ * DM / 2;
  ushort_t* Wtl = (ushort_t*)(ws + o); o += (size_t)DPROJ * DM / 2;
  ushort_t* Woh = (ushort_t*)(ws + o); o += (size_t)DM * DIN / 2;
  ushort_t* Wol = (ushort_t*)(ws + o); o += (size_t)DM * DIN / 2;

  ushort_t* yh = (ushort_t*)yreg;
  ushort_t* yl = yh + (size_t)B_ * L_ * DIN;
  ushort_t* uh = yh;   // aliases: used only before chunk_kernel overwrites y
  ushort_t* ul = yl;

  if (ws_size < o * sizeof(float)) {
    zero_out_kernel<<<(out_size + 255) / 256, 256, 0, stream>>>(out, out_size);
    return;
  }

  tsplit_kernel<<<dim3(DPROJ / 64, DM / 64), 256, 0, stream>>>(W_in, Wth, Wtl, DM, DPROJ);
  tsplit_kernel<<<dim3(DM / 64, DIN / 64), 256, 0, stream>>>(W_out, Woh, Wol, DIN, DM);
  split_kernel<<<(B_ * L_ * DM / 8 + 255) / 256, 256, 0, stream>>>(
      u, uh, ul, B_ * L_ * DM / 8);
  gemm_glds<<<(DPROJ / 128) * ((B_ * L_) / 128), 256, 0, stream>>>(
      uh, ul, Wth, Wtl, proj, B_ * L_, DPROJ, DM, DPROJ / 128);
  pointwise_kernel<<<B_ * L_, 128, 0, stream>>>(
      proj, dt_bias, B_norm_w, C_norm_w, Bn, Cn, dtg, adtg, g1g, g2g);
  theta_kernel<<<B_ * NH, 64, 0, stream>>>(proj, dtg, theta);
  chunk_kernel<<<B_ * NC * NH, 512, 0, stream>>>(
      proj, Bn, Cn, theta, B_bias, C_bias, adtg, g1g, g2g, Wsum, cdg, yh, yl);
  state_scan_kernel<<<B_ * NH, 256, 0, stream>>>(Wsum, cdg);
  finalize_kernel<<<B_ * NC * NH, 256, 0, stream>>>(
      proj, Cn, theta, C_bias, Wsum, adtg, Dv, yh, yl);
  gemm_glds<<<(DM / 128) * ((B_ * L_) / 128), 256, 0, stream>>>(
      yh, yl, Woh, Wol, out, B_ * L_, DM, DIN, DM / 128);
}

// Round 6
// 519.199 us; speedup vs baseline: 2.4572x; 1.1610x over previous
//
#include <hip/hip_runtime.h>
#include <math.h>

#define B_    2
#define L_    2048
#define DM    1024
#define DIN   2048
#define NH    32
#define HD    64
#define NST   128
#define NA    32
#define NC    32
#define CHK   64
#define DPROJ 4480

#define OFF_Z    0
#define OFF_X    2048
#define OFF_BG   4096
#define OFF_CG   4224
#define OFF_DDT  4352
#define OFF_DDA  4384
#define OFF_TRAP 4416
#define OFF_ANG  4448

typedef union { float4 v; float a[4]; } F4;
typedef unsigned short ushort_t;
typedef union { ushort4 v; ushort_t a[4]; } US4;
typedef __attribute__((ext_vector_type(8))) short bf16x8;
typedef __attribute__((ext_vector_type(4))) float f32x4;
typedef union { bf16x8 v; ushort_t u[8]; uint4 q; } BF8;

__device__ __forceinline__ float softplusf_(float x) {
  return (x > 20.0f) ? x : log1pf(expf(x));
}
__device__ __forceinline__ float sigmoidf_(float x) {
  return 1.0f / (1.0f + expf(-x));
}
__device__ __forceinline__ ushort_t f2bf(float x) {
  union { float f; unsigned u; } v; v.f = x;
  unsigned r = v.u + 0x7fffu + ((v.u >> 16) & 1u);
  return (ushort_t)(r >> 16);
}
__device__ __forceinline__ float bf2f(ushort_t h) {
  union { unsigned u; float f; } v; v.u = ((unsigned)h) << 16;
  return v.f;
}
__device__ __forceinline__ bf16x8 ldf(const char* base, int row, int stride, int cb) {
  return *(const bf16x8*)(base + row * stride + (cb ^ ((row & 7) << 4)));
}
__device__ __forceinline__ void st_bf16(char* base, int row, int stride, int colb, ushort_t v) {
  *(ushort_t*)(base + row * stride + (colb ^ ((row & 7) << 4))) = v;
}
__device__ __forceinline__ void glds16(const void* g, void* l) {
  __builtin_amdgcn_global_load_lds(
      (const __attribute__((address_space(1))) void*)g,
      (__attribute__((address_space(3))) void*)l, 16, 0, 0);
}

// ---------------- transpose+split: src[Kd][Nd] f32 -> hi/lo [Nd][Kd] bf16 ----------------
__global__ __launch_bounds__(256) void tsplit_kernel(
    const float* __restrict__ src, ushort_t* __restrict__ hi,
    ushort_t* __restrict__ lo, int Kd, int Nd) {
  __shared__ float tile[64][65];
  const int k0 = blockIdx.y * 64, n0 = blockIdx.x * 64;
  const int t = threadIdx.x;
  {
    const int r = t >> 4, c4 = (t & 15) << 2;
#pragma unroll
    for (int rr = 0; rr < 4; ++rr) {
      F4 v; v.v = *(const float4*)(src + (size_t)(k0 + r + rr * 16) * Nd + n0 + c4);
      tile[r + rr * 16][c4] = v.a[0]; tile[r + rr * 16][c4 + 1] = v.a[1];
      tile[r + rr * 16][c4 + 2] = v.a[2]; tile[r + rr * 16][c4 + 3] = v.a[3];
    }
  }
  __syncthreads();
  const int n = t >> 2, kc = (t & 3) << 4;
  BF8 h0, h1, l0, l1;
#pragma unroll
  for (int e = 0; e < 8; ++e) {
    float x = tile[kc + e][n];
    ushort_t h = f2bf(x); h0.u[e] = h; l0.u[e] = f2bf(x - bf2f(h));
    float y = tile[kc + 8 + e][n];
    ushort_t g = f2bf(y); h1.u[e] = g; l1.u[e] = f2bf(y - bf2f(g));
  }
  size_t ob = (size_t)(n0 + n) * Kd + k0 + kc;
  *(uint4*)(hi + ob) = h0.q; *(uint4*)(hi + ob + 8) = h1.q;
  *(uint4*)(lo + ob) = l0.q; *(uint4*)(lo + ob + 8) = l1.q;
}

// ---------------- elementwise split: f32 -> hi/lo bf16 ----------------
__global__ __launch_bounds__(256) void split_kernel(
    const float* __restrict__ src, ushort_t* __restrict__ hi,
    ushort_t* __restrict__ lo, int n8) {
  int i = blockIdx.x * 256 + threadIdx.x;
  if (i >= n8) return;
  const float* p = src + (size_t)i * 8;
  F4 a, b; a.v = *(const float4*)p; b.v = *(const float4*)(p + 4);
  BF8 h, l;
#pragma unroll
  for (int e = 0; e < 4; ++e) {
    ushort_t hh = f2bf(a.a[e]); h.u[e] = hh; l.u[e] = f2bf(a.a[e] - bf2f(hh));
    ushort_t gg = f2bf(b.a[e]); h.u[e + 4] = gg; l.u[e + 4] = f2bf(b.a[e] - bf2f(gg));
  }
  *(uint4*)(hi + (size_t)i * 8) = h.q;
  *(uint4*)(lo + (size_t)i * 8) = l.q;
}

// ---------------- MFMA GEMM, global_load_lds staging, 3-pass split-bf16 ----------------
__global__ __launch_bounds__(256) void gemm_glds(
    const ushort_t* __restrict__ Ah, const ushort_t* __restrict__ Al,
    const ushort_t* __restrict__ Bth, const ushort_t* __restrict__ Btl,
    float* __restrict__ C, int M, int N, int K, int nbx) {
  __shared__ __align__(16) char ldsA[16384], ldsB[16384];
  const int nwg = gridDim.x;
  const int q8 = nwg >> 3;
  const int swz = (blockIdx.x & 7) * q8 + (blockIdx.x >> 3);
  const int bm = (swz / nbx) << 7, bn = (swz % nbx) << 7;
  const int t = threadIdx.x, w = t >> 6, lane = t & 63;

  const size_t K2 = (size_t)K << 1;
  const int swl = (lane >> 3) << 4;
  const int cA = ((lane & 7) << 4) ^ swl;
  const int rl = (w << 5) + (lane >> 3);
  const char* gA = (cA < 64 ? (const char*)Ah + cA : (const char*)Al + (cA - 64))
                   + (size_t)(bm + rl) * K2;
  const char* gB = (cA < 64 ? (const char*)Bth + cA : (const char*)Btl + (cA - 64))
                   + (size_t)(bn + rl) * K2;
  const size_t istep = K2 << 3;
  char* dA = ldsA + (w << 12);
  char* dB = ldsB + (w << 12);

  const int wm = (w >> 1) << 6, wn = (w & 1) << 6;
  const int lr = lane & 15, cb = (lane >> 4) << 4;

  f32x4 acc[4][4];
#pragma unroll
  for (int i = 0; i < 4; ++i)
#pragma unroll
    for (int j = 0; j < 4; ++j) acc[i][j] = (f32x4){0.f, 0.f, 0.f, 0.f};

#define STAGE(k0) do {                                                  \
    size_t kb = (size_t)(k0) << 1;                                      \
    glds16(gA + kb,             dA);                                    \
    glds16(gA + kb + istep,     dA + 1024);                             \
    glds16(gA + kb + 2 * istep, dA + 2048);                             \
    glds16(gA + kb + 3 * istep, dA + 3072);                             \
    glds16(gB + kb,             dB);                                    \
    glds16(gB + kb + istep,     dB + 1024);                             \
    glds16(gB + kb + 2 * istep, dB + 2048);                             \
    glds16(gB + kb + 3 * istep, dB + 3072);                             \
  } while (0)

  STAGE(0);
  for (int k0 = 0; k0 < K; k0 += 32) {
    __syncthreads();
    bf16x8 ah[4], al[4], bh[4], bl[4];
#pragma unroll
    for (int mf = 0; mf < 4; ++mf) {
      int r2 = wm + (mf << 4) + lr;
      int sw2 = (r2 & 7) << 4;
      ah[mf] = *(const bf16x8*)(ldsA + (r2 << 7) + (cb ^ sw2));
      al[mf] = *(const bf16x8*)(ldsA + (r2 << 7) + ((cb + 64) ^ sw2));
    }
#pragma unroll
    for (int nf = 0; nf < 4; ++nf) {
      int r2 = wn + (nf << 4) + lr;
      int sw2 = (r2 & 7) << 4;
      bh[nf] = *(const bf16x8*)(ldsB + (r2 << 7) + (cb ^ sw2));
      bl[nf] = *(const bf16x8*)(ldsB + (r2 << 7) + ((cb + 64) ^ sw2));
    }
#pragma unroll
    for (int mf = 0; mf < 4; ++mf)
#pragma unroll
      for (int nf = 0; nf < 4; ++nf) {
        acc[mf][nf] = __builtin_amdgcn_mfma_f32_16x16x32_bf16(ah[mf], bh[nf], acc[mf][nf], 0, 0, 0);
        acc[mf][nf] = __builtin_amdgcn_mfma_f32_16x16x32_bf16(ah[mf], bl[nf], acc[mf][nf], 0, 0, 0);
        acc[mf][nf] = __builtin_amdgcn_mfma_f32_16x16x32_bf16(al[mf], bh[nf], acc[mf][nf], 0, 0, 0);
      }
    __syncthreads();
    if (k0 + 32 < K) STAGE(k0 + 32);
  }
#undef STAGE

  const int rsub = (lane >> 4) << 2;
#pragma unroll
  for (int mf = 0; mf < 4; ++mf)
#pragma unroll
    for (int nf = 0; nf < 4; ++nf) {
      float* cp = C + (size_t)(bm + wm + mf * 16 + rsub) * N + bn + wn + nf * 16 + lr;
#pragma unroll
      for (int j = 0; j < 4; ++j) cp[(size_t)j * N] = acc[mf][nf][j];
    }
}

// ---------------- P2: per-(b,l) pointwise ----------------
__global__ __launch_bounds__(128) void pointwise_kernel(
    const float* __restrict__ proj, const float* __restrict__ dt_bias,
    const float* __restrict__ Bnw, const float* __restrict__ Cnw,
    float* __restrict__ Bn, float* __restrict__ Cn,
    float* __restrict__ dtg, float* __restrict__ adtg,
    float* __restrict__ g1g, float* __restrict__ g2g) {
  const int bl = blockIdx.x;
  const int l  = bl & (L_ - 1);
  const int b  = bl >> 11;
  const int t  = threadIdx.x;
  const float* row = proj + (size_t)bl * DPROJ;

  float vb = row[OFF_BG + t];
  float vc = row[OFF_CG + t];
  float sb = vb * vb, sc = vc * vc;
#pragma unroll
  for (int off = 32; off >= 1; off >>= 1) {
    sb += __shfl_xor(sb, off, 64);
    sc += __shfl_xor(sc, off, 64);
  }
  __shared__ float red[4];
  if ((t & 63) == 0) { red[t >> 6] = sb; red[2 + (t >> 6)] = sc; }
  __syncthreads();
  sb = red[0] + red[1];
  sc = red[2] + red[3];
  float rb = rsqrtf(sb * (1.0f / 128.0f) + 1e-5f);
  float rc = rsqrtf(sc * (1.0f / 128.0f) + 1e-5f);
  Bn[(size_t)bl * NST + t] = vb * rb * Bnw[t];
  Cn[(size_t)bl * NST + t] = vc * rc * Cnw[t];

  if (t < NH) {
    const int h = t;
    float dt = softplusf_(row[OFF_DDT + h] + dt_bias[h]);
    float a  = -softplusf_(row[OFF_DDA + h]);
    a = fminf(a, -1e-4f);
    float adt  = a * dt;
    float beta = sigmoidf_(row[OFF_TRAP + h]);
    float dtp  = 0.0f;
    if (l > 0) dtp = softplusf_(proj[(size_t)(bl - 1) * DPROJ + OFF_DDT + h] + dt_bias[h]);
    float g2 = (1.0f - beta) * expf(adt) * dtp;
    size_t idx = ((size_t)b * NH + h) * L_ + l;
    dtg[idx]  = dt;
    adtg[idx] = adt;
    g1g[idx]  = beta * dt;
    g2g[idx]  = g2;
  }
}

// ---------------- P3: theta via segmented scan (16 segs x 128, 512 threads) ----------------
__global__ __launch_bounds__(512) void theta_kernel(
    const float* __restrict__ proj, const float* __restrict__ dtg,
    float* __restrict__ theta) {
  const int b  = blockIdx.x >> 5;
  const int h  = blockIdx.x & 31;
  const int t  = threadIdx.x;
  const int na = t & 31, seg = t >> 5;
  const int l0 = seg << 7;
  const float* ap = proj + (size_t)b * L_ * DPROJ + OFF_ANG + na;
  const float* dp = dtg + ((size_t)b * NH + h) * L_;
  __shared__ float segsum[16][33];

  float s = 0.0f;
#pragma unroll 8
  for (int l = l0; l < l0 + 128; ++l)
    s = fmaf(ap[(size_t)l * DPROJ], dp[l], s);
  segsum[seg][na] = s;
  __syncthreads();
  if (t < 32) {
    float run = 0.0f;
#pragma unroll
    for (int sg = 0; sg < 16; ++sg) {
      float v = segsum[sg][t];
      segsum[sg][t] = run;
      run += v;
    }
  }
  __syncthreads();
  float th = segsum[seg][na];
  float* tp = theta + ((size_t)b * L_ * NH + h) * NA + na;
#pragma unroll 8
  for (int l = l0; l < l0 + 128; ++l) {
    th = fmaf(ap[(size_t)l * DPROJ], dp[l], th);
    tp[(size_t)l * NH * NA] = th;
  }
}

// ---------------- P4: MFMA chunk kernel (512 threads) ----------------
__global__ __launch_bounds__(512, 1) void chunk_kernel(
    const float* __restrict__ proj,
    const float* __restrict__ Bn, const float* __restrict__ Cn,
    const float* __restrict__ theta,
    const float* __restrict__ B_bias, const float* __restrict__ C_bias,
    const float* __restrict__ adtg, const float* __restrict__ g1g,
    const float* __restrict__ g2g,
    float* __restrict__ WsT, float* __restrict__ cdg,
    ushort_t* __restrict__ yh, ushort_t* __restrict__ yl) {
  const int h  = blockIdx.x & 31;
  const int c  = (blockIdx.x >> 5) & 31;
  const int b  = blockIdx.x >> 10;
  const int t  = threadIdx.x;
  const int l0 = c * CHK;

  __shared__ __align__(16) char QbH[16384], QbL[16384];
  __shared__ __align__(16) char KbH[16640], KbL[16640];
  __shared__ __align__(16) char KTwH[16384], KTwL[16384];
  __shared__ __align__(16) char xT0H[8192], xT0L[8192];
  __shared__ __align__(16) char xT1H[8192], xT1L[8192];
  __shared__ __align__(16) char Ubuf[17680];
  __shared__ float ell[64], g1s[64], g2s[64], w1s[64], cw[64], xtail[64], ktail[128];
  float (*xxs)[68] = (float(*)[68])Ubuf;
  char* SbH = Ubuf;
  char* SbL = Ubuf + 8192;

  // ---------- phase 1 ----------
  if (t < 64) {
    size_t idx = ((size_t)b * NH + h) * L_ + l0 + t;
    float adt = adtg[idx], g1 = g1g[idx], g2 = g2g[idx];
    float v = adt;
#pragma unroll
    for (int off = 1; off < 64; off <<= 1) {
      float u = __shfl_up(v, off, 64);
      if (t >= off) v += u;
    }
    ell[t] = v;
    float last = __shfl(v, 63, 64);
    float de = expf(last - v);
    float w1 = g1 * de, w2 = g2 * de;
    g1s[t] = g1; g2s[t] = g2; w1s[t] = w1;
    float w1p = __shfl_up(w1, 1, 64);
    cw[t] = (t >= 1 ? w1p : 0.0f) + w2;
    if (t == 63) cdg[((size_t)b * NC + c) * NH + h] = expf(v);
  }
#pragma unroll
  for (int k = 0; k < 4; ++k) {
    int f = t + k * 512;
    int i = f >> 5, na = f & 31;
    size_t lrow = (size_t)(b * L_ + l0 + i);
    float c1 = Cn[lrow * NST + na]      + C_bias[h * NST + na];
    float c2 = Cn[lrow * NST + na + 32] + C_bias[h * NST + na + 32];
    float th = theta[(lrow * NH + h) * NA + na];
    float sn, cs; sincosf(th, &sn, &cs);
    float q1 = c1 * cs - c2 * sn;
    float q2 = c1 * sn + c2 * cs;
    ushort_t h1 = f2bf(q1), h2 = f2bf(q2);
    st_bf16(QbH, i, 256, na * 2, h1);
    st_bf16(QbH, i, 256, (na + 32) * 2, h2);
    st_bf16(QbL, i, 256, na * 2, f2bf(q1 - bf2f(h1)));
    st_bf16(QbL, i, 256, (na + 32) * 2, f2bf(q2 - bf2f(h2)));
  }
#pragma unroll
  for (int k = 0; k < 4; ++k) {
    int f = t + k * 512;
    int i = f >> 5, e2 = f & 31;
    int n1 = 64 + 2 * e2;
    size_t lrow = (size_t)(b * L_ + l0 + i);
    float v1 = Cn[lrow * NST + n1]     + C_bias[h * NST + n1];
    float v2 = Cn[lrow * NST + n1 + 1] + C_bias[h * NST + n1 + 1];
    ushort_t h1 = f2bf(v1), h2 = f2bf(v2);
    st_bf16(QbH, i, 256, n1 * 2, h1);
    st_bf16(QbH, i, 256, (n1 + 1) * 2, h2);
    st_bf16(QbL, i, 256, n1 * 2, f2bf(v1 - bf2f(h1)));
    st_bf16(QbL, i, 256, (n1 + 1) * 2, f2bf(v2 - bf2f(h2)));
  }
#pragma unroll
  for (int k = 0; k < 3; ++k) {
    int f = t + k * 512;
    if (f < 65 * 16) {
      int i = f >> 4, p4 = (f & 15) << 2;
      float4 v;
      if (i == 0 && c == 0) v = make_float4(0.f, 0.f, 0.f, 0.f);
      else v = *(const float4*)(proj + (size_t)(b * L_ + l0 + i - 1) * DPROJ + OFF_X + h * HD + p4);
      *(float4*)&xxs[i][p4] = v;
    }
  }
  __syncthreads();

  // ---------- phase 2 ----------
#pragma unroll
  for (int k = 0; k < 5; ++k) {
    int f = t + k * 512;
    if (f < 65 * 32) {
      int i = f >> 5, na = f & 31;
      float k1 = 0.f, k2 = 0.f;
      if (!(i == 0 && c == 0)) {
        size_t lrow = (size_t)(b * L_ + l0 + i - 1);
        float b1 = Bn[lrow * NST + na]      + B_bias[h * NST + na];
        float b2 = Bn[lrow * NST + na + 32] + B_bias[h * NST + na + 32];
        float th = theta[(lrow * NH + h) * NA + na];
        float sn, cs; sincosf(th, &sn, &cs);
        k1 = b1 * cs - b2 * sn;
        k2 = b1 * sn + b2 * cs;
      }
      ushort_t h1 = f2bf(k1), h2 = f2bf(k2);
      st_bf16(KbH, i, 256, na * 2, h1);
      st_bf16(KbH, i, 256, (na + 32) * 2, h2);
      st_bf16(KbL, i, 256, na * 2, f2bf(k1 - bf2f(h1)));
      st_bf16(KbL, i, 256, (na + 32) * 2, f2bf(k2 - bf2f(h2)));
      if (i < 64) {
        float wc = cw[i];
        float kw1 = k1 * wc, kw2 = k2 * wc;
        ushort_t g1_ = f2bf(kw1), g2_ = f2bf(kw2);
        st_bf16(KTwH, na, 128, i * 2, g1_);
        st_bf16(KTwH, na + 32, 128, i * 2, g2_);
        st_bf16(KTwL, na, 128, i * 2, f2bf(kw1 - bf2f(g1_)));
        st_bf16(KTwL, na + 32, 128, i * 2, f2bf(kw2 - bf2f(g2_)));
      } else {
        float tw = w1s[63];
        ktail[na]      = k1 * tw;
        ktail[na + 32] = k2 * tw;
      }
    }
  }
#pragma unroll
  for (int k = 0; k < 5; ++k) {
    int f = t + k * 512;
    if (f < 65 * 32) {
      int i = f >> 5, e2 = f & 31;
      int n1 = 64 + 2 * e2;
      float v1 = 0.f, v2 = 0.f;
      if (!(i == 0 && c == 0)) {
        size_t lrow = (size_t)(b * L_ + l0 + i - 1);
        v1 = Bn[lrow * NST + n1]     + B_bias[h * NST + n1];
        v2 = Bn[lrow * NST + n1 + 1] + B_bias[h * NST + n1 + 1];
      }
      ushort_t h1 = f2bf(v1), h2 = f2bf(v2);
      st_bf16(KbH, i, 256, n1 * 2, h1);
      st_bf16(KbH, i, 256, (n1 + 1) * 2, h2);
      st_bf16(KbL, i, 256, n1 * 2, f2bf(v1 - bf2f(h1)));
      st_bf16(KbL, i, 256, (n1 + 1) * 2, f2bf(v2 - bf2f(h2)));
      if (i < 64) {
        float wc = cw[i];
        float kw1 = v1 * wc, kw2 = v2 * wc;
        ushort_t g1_ = f2bf(kw1), g2_ = f2bf(kw2);
        st_bf16(KTwH, n1, 128, i * 2, g1_);
        st_bf16(KTwH, n1 + 1, 128, i * 2, g2_);
        st_bf16(KTwL, n1, 128, i * 2, f2bf(kw1 - bf2f(g1_)));
        st_bf16(KTwL, n1 + 1, 128, i * 2, f2bf(kw2 - bf2f(g2_)));
      } else {
        float tw = w1s[63];
        ktail[n1]     = v1 * tw;
        ktail[n1 + 1] = v2 * tw;
      }
    }
  }
  {
    int p = t >> 3, jc = (t & 7) << 3;
    float r[9];
#pragma unroll
    for (int e = 0; e < 9; ++e) r[e] = xxs[jc + e][p];
    BF8 t0h, t0l, t1h, t1l;
#pragma unroll
    for (int e = 0; e < 8; ++e) {
      ushort_t hh = f2bf(r[e]);     t0h.u[e] = hh; t0l.u[e] = f2bf(r[e] - bf2f(hh));
      ushort_t gg = f2bf(r[e + 1]); t1h.u[e] = gg; t1l.u[e] = f2bf(r[e + 1] - bf2f(gg));
    }
    int cb = (jc * 2) ^ ((p & 7) << 4);
    *(uint4*)(xT0H + p * 128 + cb) = t0h.q;
    *(uint4*)(xT0L + p * 128 + cb) = t0l.q;
    *(uint4*)(xT1H + p * 128 + cb) = t1h.q;
    *(uint4*)(xT1L + p * 128 + cb) = t1l.q;
    if (jc == 56) xtail[p] = r[8];
  }
  __syncthreads();

  // ---------- phase 3: compute ----------
  const int lane = t & 63, wv = t >> 6;
  const int q4 = lane >> 4, l15 = lane & 15;
  const int Rr = (wv >> 1) << 4;
  const int Cb = (wv & 1) << 5;

  bf16x8 qh[4], ql[4];
#pragma unroll
  for (int ks = 0; ks < 4; ++ks) {
    int cb = ks * 64 + q4 * 16;
    qh[ks] = ldf(QbH, Rr + l15, 256, cb);
    ql[ks] = ldf(QbL, Rr + l15, 256, cb);
  }
  f32x4 s1a[2], s2a[2];
#pragma unroll
  for (int ct = 0; ct < 2; ++ct) { s1a[ct] = (f32x4){0.f,0.f,0.f,0.f}; s2a[ct] = (f32x4){0.f,0.f,0.f,0.f}; }

#pragma unroll
  for (int ct = 0; ct < 2; ++ct) {
    int jb = Cb + ct * 16 + l15;
#pragma unroll
    for (int ks = 0; ks < 4; ++ks) {
      int cb = ks * 64 + q4 * 16;
      bf16x8 kh1 = ldf(KbH, jb + 1, 256, cb);
      bf16x8 kl1 = ldf(KbL, jb + 1, 256, cb);
      s1a[ct] = __builtin_amdgcn_mfma_f32_16x16x32_bf16(qh[ks], kh1, s1a[ct], 0, 0, 0);
      s1a[ct] = __builtin_amdgcn_mfma_f32_16x16x32_bf16(qh[ks], kl1, s1a[ct], 0, 0, 0);
      s1a[ct] = __builtin_amdgcn_mfma_f32_16x16x32_bf16(ql[ks], kh1, s1a[ct], 0, 0, 0);
      bf16x8 kh0 = ldf(KbH, jb, 256, cb);
      bf16x8 kl0 = ldf(KbL, jb, 256, cb);
      s2a[ct] = __builtin_amdgcn_mfma_f32_16x16x32_bf16(qh[ks], kh0, s2a[ct], 0, 0, 0);
      s2a[ct] = __builtin_amdgcn_mfma_f32_16x16x32_bf16(qh[ks], kl0, s2a[ct], 0, 0, 0);
      s2a[ct] = __builtin_amdgcn_mfma_f32_16x16x32_bf16(ql[ks], kh0, s2a[ct], 0, 0, 0);
    }
  }

#pragma unroll
  for (int ct = 0; ct < 2; ++ct) {
    int j = Cb + ct * 16 + l15;
    float ej = ell[j], gj = g1s[j];
#pragma unroll
    for (int reg = 0; reg < 4; ++reg) {
      int i = Rr + q4 * 4 + reg;
      float v = (j <= i) ? s1a[ct][reg] * gj * expf(ell[i] - ej) : 0.0f;
      ushort_t hv = f2bf(v);
      st_bf16(SbH, i, 128, j * 2, hv);
      st_bf16(SbL, i, 128, j * 2, f2bf(v - bf2f(hv)));
    }
  }
  __syncthreads();

  f32x4 yacc[2];
  yacc[0] = (f32x4){0.f,0.f,0.f,0.f}; yacc[1] = (f32x4){0.f,0.f,0.f,0.f};
  {
    bf16x8 sh[2], sl[2];
#pragma unroll
    for (int ks = 0; ks < 2; ++ks) {
      int cb = ks * 64 + q4 * 16;
      sh[ks] = ldf(SbH, Rr + l15, 128, cb);
      sl[ks] = ldf(SbL, Rr + l15, 128, cb);
    }
#pragma unroll
    for (int pt = 0; pt < 2; ++pt) {
      int prow = Cb + pt * 16 + l15;
#pragma unroll
      for (int ks = 0; ks < 2; ++ks) {
        int cb = ks * 64 + q4 * 16;
        bf16x8 xh = ldf(xT1H, prow, 128, cb);
        bf16x8 xl = ldf(xT1L, prow, 128, cb);
        yacc[pt] = __builtin_amdgcn_mfma_f32_16x16x32_bf16(sh[ks], xh, yacc[pt], 0, 0, 0);
        yacc[pt] = __builtin_amdgcn_mfma_f32_16x16x32_bf16(sh[ks], xl, yacc[pt], 0, 0, 0);
        yacc[pt] = __builtin_amdgcn_mfma_f32_16x16x32_bf16(sl[ks], xh, yacc[pt], 0, 0, 0);
      }
    }
  }
  __syncthreads();

#pragma unroll
  for (int ct = 0; ct < 2; ++ct) {
    int j = Cb + ct * 16 + l15;
    float ej = ell[j], gj = g2s[j];
#pragma unroll
    for (int reg = 0; reg < 4; ++reg) {
      int i = Rr + q4 * 4 + reg;
      float v = (j <= i) ? s2a[ct][reg] * gj * expf(ell[i] - ej) : 0.0f;
      ushort_t hv = f2bf(v);
      st_bf16(SbH, i, 128, j * 2, hv);
      st_bf16(SbL, i, 128, j * 2, f2bf(v - bf2f(hv)));
    }
  }
  __syncthreads();

  {
    bf16x8 sh[2], sl[2];
#pragma unroll
    for (int ks = 0; ks < 2; ++ks) {
      int cb = ks * 64 + q4 * 16;
      sh[ks] = ldf(SbH, Rr + l15, 128, cb);
      sl[ks] = ldf(SbL, Rr + l15, 128, cb);
    }
#pragma unroll
    for (int pt = 0; pt < 2; ++pt) {
      int prow = Cb + pt * 16 + l15;
#pragma unroll
      for (int ks = 0; ks < 2; ++ks) {
        int cb = ks * 64 + q4 * 16;
        bf16x8 xh = ldf(xT0H, prow, 128, cb);
        bf16x8 xl = ldf(xT0L, prow, 128, cb);
        yacc[pt] = __builtin_amdgcn_mfma_f32_16x16x32_bf16(sh[ks], xh, yacc[pt], 0, 0, 0);
        yacc[pt] = __builtin_amdgcn_mfma_f32_16x16x32_bf16(sh[ks], xl, yacc[pt], 0, 0, 0);
        yacc[pt] = __builtin_amdgcn_mfma_f32_16x16x32_bf16(sl[ks], xh, yacc[pt], 0, 0, 0);
      }
    }
  }
#pragma unroll
  for (int pt = 0; pt < 2; ++pt) {
    int p = Cb + pt * 16 + l15;
#pragma unroll
    for (int reg = 0; reg < 4; ++reg) {
      int i = Rr + q4 * 4 + reg;
      size_t idx = (size_t)(b * L_ + l0 + i) * DIN + h * HD + p;
      float v = yacc[pt][reg];
      ushort_t hv = f2bf(v);
      yh[idx] = hv;
      yl[idx] = f2bf(v - bf2f(hv));
    }
  }

  // WsumT[p][n]
  {
    const int Pw = (wv >> 1) << 4;
    const int Nb = (wv & 1) << 6;
    f32x4 wacc[4];
#pragma unroll
    for (int nt = 0; nt < 4; ++nt) wacc[nt] = (f32x4){0.f,0.f,0.f,0.f};
    bf16x8 axh[2], axl[2];
#pragma unroll
    for (int ks = 0; ks < 2; ++ks) {
      int cb = ks * 64 + q4 * 16;
      axh[ks] = ldf(xT0H, Pw + l15, 128, cb);
      axl[ks] = ldf(xT0L, Pw + l15, 128, cb);
    }
#pragma unroll
    for (int nt = 0; nt < 4; ++nt) {
      int nrow = Nb + nt * 16 + l15;
#pragma unroll
      for (int ks = 0; ks < 2; ++ks) {
        int cb = ks * 64 + q4 * 16;
        bf16x8 bh = ldf(KTwH, nrow, 128, cb);
        bf16x8 bl = ldf(KTwL, nrow, 128, cb);
        wacc[nt] = __builtin_amdgcn_mfma_f32_16x16x32_bf16(axh[ks], bh, wacc[nt], 0, 0, 0);
        wacc[nt] = __builtin_amdgcn_mfma_f32_16x16x32_bf16(axh[ks], bl, wacc[nt], 0, 0, 0);
        wacc[nt] = __builtin_amdgcn_mfma_f32_16x16x32_bf16(axl[ks], bh, wacc[nt], 0, 0, 0);
      }
    }
    size_t wbase = ((size_t)(b * NC + c) * NH + h) * (size_t)(NST * HD);
#pragma unroll
    for (int nt = 0; nt < 4; ++nt) {
      int n = Nb + nt * 16 + l15;
      float kt = ktail[n];
#pragma unroll
      for (int reg = 0; reg < 4; ++reg) {
        int p = Pw + q4 * 4 + reg;
        WsT[wbase + (size_t)p * NST + n] = wacc[nt][reg] + xtail[p] * kt;
      }
    }
  }
}

// ---------------- P5: state scan (512 blocks, float4/thread, prefetch pipeline) ----------------
__global__ __launch_bounds__(256) void state_scan_kernel(
    float* __restrict__ Wsum, const float* __restrict__ cdg) {
  const int b = blockIdx.x >> 8;
  const int h = (blockIdx.x >> 3) & 31;
  const int g = blockIdx.x & 7;
  const int e = (g << 10) + (threadIdx.x << 2);

  __shared__ float cds[NC];
  if (threadIdx.x < NC)
    cds[threadIdx.x] = cdg[((size_t)b * NC + threadIdx.x) * NH + h];
  __syncthreads();

  float* base = Wsum + ((size_t)(b * NC) * NH + h) * (size_t)(NST * HD) + e;
  const size_t cstride = (size_t)NH * NST * HD;

  F4 Hst; Hst.v = make_float4(0.f, 0.f, 0.f, 0.f);
  F4 w;   w.v = *(const float4*)base;
  for (int c = 0; c < NC; ++c) {
    F4 wn;
    if (c + 1 < NC) wn.v = *(const float4*)(base + (size_t)(c + 1) * cstride);  // prefetch
    const float cd = cds[c];
    *(float4*)(base + (size_t)c * cstride) = Hst.v;   // store Hprev
#pragma unroll
    for (int k = 0; k < 4; ++k) Hst.a[k] = fmaf(cd, Hst.a[k], w.a[k]);
    w = wn;
  }
}

// ---------------- P6: finalize ----------------
__global__ __launch_bounds__(256) void finalize_kernel(
    const float* __restrict__ proj, const float* __restrict__ Cn,
    const float* __restrict__ theta, const float* __restrict__ C_bias,
    const float* __restrict__ Hprev, const float* __restrict__ adtg,
    const float* __restrict__ dvec,
    ushort_t* __restrict__ yh, ushort_t* __restrict__ yl) {
  const int h  = blockIdx.x & 31;
  const int c  = (blockIdx.x >> 5) & 31;
  const int b  = blockIdx.x >> 10;
  const int t  = threadIdx.x;
  const int l0 = c * CHK;

  __shared__ float Qs[64][132];
  __shared__ float HsT[64][132];
  __shared__ float ell[64];

#pragma unroll
  for (int k = 0; k < 8; ++k) {
    int f = t + k * 256;
    int i = f >> 5, n = (f & 31) << 2;
    F4 v, bb;
    v.v  = *(const float4*)(Cn + (size_t)(b * L_ + l0 + i) * NST + n);
    bb.v = *(const float4*)(C_bias + h * NST + n);
#pragma unroll
    for (int q = 0; q < 4; ++q) v.a[q] += bb.a[q];
    *(float4*)&Qs[i][n] = v.v;
  }
  {
    const float* hp = Hprev + ((size_t)(b * NC + c) * NH + h) * (size_t)(NST * HD);
#pragma unroll
    for (int k = 0; k < 8; ++k) {
      int f = t + k * 256;
      int p = f >> 5, n4 = (f & 31) << 2;
      *(float4*)&HsT[p][n4] = *(const float4*)(hp + (size_t)p * NST + n4);
    }
  }
  if (t < 64) {
    float v = adtg[((size_t)b * NH + h) * L_ + l0 + t];
#pragma unroll
    for (int off = 1; off < 64; off <<= 1) {
      float u = __shfl_up(v, off, 64);
      if (t >= off) v += u;
    }
    ell[t] = v;
  }
  __syncthreads();

#pragma unroll
  for (int k = 0; k < 8; ++k) {
    int f = t + k * 256;
    int i = f >> 5, na = f & 31;
    float th = theta[((size_t)(b * L_ + l0 + i) * NH + h) * NA + na];
    float sn, cs;
    sincosf(th, &sn, &cs);
    float q1 = Qs[i][na], q2 = Qs[i][na + 32];
    Qs[i][na]      = q1 * cs - q2 * sn;
    Qs[i][na + 32] = q1 * sn + q2 * cs;
  }
  __syncthreads();

  const int i0 = (t >> 4) << 2, p0 = (t & 15) << 2;
  float acc[4][4];
#pragma unroll
  for (int r = 0; r < 4; ++r)
#pragma unroll
    for (int p = 0; p < 4; ++p) acc[r][p] = 0.0f;

  for (int n4 = 0; n4 < 32; ++n4) {
    F4 qa[4], hb[4];
#pragma unroll
    for (int r = 0; r < 4; ++r)  qa[r].v = *(const float4*)&Qs[i0 + r][n4 << 2];
#pragma unroll
    for (int pp = 0; pp < 4; ++pp) hb[pp].v = *(const float4*)&HsT[p0 + pp][n4 << 2];
#pragma unroll
    for (int r = 0; r < 4; ++r)
#pragma unroll
      for (int pp = 0; pp < 4; ++pp) {
        acc[r][pp] = fmaf(qa[r].a[0], hb[pp].a[0], acc[r][pp]);
        acc[r][pp] = fmaf(qa[r].a[1], hb[pp].a[1], acc[r][pp]);
        acc[r][pp] = fmaf(qa[r].a[2], hb[pp].a[2], acc[r][pp]);
        acc[r][pp] = fmaf(qa[r].a[3], hb[pp].a[3], acc[r][pp]);
      }
  }

  const float Dv = dvec[h];
#pragma unroll
  for (int r = 0; r < 4; ++r) {
    const int l = l0 + i0 + r;
    const float e = expf(ell[i0 + r]);
    const size_t rowoff = (size_t)(b * L_ + l);
    const size_t yidx = rowoff * DIN + h * HD + p0;
    US4 yhv, ylv, oh, ol;
    yhv.v = *(const ushort4*)(yh + yidx);
    ylv.v = *(const ushort4*)(yl + yidx);
    F4 xv, zv;
    xv.v = *(const float4*)(proj + rowoff * DPROJ + OFF_X + h * HD + p0);
    zv.v = *(const float4*)(proj + rowoff * DPROJ + OFF_Z + h * HD + p0);
#pragma unroll
    for (int p = 0; p < 4; ++p) {
      float yi = bf2f(yhv.a[p]) + bf2f(ylv.a[p]);
      float z = zv.a[p];
      float o = (yi + e * acc[r][p] + Dv * xv.a[p]) * (z * sigmoidf_(z));
      ushort_t hv = f2bf(o);
      oh.a[p] = hv;
      ol.a[p] = f2bf(o - bf2f(hv));
    }
    *(ushort4*)(yh + yidx) = oh.v;
    *(ushort4*)(yl + yidx) = ol.v;
  }
}

__global__ void zero_out_kernel(float* __restrict__ out, int n) {
  int i = blockIdx.x * 256 + threadIdx.x;
  if (i < n) out[i] = 0.0f;
}

extern "C" void kernel_launch(void* const* d_in, const int* in_sizes, int n_in,
                              void* d_out, int out_size, void* d_ws, size_t ws_size,
                              hipStream_t stream) {
  const float* u        = (const float*)d_in[0];
  const float* W_in     = (const float*)d_in[1];
  const float* W_out    = (const float*)d_in[2];
  const float* dt_bias  = (const float*)d_in[3];
  const float* B_bias   = (const float*)d_in[4];
  const float* C_bias   = (const float*)d_in[5];
  const float* B_norm_w = (const float*)d_in[6];
  const float* C_norm_w = (const float*)d_in[7];
  const float* Dv       = (const float*)d_in[8];
  float* out = (float*)d_out;
  float* ws  = (float*)d_ws;

  size_t o = 0;
  float* proj  = ws + o; o += (size_t)B_ * L_ * DPROJ;
  float* Bn    = ws + o; o += (size_t)B_ * L_ * NST;
  float* Cn    = ws + o; o += (size_t)B_ * L_ * NST;
  float* dtg   = ws + o; o += (size_t)B_ * NH * L_;
  float* adtg  = ws + o; o += (size_t)B_ * NH * L_;
  float* g1g   = ws + o; o += (size_t)B_ * NH * L_;
  float* g2g   = ws + o; o += (size_t)B_ * NH * L_;
  float* theta = ws + o; o += (size_t)B_ * L_ * NH * NA;
  float* Wsum  = ws + o; o += (size_t)B_ * NC * NH * NST * HD;
  float* cdg   = ws + o; o += (size_t)B_ * NC * NH;
  float* yreg  = ws + o; o += (size_t)B_ * L_ * DIN;
  ushort_t* Wth = (ushort_t*)(ws + o); o += (size_t)DPROJ * DM / 2;
  ushort_t* Wtl = (ushort_t*)(ws + o); o += (size_t)DPROJ * DM / 2;
  ushort_t* Woh = (ushort_t*)(ws + o); o += (size_t)DM * DIN / 2;
  ushort_t* Wol = (ushort_t*)(ws + o); o += (size_t)DM * DIN / 2;

  ushort_t* yh = (ushort_t*)yreg;
  ushort_t* yl = yh + (size_t)B_ * L_ * DIN;
  ushort_t* uh = yh;   // alias: consumed by GEMM1 before chunk overwrites y
  ushort_t* ul = yl;

  if (ws_size < o * sizeof(float)) {
    zero_out_kernel<<<(out_size + 255) / 256, 256, 0, stream>>>(out, out_size);
    return;
  }

  tsplit_kernel<<<dim3(DPROJ / 64, DM / 64), 256, 0, stream>>>(W_in, Wth, Wtl, DM, DPROJ);
  tsplit_kernel<<<dim3(DM / 64, DIN / 64), 256, 0, stream>>>(W_out, Woh, Wol, DIN, DM);
  split_kernel<<<(B_ * L_ * DM / 8 + 255) / 256, 256, 0, stream>>>(
      u, uh, ul, B_ * L_ * DM / 8);
  gemm_glds<<<(DPROJ / 128) * ((B_ * L_) / 128), 256, 0, stream>>>(
      uh, ul, Wth, Wtl, proj, B_ * L_, DPROJ, DM, DPROJ / 128);
  pointwise_kernel<<<B_ * L_, 128, 0, stream>>>(
      proj, dt_bias, B_norm_w, C_norm_w, Bn, Cn, dtg, adtg, g1g, g2g);
  theta_kernel<<<B_ * NH, 512, 0, stream>>>(proj, dtg, theta);
  chunk_kernel<<<B_ * NC * NH, 512, 0, stream>>>(
      proj, Bn, Cn, theta, B_bias, C_bias, adtg, g1g, g2g, Wsum, cdg, yh, yl);
  state_scan_kernel<<<B_ * NH * 8, 256, 0, stream>>>(Wsum, cdg);
  finalize_kernel<<<B_ * NC * NH, 256, 0, stream>>>(
      proj, Cn, theta, C_bias, Wsum, adtg, Dv, yh, yl);
  gemm_glds<<<(DM / 128) * ((B_ * L_) / 128), 256, 0, stream>>>(
      yh, yl, Woh, Wol, out, B_ * L_, DM, DIN, DM / 128);
}

// Round 7
// 485.860 us; speedup vs baseline: 2.6258x; 1.0686x over previous
//
#include <hip/hip_runtime.h>
#include <math.h>

#define B_    2
#define L_    2048
#define DM    1024
#define DIN   2048
#define NH    32
#define HD    64
#define NST   128
#define NA    32
#define NC    32
#define CHK   64
#define DPROJ 4480

#define OFF_Z    0
#define OFF_X    2048
#define OFF_BG   4096
#define OFF_CG   4224
#define OFF_DDT  4352
#define OFF_DDA  4384
#define OFF_TRAP 4416
#define OFF_ANG  4448

typedef union { float4 v; float a[4]; } F4;
typedef unsigned short ushort_t;
typedef union { ushort4 v; ushort_t a[4]; } US4;
typedef __attribute__((ext_vector_type(8))) short bf16x8;
typedef __attribute__((ext_vector_type(4))) float f32x4;
typedef union { bf16x8 v; ushort_t u[8]; uint4 q; } BF8;

__device__ __forceinline__ float softplusf_(float x) {
  return (x > 20.0f) ? x : log1pf(__expf(x));
}
__device__ __forceinline__ float sigmoidf_(float x) {
  return 1.0f / (1.0f + __expf(-x));
}
__device__ __forceinline__ ushort_t f2bf(float x) {
  union { float f; unsigned u; } v; v.f = x;
  unsigned r = v.u + 0x7fffu + ((v.u >> 16) & 1u);
  return (ushort_t)(r >> 16);
}
__device__ __forceinline__ float bf2f(ushort_t h) {
  union { unsigned u; float f; } v; v.u = ((unsigned)h) << 16;
  return v.f;
}
__device__ __forceinline__ bf16x8 ldf(const char* base, int row, int stride, int cb) {
  return *(const bf16x8*)(base + row * stride + (cb ^ ((row & 7) << 4)));
}
__device__ __forceinline__ void st_bf16(char* base, int row, int stride, int colb, ushort_t v) {
  *(ushort_t*)(base + row * stride + (colb ^ ((row & 7) << 4))) = v;
}
__device__ __forceinline__ void glds16(const void* g, void* l) {
  __builtin_amdgcn_global_load_lds(
      (const __attribute__((address_space(1))) void*)g,
      (__attribute__((address_space(3))) void*)l, 16, 0, 0);
}

// ---------------- transpose+split: src[Kd][Nd] f32 -> hi/lo [Nd][Kd] bf16 ----------------
__global__ __launch_bounds__(256) void tsplit_kernel(
    const float* __restrict__ src, ushort_t* __restrict__ hi,
    ushort_t* __restrict__ lo, int Kd, int Nd) {
  __shared__ float tile[64][65];
  const int k0 = blockIdx.y * 64, n0 = blockIdx.x * 64;
  const int t = threadIdx.x;
  {
    const int r = t >> 4, c4 = (t & 15) << 2;
#pragma unroll
    for (int rr = 0; rr < 4; ++rr) {
      F4 v; v.v = *(const float4*)(src + (size_t)(k0 + r + rr * 16) * Nd + n0 + c4);
      tile[r + rr * 16][c4] = v.a[0]; tile[r + rr * 16][c4 + 1] = v.a[1];
      tile[r + rr * 16][c4 + 2] = v.a[2]; tile[r + rr * 16][c4 + 3] = v.a[3];
    }
  }
  __syncthreads();
  const int n = t >> 2, kc = (t & 3) << 4;
  BF8 h0, h1, l0, l1;
#pragma unroll
  for (int e = 0; e < 8; ++e) {
    float x = tile[kc + e][n];
    ushort_t h = f2bf(x); h0.u[e] = h; l0.u[e] = f2bf(x - bf2f(h));
    float y = tile[kc + 8 + e][n];
    ushort_t g = f2bf(y); h1.u[e] = g; l1.u[e] = f2bf(y - bf2f(g));
  }
  size_t ob = (size_t)(n0 + n) * Kd + k0 + kc;
  *(uint4*)(hi + ob) = h0.q; *(uint4*)(hi + ob + 8) = h1.q;
  *(uint4*)(lo + ob) = l0.q; *(uint4*)(lo + ob + 8) = l1.q;
}

// ---------------- elementwise split: f32 -> hi/lo bf16 ----------------
__global__ __launch_bounds__(256) void split_kernel(
    const float* __restrict__ src, ushort_t* __restrict__ hi,
    ushort_t* __restrict__ lo, int n8) {
  int i = blockIdx.x * 256 + threadIdx.x;
  if (i >= n8) return;
  const float* p = src + (size_t)i * 8;
  F4 a, b; a.v = *(const float4*)p; b.v = *(const float4*)(p + 4);
  BF8 h, l;
#pragma unroll
  for (int e = 0; e < 4; ++e) {
    ushort_t hh = f2bf(a.a[e]); h.u[e] = hh; l.u[e] = f2bf(a.a[e] - bf2f(hh));
    ushort_t gg = f2bf(b.a[e]); h.u[e + 4] = gg; l.u[e + 4] = f2bf(b.a[e] - bf2f(gg));
  }
  *(uint4*)(hi + (size_t)i * 8) = h.q;
  *(uint4*)(lo + (size_t)i * 8) = l.q;
}

// ---------------- MFMA GEMM, global_load_lds staging, 3-pass split-bf16 ----------------
__global__ __launch_bounds__(256) void gemm_glds(
    const ushort_t* __restrict__ Ah, const ushort_t* __restrict__ Al,
    const ushort_t* __restrict__ Bth, const ushort_t* __restrict__ Btl,
    float* __restrict__ C, int M, int N, int K, int nbx) {
  __shared__ __align__(16) char ldsA[16384], ldsB[16384];
  const int nwg = gridDim.x;
  const int q8 = nwg >> 3;
  const int swz = (blockIdx.x & 7) * q8 + (blockIdx.x >> 3);
  const int bm = (swz / nbx) << 7, bn = (swz % nbx) << 7;
  const int t = threadIdx.x, w = t >> 6, lane = t & 63;

  const size_t K2 = (size_t)K << 1;
  const int swl = (lane >> 3) << 4;
  const int cA = ((lane & 7) << 4) ^ swl;
  const int rl = (w << 5) + (lane >> 3);
  const char* gA = (cA < 64 ? (const char*)Ah + cA : (const char*)Al + (cA - 64))
                   + (size_t)(bm + rl) * K2;
  const char* gB = (cA < 64 ? (const char*)Bth + cA : (const char*)Btl + (cA - 64))
                   + (size_t)(bn + rl) * K2;
  const size_t istep = K2 << 3;
  char* dA = ldsA + (w << 12);
  char* dB = ldsB + (w << 12);

  const int wm = (w >> 1) << 6, wn = (w & 1) << 6;
  const int lr = lane & 15, cb = (lane >> 4) << 4;

  f32x4 acc[4][4];
#pragma unroll
  for (int i = 0; i < 4; ++i)
#pragma unroll
    for (int j = 0; j < 4; ++j) acc[i][j] = (f32x4){0.f, 0.f, 0.f, 0.f};

#define STAGE(k0) do {                                                  \
    size_t kb = (size_t)(k0) << 1;                                      \
    glds16(gA + kb,             dA);                                    \
    glds16(gA + kb + istep,     dA + 1024);                             \
    glds16(gA + kb + 2 * istep, dA + 2048);                             \
    glds16(gA + kb + 3 * istep, dA + 3072);                             \
    glds16(gB + kb,             dB);                                    \
    glds16(gB + kb + istep,     dB + 1024);                             \
    glds16(gB + kb + 2 * istep, dB + 2048);                             \
    glds16(gB + kb + 3 * istep, dB + 3072);                             \
  } while (0)

  STAGE(0);
  for (int k0 = 0; k0 < K; k0 += 32) {
    __syncthreads();
    bf16x8 ah[4], al[4], bh[4], bl[4];
#pragma unroll
    for (int mf = 0; mf < 4; ++mf) {
      int r2 = wm + (mf << 4) + lr;
      int sw2 = (r2 & 7) << 4;
      ah[mf] = *(const bf16x8*)(ldsA + (r2 << 7) + (cb ^ sw2));
      al[mf] = *(const bf16x8*)(ldsA + (r2 << 7) + ((cb + 64) ^ sw2));
    }
#pragma unroll
    for (int nf = 0; nf < 4; ++nf) {
      int r2 = wn + (nf << 4) + lr;
      int sw2 = (r2 & 7) << 4;
      bh[nf] = *(const bf16x8*)(ldsB + (r2 << 7) + (cb ^ sw2));
      bl[nf] = *(const bf16x8*)(ldsB + (r2 << 7) + ((cb + 64) ^ sw2));
    }
#pragma unroll
    for (int mf = 0; mf < 4; ++mf)
#pragma unroll
      for (int nf = 0; nf < 4; ++nf) {
        acc[mf][nf] = __builtin_amdgcn_mfma_f32_16x16x32_bf16(ah[mf], bh[nf], acc[mf][nf], 0, 0, 0);
        acc[mf][nf] = __builtin_amdgcn_mfma_f32_16x16x32_bf16(ah[mf], bl[nf], acc[mf][nf], 0, 0, 0);
        acc[mf][nf] = __builtin_amdgcn_mfma_f32_16x16x32_bf16(al[mf], bh[nf], acc[mf][nf], 0, 0, 0);
      }
    __syncthreads();
    if (k0 + 32 < K) STAGE(k0 + 32);
  }
#undef STAGE

  const int rsub = (lane >> 4) << 2;
#pragma unroll
  for (int mf = 0; mf < 4; ++mf)
#pragma unroll
    for (int nf = 0; nf < 4; ++nf) {
      float* cp = C + (size_t)(bm + wm + mf * 16 + rsub) * N + bn + wn + nf * 16 + lr;
#pragma unroll
      for (int j = 0; j < 4; ++j) cp[(size_t)j * N] = acc[mf][nf][j];
    }
}

// ---------------- P2: per-(b,l) pointwise ----------------
__global__ __launch_bounds__(128) void pointwise_kernel(
    const float* __restrict__ proj, const float* __restrict__ dt_bias,
    const float* __restrict__ Bnw, const float* __restrict__ Cnw,
    float* __restrict__ Bn, float* __restrict__ Cn,
    float* __restrict__ dtg, float* __restrict__ adtg,
    float* __restrict__ g1g, float* __restrict__ g2g) {
  const int bl = blockIdx.x;
  const int l  = bl & (L_ - 1);
  const int b  = bl >> 11;
  const int t  = threadIdx.x;
  const float* row = proj + (size_t)bl * DPROJ;

  float vb = row[OFF_BG + t];
  float vc = row[OFF_CG + t];
  float sb = vb * vb, sc = vc * vc;
#pragma unroll
  for (int off = 32; off >= 1; off >>= 1) {
    sb += __shfl_xor(sb, off, 64);
    sc += __shfl_xor(sc, off, 64);
  }
  __shared__ float red[4];
  if ((t & 63) == 0) { red[t >> 6] = sb; red[2 + (t >> 6)] = sc; }
  __syncthreads();
  sb = red[0] + red[1];
  sc = red[2] + red[3];
  float rb = rsqrtf(sb * (1.0f / 128.0f) + 1e-5f);
  float rc = rsqrtf(sc * (1.0f / 128.0f) + 1e-5f);
  Bn[(size_t)bl * NST + t] = vb * rb * Bnw[t];
  Cn[(size_t)bl * NST + t] = vc * rc * Cnw[t];

  if (t < NH) {
    const int h = t;
    float dt = softplusf_(row[OFF_DDT + h] + dt_bias[h]);
    float a  = -softplusf_(row[OFF_DDA + h]);
    a = fminf(a, -1e-4f);
    float adt  = a * dt;
    float beta = sigmoidf_(row[OFF_TRAP + h]);
    float dtp  = 0.0f;
    if (l > 0) dtp = softplusf_(proj[(size_t)(bl - 1) * DPROJ + OFF_DDT + h] + dt_bias[h]);
    float g2 = (1.0f - beta) * __expf(adt) * dtp;
    size_t idx = ((size_t)b * NH + h) * L_ + l;
    dtg[idx]  = dt;
    adtg[idx] = adt;
    g1g[idx]  = beta * dt;
    g2g[idx]  = g2;
  }
}

// ---------------- P3: theta via segmented scan (16 segs x 128, 512 threads) ----------------
__global__ __launch_bounds__(512) void theta_kernel(
    const float* __restrict__ proj, const float* __restrict__ dtg,
    float* __restrict__ theta) {
  const int b  = blockIdx.x >> 5;
  const int h  = blockIdx.x & 31;
  const int t  = threadIdx.x;
  const int na = t & 31, seg = t >> 5;
  const int l0 = seg << 7;
  const float* ap = proj + (size_t)b * L_ * DPROJ + OFF_ANG + na;
  const float* dp = dtg + ((size_t)b * NH + h) * L_;
  __shared__ float segsum[16][33];

  float s = 0.0f;
#pragma unroll 8
  for (int l = l0; l < l0 + 128; ++l)
    s = fmaf(ap[(size_t)l * DPROJ], dp[l], s);
  segsum[seg][na] = s;
  __syncthreads();
  if (t < 32) {
    float run = 0.0f;
#pragma unroll
    for (int sg = 0; sg < 16; ++sg) {
      float v = segsum[sg][t];
      segsum[sg][t] = run;
      run += v;
    }
  }
  __syncthreads();
  float th = segsum[seg][na];
  float* tp = theta + ((size_t)b * L_ * NH + h) * NA + na;
#pragma unroll 8
  for (int l = l0; l < l0 + 128; ++l) {
    th = fmaf(ap[(size_t)l * DPROJ], dp[l], th);
    tp[(size_t)l * NH * NA] = th;
  }
}

// ---------------- P4: MFMA chunk kernel (512 threads) ----------------
__global__ __launch_bounds__(512, 1) void chunk_kernel(
    const float* __restrict__ proj,
    const float* __restrict__ Bn, const float* __restrict__ Cn,
    const float* __restrict__ theta,
    const float* __restrict__ B_bias, const float* __restrict__ C_bias,
    const float* __restrict__ adtg, const float* __restrict__ g1g,
    const float* __restrict__ g2g,
    float* __restrict__ WsT, float* __restrict__ cdg,
    ushort_t* __restrict__ yh, ushort_t* __restrict__ yl) {
  const int h  = blockIdx.x & 31;
  const int c  = (blockIdx.x >> 5) & 31;
  const int b  = blockIdx.x >> 10;
  const int t  = threadIdx.x;
  const int l0 = c * CHK;

  __shared__ __align__(16) char QbH[16384], QbL[16384];
  __shared__ __align__(16) char KbH[16640], KbL[16640];
  __shared__ __align__(16) char KTwH[16384], KTwL[16384];
  __shared__ __align__(16) char xT0H[8192], xT0L[8192];
  __shared__ __align__(16) char xT1H[8192], xT1L[8192];
  __shared__ __align__(16) char Ubuf[17680];
  __shared__ float ell[64], g1s[64], g2s[64], w1s[64], cw[64], xtail[64], ktail[128];
  float (*xxs)[68] = (float(*)[68])Ubuf;
  char* SbH = Ubuf;
  char* SbL = Ubuf + 8192;

  // ---------- phase 1 ----------
  if (t < 64) {
    size_t idx = ((size_t)b * NH + h) * L_ + l0 + t;
    float adt = adtg[idx], g1 = g1g[idx], g2 = g2g[idx];
    float v = adt;
#pragma unroll
    for (int off = 1; off < 64; off <<= 1) {
      float u = __shfl_up(v, off, 64);
      if (t >= off) v += u;
    }
    ell[t] = v;
    float last = __shfl(v, 63, 64);
    float de = __expf(last - v);
    float w1 = g1 * de, w2 = g2 * de;
    g1s[t] = g1; g2s[t] = g2; w1s[t] = w1;
    float w1p = __shfl_up(w1, 1, 64);
    cw[t] = (t >= 1 ? w1p : 0.0f) + w2;
    if (t == 63) cdg[((size_t)b * NC + c) * NH + h] = __expf(v);
  }
#pragma unroll
  for (int k = 0; k < 4; ++k) {
    int f = t + k * 512;
    int i = f >> 5, na = f & 31;
    size_t lrow = (size_t)(b * L_ + l0 + i);
    float c1 = Cn[lrow * NST + na]      + C_bias[h * NST + na];
    float c2 = Cn[lrow * NST + na + 32] + C_bias[h * NST + na + 32];
    float th = theta[(lrow * NH + h) * NA + na];
    float sn, cs; __sincosf(th, &sn, &cs);
    float q1 = c1 * cs - c2 * sn;
    float q2 = c1 * sn + c2 * cs;
    ushort_t h1 = f2bf(q1), h2 = f2bf(q2);
    st_bf16(QbH, i, 256, na * 2, h1);
    st_bf16(QbH, i, 256, (na + 32) * 2, h2);
    st_bf16(QbL, i, 256, na * 2, f2bf(q1 - bf2f(h1)));
    st_bf16(QbL, i, 256, (na + 32) * 2, f2bf(q2 - bf2f(h2)));
  }
#pragma unroll
  for (int k = 0; k < 4; ++k) {
    int f = t + k * 512;
    int i = f >> 5, e2 = f & 31;
    int n1 = 64 + 2 * e2;
    size_t lrow = (size_t)(b * L_ + l0 + i);
    float v1 = Cn[lrow * NST + n1]     + C_bias[h * NST + n1];
    float v2 = Cn[lrow * NST + n1 + 1] + C_bias[h * NST + n1 + 1];
    ushort_t h1 = f2bf(v1), h2 = f2bf(v2);
    st_bf16(QbH, i, 256, n1 * 2, h1);
    st_bf16(QbH, i, 256, (n1 + 1) * 2, h2);
    st_bf16(QbL, i, 256, n1 * 2, f2bf(v1 - bf2f(h1)));
    st_bf16(QbL, i, 256, (n1 + 1) * 2, f2bf(v2 - bf2f(h2)));
  }
#pragma unroll
  for (int k = 0; k < 3; ++k) {
    int f = t + k * 512;
    if (f < 65 * 16) {
      int i = f >> 4, p4 = (f & 15) << 2;
      float4 v;
      if (i == 0 && c == 0) v = make_float4(0.f, 0.f, 0.f, 0.f);
      else v = *(const float4*)(proj + (size_t)(b * L_ + l0 + i - 1) * DPROJ + OFF_X + h * HD + p4);
      *(float4*)&xxs[i][p4] = v;
    }
  }
  __syncthreads();

  // ---------- phase 2 ----------
#pragma unroll
  for (int k = 0; k < 5; ++k) {
    int f = t + k * 512;
    if (f < 65 * 32) {
      int i = f >> 5, na = f & 31;
      float k1 = 0.f, k2 = 0.f;
      if (!(i == 0 && c == 0)) {
        size_t lrow = (size_t)(b * L_ + l0 + i - 1);
        float b1 = Bn[lrow * NST + na]      + B_bias[h * NST + na];
        float b2 = Bn[lrow * NST + na + 32] + B_bias[h * NST + na + 32];
        float th = theta[(lrow * NH + h) * NA + na];
        float sn, cs; __sincosf(th, &sn, &cs);
        k1 = b1 * cs - b2 * sn;
        k2 = b1 * sn + b2 * cs;
      }
      ushort_t h1 = f2bf(k1), h2 = f2bf(k2);
      st_bf16(KbH, i, 256, na * 2, h1);
      st_bf16(KbH, i, 256, (na + 32) * 2, h2);
      st_bf16(KbL, i, 256, na * 2, f2bf(k1 - bf2f(h1)));
      st_bf16(KbL, i, 256, (na + 32) * 2, f2bf(k2 - bf2f(h2)));
      if (i < 64) {
        float wc = cw[i];
        float kw1 = k1 * wc, kw2 = k2 * wc;
        ushort_t g1_ = f2bf(kw1), g2_ = f2bf(kw2);
        st_bf16(KTwH, na, 128, i * 2, g1_);
        st_bf16(KTwH, na + 32, 128, i * 2, g2_);
        st_bf16(KTwL, na, 128, i * 2, f2bf(kw1 - bf2f(g1_)));
        st_bf16(KTwL, na + 32, 128, i * 2, f2bf(kw2 - bf2f(g2_)));
      } else {
        float tw = w1s[63];
        ktail[na]      = k1 * tw;
        ktail[na + 32] = k2 * tw;
      }
    }
  }
#pragma unroll
  for (int k = 0; k < 5; ++k) {
    int f = t + k * 512;
    if (f < 65 * 32) {
      int i = f >> 5, e2 = f & 31;
      int n1 = 64 + 2 * e2;
      float v1 = 0.f, v2 = 0.f;
      if (!(i == 0 && c == 0)) {
        size_t lrow = (size_t)(b * L_ + l0 + i - 1);
        v1 = Bn[lrow * NST + n1]     + B_bias[h * NST + n1];
        v2 = Bn[lrow * NST + n1 + 1] + B_bias[h * NST + n1 + 1];
      }
      ushort_t h1 = f2bf(v1), h2 = f2bf(v2);
      st_bf16(KbH, i, 256, n1 * 2, h1);
      st_bf16(KbH, i, 256, (n1 + 1) * 2, h2);
      st_bf16(KbL, i, 256, n1 * 2, f2bf(v1 - bf2f(h1)));
      st_bf16(KbL, i, 256, (n1 + 1) * 2, f2bf(v2 - bf2f(h2)));
      if (i < 64) {
        float wc = cw[i];
        float kw1 = v1 * wc, kw2 = v2 * wc;
        ushort_t g1_ = f2bf(kw1), g2_ = f2bf(kw2);
        st_bf16(KTwH, n1, 128, i * 2, g1_);
        st_bf16(KTwH, n1 + 1, 128, i * 2, g2_);
        st_bf16(KTwL, n1, 128, i * 2, f2bf(kw1 - bf2f(g1_)));
        st_bf16(KTwL, n1 + 1, 128, i * 2, f2bf(kw2 - bf2f(g2_)));
      } else {
        float tw = w1s[63];
        ktail[n1]     = v1 * tw;
        ktail[n1 + 1] = v2 * tw;
      }
    }
  }
  {
    int p = t >> 3, jc = (t & 7) << 3;
    float r[9];
#pragma unroll
    for (int e = 0; e < 9; ++e) r[e] = xxs[jc + e][p];
    BF8 t0h, t0l, t1h, t1l;
#pragma unroll
    for (int e = 0; e < 8; ++e) {
      ushort_t hh = f2bf(r[e]);     t0h.u[e] = hh; t0l.u[e] = f2bf(r[e] - bf2f(hh));
      ushort_t gg = f2bf(r[e + 1]); t1h.u[e] = gg; t1l.u[e] = f2bf(r[e + 1] - bf2f(gg));
    }
    int cb = (jc * 2) ^ ((p & 7) << 4);
    *(uint4*)(xT0H + p * 128 + cb) = t0h.q;
    *(uint4*)(xT0L + p * 128 + cb) = t0l.q;
    *(uint4*)(xT1H + p * 128 + cb) = t1h.q;
    *(uint4*)(xT1L + p * 128 + cb) = t1l.q;
    if (jc == 56) xtail[p] = r[8];
  }
  __syncthreads();

  // ---------- phase 3: compute ----------
  const int lane = t & 63, wv = t >> 6;
  const int q4 = lane >> 4, l15 = lane & 15;
  const int Rr = (wv >> 1) << 4;
  const int Cb = (wv & 1) << 5;

  bf16x8 qh[4], ql[4];
#pragma unroll
  for (int ks = 0; ks < 4; ++ks) {
    int cb = ks * 64 + q4 * 16;
    qh[ks] = ldf(QbH, Rr + l15, 256, cb);
    ql[ks] = ldf(QbL, Rr + l15, 256, cb);
  }
  f32x4 s1a[2], s2a[2];
#pragma unroll
  for (int ct = 0; ct < 2; ++ct) { s1a[ct] = (f32x4){0.f,0.f,0.f,0.f}; s2a[ct] = (f32x4){0.f,0.f,0.f,0.f}; }

#pragma unroll
  for (int ct = 0; ct < 2; ++ct) {
    int jb = Cb + ct * 16 + l15;
#pragma unroll
    for (int ks = 0; ks < 4; ++ks) {
      int cb = ks * 64 + q4 * 16;
      bf16x8 kh1 = ldf(KbH, jb + 1, 256, cb);
      bf16x8 kl1 = ldf(KbL, jb + 1, 256, cb);
      s1a[ct] = __builtin_amdgcn_mfma_f32_16x16x32_bf16(qh[ks], kh1, s1a[ct], 0, 0, 0);
      s1a[ct] = __builtin_amdgcn_mfma_f32_16x16x32_bf16(qh[ks], kl1, s1a[ct], 0, 0, 0);
      s1a[ct] = __builtin_amdgcn_mfma_f32_16x16x32_bf16(ql[ks], kh1, s1a[ct], 0, 0, 0);
      bf16x8 kh0 = ldf(KbH, jb, 256, cb);
      bf16x8 kl0 = ldf(KbL, jb, 256, cb);
      s2a[ct] = __builtin_amdgcn_mfma_f32_16x16x32_bf16(qh[ks], kh0, s2a[ct], 0, 0, 0);
      s2a[ct] = __builtin_amdgcn_mfma_f32_16x16x32_bf16(qh[ks], kl0, s2a[ct], 0, 0, 0);
      s2a[ct] = __builtin_amdgcn_mfma_f32_16x16x32_bf16(ql[ks], kh0, s2a[ct], 0, 0, 0);
    }
  }

#pragma unroll
  for (int ct = 0; ct < 2; ++ct) {
    int j = Cb + ct * 16 + l15;
    float ej = ell[j], gj = g1s[j];
#pragma unroll
    for (int reg = 0; reg < 4; ++reg) {
      int i = Rr + q4 * 4 + reg;
      float v = (j <= i) ? s1a[ct][reg] * gj * __expf(ell[i] - ej) : 0.0f;
      ushort_t hv = f2bf(v);
      st_bf16(SbH, i, 128, j * 2, hv);
      st_bf16(SbL, i, 128, j * 2, f2bf(v - bf2f(hv)));
    }
  }
  __syncthreads();

  f32x4 yacc[2];
  yacc[0] = (f32x4){0.f,0.f,0.f,0.f}; yacc[1] = (f32x4){0.f,0.f,0.f,0.f};
  {
    bf16x8 sh[2], sl[2];
#pragma unroll
    for (int ks = 0; ks < 2; ++ks) {
      int cb = ks * 64 + q4 * 16;
      sh[ks] = ldf(SbH, Rr + l15, 128, cb);
      sl[ks] = ldf(SbL, Rr + l15, 128, cb);
    }
#pragma unroll
    for (int pt = 0; pt < 2; ++pt) {
      int prow = Cb + pt * 16 + l15;
#pragma unroll
      for (int ks = 0; ks < 2; ++ks) {
        int cb = ks * 64 + q4 * 16;
        bf16x8 xh = ldf(xT1H, prow, 128, cb);
        bf16x8 xl = ldf(xT1L, prow, 128, cb);
        yacc[pt] = __builtin_amdgcn_mfma_f32_16x16x32_bf16(sh[ks], xh, yacc[pt], 0, 0, 0);
        yacc[pt] = __builtin_amdgcn_mfma_f32_16x16x32_bf16(sh[ks], xl, yacc[pt], 0, 0, 0);
        yacc[pt] = __builtin_amdgcn_mfma_f32_16x16x32_bf16(sl[ks], xh, yacc[pt], 0, 0, 0);
      }
    }
  }
  __syncthreads();

#pragma unroll
  for (int ct = 0; ct < 2; ++ct) {
    int j = Cb + ct * 16 + l15;
    float ej = ell[j], gj = g2s[j];
#pragma unroll
    for (int reg = 0; reg < 4; ++reg) {
      int i = Rr + q4 * 4 + reg;
      float v = (j <= i) ? s2a[ct][reg] * gj * __expf(ell[i] - ej) : 0.0f;
      ushort_t hv = f2bf(v);
      st_bf16(SbH, i, 128, j * 2, hv);
      st_bf16(SbL, i, 128, j * 2, f2bf(v - bf2f(hv)));
    }
  }
  __syncthreads();

  {
    bf16x8 sh[2], sl[2];
#pragma unroll
    for (int ks = 0; ks < 2; ++ks) {
      int cb = ks * 64 + q4 * 16;
      sh[ks] = ldf(SbH, Rr + l15, 128, cb);
      sl[ks] = ldf(SbL, Rr + l15, 128, cb);
    }
#pragma unroll
    for (int pt = 0; pt < 2; ++pt) {
      int prow = Cb + pt * 16 + l15;
#pragma unroll
      for (int ks = 0; ks < 2; ++ks) {
        int cb = ks * 64 + q4 * 16;
        bf16x8 xh = ldf(xT0H, prow, 128, cb);
        bf16x8 xl = ldf(xT0L, prow, 128, cb);
        yacc[pt] = __builtin_amdgcn_mfma_f32_16x16x32_bf16(sh[ks], xh, yacc[pt], 0, 0, 0);
        yacc[pt] = __builtin_amdgcn_mfma_f32_16x16x32_bf16(sh[ks], xl, yacc[pt], 0, 0, 0);
        yacc[pt] = __builtin_amdgcn_mfma_f32_16x16x32_bf16(sl[ks], xh, yacc[pt], 0, 0, 0);
      }
    }
  }
#pragma unroll
  for (int pt = 0; pt < 2; ++pt) {
    int p = Cb + pt * 16 + l15;
#pragma unroll
    for (int reg = 0; reg < 4; ++reg) {
      int i = Rr + q4 * 4 + reg;
      size_t idx = (size_t)(b * L_ + l0 + i) * DIN + h * HD + p;
      float v = yacc[pt][reg];
      ushort_t hv = f2bf(v);
      yh[idx] = hv;
      yl[idx] = f2bf(v - bf2f(hv));
    }
  }

  // WsumT[p][n]
  {
    const int Pw = (wv >> 1) << 4;
    const int Nb = (wv & 1) << 6;
    f32x4 wacc[4];
#pragma unroll
    for (int nt = 0; nt < 4; ++nt) wacc[nt] = (f32x4){0.f,0.f,0.f,0.f};
    bf16x8 axh[2], axl[2];
#pragma unroll
    for (int ks = 0; ks < 2; ++ks) {
      int cb = ks * 64 + q4 * 16;
      axh[ks] = ldf(xT0H, Pw + l15, 128, cb);
      axl[ks] = ldf(xT0L, Pw + l15, 128, cb);
    }
#pragma unroll
    for (int nt = 0; nt < 4; ++nt) {
      int nrow = Nb + nt * 16 + l15;
#pragma unroll
      for (int ks = 0; ks < 2; ++ks) {
        int cb = ks * 64 + q4 * 16;
        bf16x8 bh = ldf(KTwH, nrow, 128, cb);
        bf16x8 bl = ldf(KTwL, nrow, 128, cb);
        wacc[nt] = __builtin_amdgcn_mfma_f32_16x16x32_bf16(axh[ks], bh, wacc[nt], 0, 0, 0);
        wacc[nt] = __builtin_amdgcn_mfma_f32_16x16x32_bf16(axh[ks], bl, wacc[nt], 0, 0, 0);
        wacc[nt] = __builtin_amdgcn_mfma_f32_16x16x32_bf16(axl[ks], bh, wacc[nt], 0, 0, 0);
      }
    }
    size_t wbase = ((size_t)(b * NC + c) * NH + h) * (size_t)(NST * HD);
#pragma unroll
    for (int nt = 0; nt < 4; ++nt) {
      int n = Nb + nt * 16 + l15;
      float kt = ktail[n];
#pragma unroll
      for (int reg = 0; reg < 4; ++reg) {
        int p = Pw + q4 * 4 + reg;
        WsT[wbase + (size_t)p * NST + n] = wacc[nt][reg] + xtail[p] * kt;
      }
    }
  }
}

// ---------------- P5: state scan (512 blocks, float4/thread, prefetch pipeline) ----------------
__global__ __launch_bounds__(256) void state_scan_kernel(
    float* __restrict__ Wsum, const float* __restrict__ cdg) {
  const int b = blockIdx.x >> 8;
  const int h = (blockIdx.x >> 3) & 31;
  const int g = blockIdx.x & 7;
  const int e = (g << 10) + (threadIdx.x << 2);

  __shared__ float cds[NC];
  if (threadIdx.x < NC)
    cds[threadIdx.x] = cdg[((size_t)b * NC + threadIdx.x) * NH + h];
  __syncthreads();

  float* base = Wsum + ((size_t)(b * NC) * NH + h) * (size_t)(NST * HD) + e;
  const size_t cstride = (size_t)NH * NST * HD;

  F4 Hst; Hst.v = make_float4(0.f, 0.f, 0.f, 0.f);
  F4 w;   w.v = *(const float4*)base;
  for (int c = 0; c < NC; ++c) {
    F4 wn;
    if (c + 1 < NC) wn.v = *(const float4*)(base + (size_t)(c + 1) * cstride);
    const float cd = cds[c];
    *(float4*)(base + (size_t)c * cstride) = Hst.v;
#pragma unroll
    for (int k = 0; k < 4; ++k) Hst.a[k] = fmaf(cd, Hst.a[k], w.a[k]);
    w = wn;
  }
}

// ---------------- P6: finalize (MFMA 3-pass Q.H^T + gate) ----------------
__global__ __launch_bounds__(256) void finalize_kernel(
    const float* __restrict__ proj, const float* __restrict__ Cn,
    const float* __restrict__ theta, const float* __restrict__ C_bias,
    const float* __restrict__ Hprev, const float* __restrict__ adtg,
    const float* __restrict__ dvec,
    ushort_t* __restrict__ yh, ushort_t* __restrict__ yl) {
  const int h  = blockIdx.x & 31;
  const int c  = (blockIdx.x >> 5) & 31;
  const int b  = blockIdx.x >> 10;
  const int t  = threadIdx.x;
  const int l0 = c * CHK;

  __shared__ float Qs[64][64];                             // rope inputs; row 0 reused for ell
  __shared__ __align__(16) char QbH[16384], QbL[16384];    // [64] rows x 256B, swz
  __shared__ __align__(16) char HbH[16384], HbL[16384];

  // phase 1a: Q cols 0..63 (rope inputs) -> Qs f32
#pragma unroll
  for (int k = 0; k < 4; ++k) {
    int f = t + k * 256;
    int i = f >> 4, n4 = (f & 15) << 2;
    F4 v, bb;
    v.v  = *(const float4*)(Cn + (size_t)(b * L_ + l0 + i) * NST + n4);
    bb.v = *(const float4*)(C_bias + h * NST + n4);
#pragma unroll
    for (int q = 0; q < 4; ++q) Qs[i][n4 + q] = v.a[q] + bb.a[q];
  }
  // phase 1b: Q cols 64..127 -> Qb split directly
#pragma unroll
  for (int k = 0; k < 4; ++k) {
    int f = t + k * 256;
    int i = f >> 4, n4 = 64 + ((f & 15) << 2);
    F4 v, bb;
    v.v  = *(const float4*)(Cn + (size_t)(b * L_ + l0 + i) * NST + n4);
    bb.v = *(const float4*)(C_bias + h * NST + n4);
#pragma unroll
    for (int q = 0; q < 4; ++q) {
      float x = v.a[q] + bb.a[q];
      ushort_t hv = f2bf(x);
      st_bf16(QbH, i, 256, (n4 + q) * 2, hv);
      st_bf16(QbL, i, 256, (n4 + q) * 2, f2bf(x - bf2f(hv)));
    }
  }
  // phase 1c: Hprev [p][n] f32 -> Hb split
  {
    const float* hp = Hprev + ((size_t)(b * NC + c) * NH + h) * (size_t)(NST * HD);
#pragma unroll
    for (int k = 0; k < 8; ++k) {
      int f = t + k * 256;
      int p = f >> 5, n4 = (f & 31) << 2;
      F4 v; v.v = *(const float4*)(hp + (size_t)p * NST + n4);
#pragma unroll
      for (int q = 0; q < 4; ++q) {
        ushort_t hv = f2bf(v.a[q]);
        st_bf16(HbH, p, 256, (n4 + q) * 2, hv);
        st_bf16(HbL, p, 256, (n4 + q) * 2, f2bf(v.a[q] - bf2f(hv)));
      }
    }
  }
  __syncthreads();

  // phase 2: rope cols 0..63 -> Qb split
#pragma unroll
  for (int k = 0; k < 8; ++k) {
    int f = t + k * 256;
    int i = f >> 5, na = f & 31;
    float th = theta[((size_t)(b * L_ + l0 + i) * NH + h) * NA + na];
    float sn, cs;
    __sincosf(th, &sn, &cs);
    float q1 = Qs[i][na], q2 = Qs[i][na + 32];
    float o1 = q1 * cs - q2 * sn;
    float o2 = q1 * sn + q2 * cs;
    ushort_t h1 = f2bf(o1), h2 = f2bf(o2);
    st_bf16(QbH, i, 256, na * 2, h1);
    st_bf16(QbL, i, 256, na * 2, f2bf(o1 - bf2f(h1)));
    st_bf16(QbH, i, 256, (na + 32) * 2, h2);
    st_bf16(QbL, i, 256, (na + 32) * 2, f2bf(o2 - bf2f(h2)));
  }
  __syncthreads();

  // phase 3: ell cumsum -> Qs[0][*]   (Qs rope inputs no longer needed)
  if (t < 64) {
    float v = adtg[((size_t)b * NH + h) * L_ + l0 + t];
#pragma unroll
    for (int off = 1; off < 64; off <<= 1) {
      float u = __shfl_up(v, off, 64);
      if (t >= off) v += u;
    }
    Qs[0][t] = v;
  }
  __syncthreads();

  // phase 4: MFMA y_inter = Q . H^T (K=128, 3-pass)
  const int lane = t & 63, wv = t >> 6;
  const int q4 = lane >> 4, l15 = lane & 15;
  const int ib = (wv >> 1) << 5;   // 0 or 32
  const int pb = (wv & 1) << 5;    // 0 or 32

  f32x4 acc[2][2];
  acc[0][0] = (f32x4){0.f,0.f,0.f,0.f}; acc[0][1] = (f32x4){0.f,0.f,0.f,0.f};
  acc[1][0] = (f32x4){0.f,0.f,0.f,0.f}; acc[1][1] = (f32x4){0.f,0.f,0.f,0.f};
#pragma unroll
  for (int ks = 0; ks < 4; ++ks) {
    int cb = ks * 64 + q4 * 16;
    bf16x8 qah[2], qal[2], hbh[2], hbl[2];
#pragma unroll
    for (int fi = 0; fi < 2; ++fi) {
      qah[fi] = ldf(QbH, ib + fi * 16 + l15, 256, cb);
      qal[fi] = ldf(QbL, ib + fi * 16 + l15, 256, cb);
    }
#pragma unroll
    for (int fp = 0; fp < 2; ++fp) {
      hbh[fp] = ldf(HbH, pb + fp * 16 + l15, 256, cb);
      hbl[fp] = ldf(HbL, pb + fp * 16 + l15, 256, cb);
    }
#pragma unroll
    for (int fi = 0; fi < 2; ++fi)
#pragma unroll
      for (int fp = 0; fp < 2; ++fp) {
        acc[fi][fp] = __builtin_amdgcn_mfma_f32_16x16x32_bf16(qah[fi], hbh[fp], acc[fi][fp], 0, 0, 0);
        acc[fi][fp] = __builtin_amdgcn_mfma_f32_16x16x32_bf16(qah[fi], hbl[fp], acc[fi][fp], 0, 0, 0);
        acc[fi][fp] = __builtin_amdgcn_mfma_f32_16x16x32_bf16(qal[fi], hbh[fp], acc[fi][fp], 0, 0, 0);
      }
  }

  // epilogue: y = (y_intra + e*y_inter + D*x) * silu(z), stored split
  const float Dv = dvec[h];
#pragma unroll
  for (int fi = 0; fi < 2; ++fi)
#pragma unroll
    for (int reg = 0; reg < 4; ++reg) {
      int i = ib + fi * 16 + q4 * 4 + reg;
      float e = __expf(Qs[0][i]);
      size_t rowoff = (size_t)(b * L_ + l0 + i);
#pragma unroll
      for (int fp = 0; fp < 2; ++fp) {
        int p = pb + fp * 16 + l15;
        size_t yidx = rowoff * DIN + h * HD + p;
        float yi = bf2f(yh[yidx]) + bf2f(yl[yidx]);
        float xv = proj[rowoff * DPROJ + OFF_X + h * HD + p];
        float z  = proj[rowoff * DPROJ + OFF_Z + h * HD + p];
        float o = (yi + e * acc[fi][fp][reg] + Dv * xv) * (z * sigmoidf_(z));
        ushort_t hv = f2bf(o);
        yh[yidx] = hv;
        yl[yidx] = f2bf(o - bf2f(hv));
      }
    }
}

__global__ void zero_out_kernel(float* __restrict__ out, int n) {
  int i = blockIdx.x * 256 + threadIdx.x;
  if (i < n) out[i] = 0.0f;
}

extern "C" void kernel_launch(void* const* d_in, const int* in_sizes, int n_in,
                              void* d_out, int out_size, void* d_ws, size_t ws_size,
                              hipStream_t stream) {
  const float* u        = (const float*)d_in[0];
  const float* W_in     = (const float*)d_in[1];
  const float* W_out    = (const float*)d_in[2];
  const float* dt_bias  = (const float*)d_in[3];
  const float* B_bias   = (const float*)d_in[4];
  const float* C_bias   = (const float*)d_in[5];
  const float* B_norm_w = (const float*)d_in[6];
  const float* C_norm_w = (const float*)d_in[7];
  const float* Dv       = (const float*)d_in[8];
  float* out = (float*)d_out;
  float* ws  = (float*)d_ws;

  size_t o = 0;
  float* proj  = ws + o; o += (size_t)B_ * L_ * DPROJ;
  float* Bn    = ws + o; o += (size_t)B_ * L_ * NST;
  float* Cn    = ws + o; o += (size_t)B_ * L_ * NST;
  float* dtg   = ws + o; o += (size_t)B_ * NH * L_;
  float* adtg  = ws + o; o += (size_t)B_ * NH * L_;
  float* g1g   = ws + o; o += (size_t)B_ * NH * L_;
  float* g2g   = ws + o; o += (size_t)B_ * NH * L_;
  float* theta = ws + o; o += (size_t)B_ * L_ * NH * NA;
  float* Wsum  = ws + o; o += (size_t)B_ * NC * NH * NST * HD;
  float* cdg   = ws + o; o += (size_t)B_ * NC * NH;
  float* yreg  = ws + o; o += (size_t)B_ * L_ * DIN;
  ushort_t* Wth = (ushort_t*)(ws + o); o += (size_t)DPROJ * DM / 2;
  ushort_t* Wtl = (ushort_t*)(ws + o); o += (size_t)DPROJ * DM / 2;
  ushort_t* Woh = (ushort_t*)(ws + o); o += (size_t)DM * DIN / 2;
  ushort_t* Wol = (ushort_t*)(ws + o); o += (size_t)DM * DIN / 2;

  ushort_t* yh = (ushort_t*)yreg;
  ushort_t* yl = yh + (size_t)B_ * L_ * DIN;
  ushort_t* uh = yh;   // alias: consumed by GEMM1 before chunk overwrites y
  ushort_t* ul = yl;

  if (ws_size < o * sizeof(float)) {
    zero_out_kernel<<<(out_size + 255) / 256, 256, 0, stream>>>(out, out_size);
    return;
  }

  tsplit_kernel<<<dim3(DPROJ / 64, DM / 64), 256, 0, stream>>>(W_in, Wth, Wtl, DM, DPROJ);
  tsplit_kernel<<<dim3(DM / 64, DIN / 64), 256, 0, stream>>>(W_out, Woh, Wol, DIN, DM);
  split_kernel<<<(B_ * L_ * DM / 8 + 255) / 256, 256, 0, stream>>>(
      u, uh, ul, B_ * L_ * DM / 8);
  gemm_glds<<<(DPROJ / 128) * ((B_ * L_) / 128), 256, 0, stream>>>(
      uh, ul, Wth, Wtl, proj, B_ * L_, DPROJ, DM, DPROJ / 128);
  pointwise_kernel<<<B_ * L_, 128, 0, stream>>>(
      proj, dt_bias, B_norm_w, C_norm_w, Bn, Cn, dtg, adtg, g1g, g2g);
  theta_kernel<<<B_ * NH, 512, 0, stream>>>(proj, dtg, theta);
  chunk_kernel<<<B_ * NC * NH, 512, 0, stream>>>(
      proj, Bn, Cn, theta, B_bias, C_bias, adtg, g1g, g2g, Wsum, cdg, yh, yl);
  state_scan_kernel<<<B_ * NH * 8, 256, 0, stream>>>(Wsum, cdg);
  finalize_kernel<<<B_ * NC * NH, 256, 0, stream>>>(
      proj, Cn, theta, C_bias, Wsum, adtg, Dv, yh, yl);
  gemm_glds<<<(DM / 128) * ((B_ * L_) / 128), 256, 0, stream>>>(
      yh, yl, Woh, Wol, out, B_ * L_, DM, DIN, DM / 128);
}